// Round 1
// baseline (1888.173 us; speedup 1.0000x reference)
//
#include <hip/hip_runtime.h>
#include <math.h>

// B=4, T=2048, C=1024, H=16, N=64, Q=256, nc=8, BT=8192
#define BB 4
#define TT 2048
#define CC 1024
#define HH 16
#define NN 64
#define QQ 256
#define NCH 8
#define BT 8192

// ---------------------------------------------------------------------------
// 1. time-shift mix: xx[t] = x[t-1]-x[t] (0-pad), xxx = x + xx*time_maa_x
// ---------------------------------------------------------------------------
__global__ __launch_bounds__(256) void mix_kernel(const float* __restrict__ x,
                                                  const float* __restrict__ tmx,
                                                  float* __restrict__ xx,
                                                  float* __restrict__ xxx) {
  size_t i = (size_t)blockIdx.x * 256 + threadIdx.x;  // < 8388608
  int c = (int)(i & 1023);
  size_t row = i >> 10;          // b*T + t
  int t = (int)(row & 2047);
  float xv = x[i];
  float prev = (t > 0) ? x[i - 1024] : 0.f;
  float d = prev - xv;
  xx[i] = d;
  xxx[i] = xv + d * tmx[c];
}

// ---------------------------------------------------------------------------
// Generic f32 tiled GEMM: C = act(A @ B), BM=BN=128, BK=16, 8x8 microtile
// M,N multiples of 128, K multiple of 16.
// ---------------------------------------------------------------------------
template <bool TANH>
__global__ __launch_bounds__(256) void gemm128(const float* __restrict__ A,
                                               const float* __restrict__ Bm,
                                               float* __restrict__ Cm,
                                               int M, int N, int K) {
  __shared__ float As[16][132];   // [kk][mm], padded, rows 16B-aligned
  __shared__ float Bs[16][128];   // [kk][nn]
  const int tid = threadIdx.x;
  const int row0 = blockIdx.y * 128;
  const int col0 = blockIdx.x * 128;
  const int tx = tid & 15;   // 16 col groups x 8
  const int ty = tid >> 4;   // 16 row groups x 8
  float acc[8][8];
#pragma unroll
  for (int i = 0; i < 8; i++)
#pragma unroll
    for (int j = 0; j < 8; j++) acc[i][j] = 0.f;

  for (int k0 = 0; k0 < K; k0 += 16) {
#pragma unroll
    for (int i = 0; i < 2; i++) {
      int idx4 = tid + i * 256;      // 0..511
      int k4 = idx4 & 3;             // float4 within the 16-wide K slab
      int mm = idx4 >> 2;            // row 0..127
      float4 av = *(const float4*)(A + (size_t)(row0 + mm) * K + k0 + k4 * 4);
      As[k4 * 4 + 0][mm] = av.x;
      As[k4 * 4 + 1][mm] = av.y;
      As[k4 * 4 + 2][mm] = av.z;
      As[k4 * 4 + 3][mm] = av.w;
      int nn4 = idx4 & 31;
      int kk2 = idx4 >> 5;
      *(float4*)&Bs[kk2][nn4 * 4] =
          *(const float4*)(Bm + (size_t)(k0 + kk2) * N + col0 + nn4 * 4);
    }
    __syncthreads();
#pragma unroll
    for (int kk = 0; kk < 16; kk++) {
      float4 a0 = *(const float4*)&As[kk][ty * 8];
      float4 a1 = *(const float4*)&As[kk][ty * 8 + 4];
      float4 b0 = *(const float4*)&Bs[kk][tx * 8];
      float4 b1 = *(const float4*)&Bs[kk][tx * 8 + 4];
      float a[8] = {a0.x, a0.y, a0.z, a0.w, a1.x, a1.y, a1.z, a1.w};
      float b[8] = {b0.x, b0.y, b0.z, b0.w, b1.x, b1.y, b1.z, b1.w};
#pragma unroll
      for (int i = 0; i < 8; i++)
#pragma unroll
        for (int j = 0; j < 8; j++) acc[i][j] += a[i] * b[j];
    }
    __syncthreads();
  }
#pragma unroll
  for (int i = 0; i < 8; i++) {
    size_t r = (size_t)(row0 + ty * 8 + i) * N + col0 + tx * 8;
#pragma unroll
    for (int j = 0; j < 8; j += 4) {
      float4 o;
      o.x = TANH ? tanhf(acc[i][j + 0]) : acc[i][j + 0];
      o.y = TANH ? tanhf(acc[i][j + 1]) : acc[i][j + 1];
      o.z = TANH ? tanhf(acc[i][j + 2]) : acc[i][j + 2];
      o.w = TANH ? tanhf(acc[i][j + 3]) : acc[i][j + 3];
      *(float4*)(Cm + r + j) = o;
    }
  }
}

// ---------------------------------------------------------------------------
// small GEMM for decay_w1 (N=64): BM=BN=64, BK=16, 4x4 microtile, tanh
// ---------------------------------------------------------------------------
__global__ __launch_bounds__(256) void gemm64tanh(const float* __restrict__ A,
                                                  const float* __restrict__ Bm,
                                                  float* __restrict__ Cm,
                                                  int M, int N, int K) {
  __shared__ float As[16][68];
  __shared__ float Bs[16][64];
  const int tid = threadIdx.x;
  const int row0 = blockIdx.y * 64;
  const int col0 = blockIdx.x * 64;
  const int tx = tid & 15;
  const int ty = tid >> 4;
  float acc[4][4];
#pragma unroll
  for (int i = 0; i < 4; i++)
#pragma unroll
    for (int j = 0; j < 4; j++) acc[i][j] = 0.f;

  for (int k0 = 0; k0 < K; k0 += 16) {
    {
      int k4 = tid & 3;
      int mm = tid >> 2;  // 0..63
      float4 av = *(const float4*)(A + (size_t)(row0 + mm) * K + k0 + k4 * 4);
      As[k4 * 4 + 0][mm] = av.x;
      As[k4 * 4 + 1][mm] = av.y;
      As[k4 * 4 + 2][mm] = av.z;
      As[k4 * 4 + 3][mm] = av.w;
      int nn4 = tid & 15;
      int kk2 = tid >> 4;
      *(float4*)&Bs[kk2][nn4 * 4] =
          *(const float4*)(Bm + (size_t)(k0 + kk2) * N + col0 + nn4 * 4);
    }
    __syncthreads();
#pragma unroll
    for (int kk = 0; kk < 16; kk++) {
      float4 a0 = *(const float4*)&As[kk][ty * 4];
      float4 b0 = *(const float4*)&Bs[kk][tx * 4];
      float a[4] = {a0.x, a0.y, a0.z, a0.w};
      float b[4] = {b0.x, b0.y, b0.z, b0.w};
#pragma unroll
      for (int i = 0; i < 4; i++)
#pragma unroll
        for (int j = 0; j < 4; j++) acc[i][j] += a[i] * b[j];
    }
    __syncthreads();
  }
#pragma unroll
  for (int i = 0; i < 4; i++) {
    float4 o;
    o.x = tanhf(acc[i][0]);
    o.y = tanhf(acc[i][1]);
    o.z = tanhf(acc[i][2]);
    o.w = tanhf(acc[i][3]);
    *(float4*)(Cm + (size_t)(row0 + ty * 4 + i) * N + col0 + tx * 4) = o;
  }
}

// ---------------------------------------------------------------------------
// 3. blend: m@maa_w2 per f, then xw/xk/xv/xr
// ---------------------------------------------------------------------------
__global__ __launch_bounds__(256) void blend_kernel(
    const float* __restrict__ x, const float* __restrict__ xx,
    const float* __restrict__ m, const float* __restrict__ tmw,
    const float* __restrict__ tmk, const float* __restrict__ tmv,
    const float* __restrict__ tmr, const float* __restrict__ w2,
    float* __restrict__ xw, float* __restrict__ xk, float* __restrict__ xv,
    float* __restrict__ xr) {
  int bt = blockIdx.x;
  __shared__ float ms[128];
  if (threadIdx.x < 128) ms[threadIdx.x] = m[(size_t)bt * 128 + threadIdx.x];
  __syncthreads();
  for (int c = threadIdx.x; c < 1024; c += 256) {
    float a0 = 0.f, a1 = 0.f, a2 = 0.f, a3 = 0.f;
#pragma unroll 8
    for (int d = 0; d < 32; d++) {
      a0 += ms[d] * w2[(size_t)d * 1024 + c];
      a1 += ms[32 + d] * w2[(size_t)(32 + d) * 1024 + c];
      a2 += ms[64 + d] * w2[(size_t)(64 + d) * 1024 + c];
      a3 += ms[96 + d] * w2[(size_t)(96 + d) * 1024 + c];
    }
    size_t g = (size_t)bt * 1024 + c;
    float xv_ = x[g], dx = xx[g];
    xw[g] = xv_ + dx * (tmw[c] + a0);
    xk[g] = xv_ + dx * (tmk[c] + a1);
    xv[g] = xv_ + dx * (tmv[c] + a2);
    xr[g] = xv_ + dx * (tmr[c] + a3);
  }
}

// ---------------------------------------------------------------------------
// 5a. reduce decay_w2 over head dim (mean over N) -> dw2r[64][16], tdr[16]
// ---------------------------------------------------------------------------
__global__ __launch_bounds__(256) void dw2r_kernel(const float* __restrict__ dw2,
                                                   const float* __restrict__ td,
                                                   float* __restrict__ dw2r,
                                                   float* __restrict__ tdr) {
  int idx = blockIdx.x * 256 + threadIdx.x;
  if (idx < 1024) {
    int j = idx >> 4, h = idx & 15;
    float s = 0.f;
    for (int n = 0; n < 64; n++) s += dw2[(size_t)j * 1024 + h * 64 + n];
    dw2r[j * 16 + h] = s * (1.f / 64.f);
  }
  if (idx < 16) {
    float s = 0.f;
    for (int n = 0; n < 64; n++) s += td[idx * 64 + n];
    tdr[idx] = s * (1.f / 64.f);
  }
}

// ---------------------------------------------------------------------------
// 5b. wlog[b,h,t] = -exp(tdr[h] + h1[bt,:] . dw2r[:,h])
// ---------------------------------------------------------------------------
__global__ __launch_bounds__(256) void wred_kernel(const float* __restrict__ h1,
                                                   const float* __restrict__ dw2r,
                                                   const float* __restrict__ tdr,
                                                   float* __restrict__ wlog) {
  int idx = blockIdx.x * 256 + threadIdx.x;  // < 131072
  int bt = idx >> 4, h = idx & 15;
  float s = tdr[h];
  const float* hrow = h1 + (size_t)bt * 64;
#pragma unroll 8
  for (int j = 0; j < 64; j++) s += hrow[j] * dw2r[j * 16 + h];
  int b = bt >> 11, t = bt & 2047;
  wlog[((size_t)(b * 16 + h)) * 2048 + t] = -expf(s);
}

// ---------------------------------------------------------------------------
// 7. per-chunk scan: inclusive cumsum (cum), exclusive (excl), chunk total (wsl)
//    blockIdx.x = (b*16+h)*8 + c ; 256 threads = Q
// ---------------------------------------------------------------------------
__global__ __launch_bounds__(256) void wprep_kernel(const float* __restrict__ wlog,
                                                    float* __restrict__ cum,
                                                    float* __restrict__ excl,
                                                    float* __restrict__ wsl) {
  int bid = blockIdx.x;
  int c = bid & 7, bh = bid >> 3;
  int q = threadIdx.x;
  float v = wlog[(size_t)bh * 2048 + c * 256 + q];
  __shared__ float s[256];
  s[q] = v;
  float val = v;
  for (int off = 1; off < 256; off <<= 1) {
    __syncthreads();
    float t = (q >= off) ? s[q - off] : 0.f;
    __syncthreads();
    val += t;
    s[q] = val;
  }
  __syncthreads();
  float total = s[255];
  cum[(size_t)bid * 256 + q] = val;
  excl[(size_t)bid * 256 + q] = val - v;
  if (q == 0) wsl[bid] = total;
}

// ---------------------------------------------------------------------------
// 8a. kv[n][m] = sum_q k[q][n]*w_inter[q]*v[q][m] per (b,h,chunk)
// ---------------------------------------------------------------------------
__global__ __launch_bounds__(256) void kv_kernel(const float* __restrict__ kg,
                                                 const float* __restrict__ vg,
                                                 const float* __restrict__ cum,
                                                 const float* __restrict__ wsl,
                                                 float* __restrict__ kvb) {
  int bid = blockIdx.x;
  int c = bid & 7, bh = bid >> 3;
  int b = bh >> 4, h = bh & 15;
  __shared__ float kw[64][65];
  __shared__ float vs[64][65];
  float wslog = wsl[bid];
  int n_ = threadIdx.x >> 2;
  int m0 = (threadIdx.x & 3) * 16;
  float acc[16];
#pragma unroll
  for (int j = 0; j < 16; j++) acc[j] = 0.f;

  for (int qt = 0; qt < 4; qt++) {
    __syncthreads();
#pragma unroll
    for (int i = 0; i < 16; i++) {
      int idx = threadIdx.x + i * 256;  // 0..4095
      int qq = idx >> 6, nn = idx & 63;
      int q = qt * 64 + qq;
      size_t g = ((size_t)(b * TT + c * QQ + q)) * CC + h * 64 + nn;
      float wi = __expf(wslog - cum[(size_t)bid * 256 + q]);
      kw[qq][nn] = kg[g] * wi;
      vs[qq][nn] = vg[g];
    }
    __syncthreads();
    for (int qq = 0; qq < 64; qq++) {
      float a = kw[qq][n_];
#pragma unroll
      for (int j = 0; j < 16; j++) acc[j] += a * vs[qq][m0 + j];
    }
  }
#pragma unroll
  for (int j = 0; j < 16; j++)
    kvb[(size_t)bid * 4096 + n_ * 64 + m0 + j] = acc[j];
}

// ---------------------------------------------------------------------------
// 8b. sequential state scan over chunks (emit state BEFORE update)
// ---------------------------------------------------------------------------
__global__ __launch_bounds__(256) void scan_kernel(const float* __restrict__ kvb,
                                                   const float* __restrict__ wsl,
                                                   float* __restrict__ st) {
  int bh = blockIdx.x;
  int tid = threadIdx.x;
  float s[16];
#pragma unroll
  for (int i = 0; i < 16; i++) s[i] = 0.f;
  for (int c = 0; c < 8; c++) {
    int bid = bh * 8 + c;
    float w = __expf(wsl[bid]);
#pragma unroll
    for (int i = 0; i < 16; i++) {
      size_t e = (size_t)bid * 4096 + i * 256 + tid;
      st[e] = s[i];
      s[i] = w * s[i] + kvb[e];
    }
  }
}

// ---------------------------------------------------------------------------
// 9. fused attention: inter (states) + masked intra scores + faaaa diag
//    block = (b,h,chunk); 256 thr = 64 q-rows x 4 m-segments (16 cols each)
// ---------------------------------------------------------------------------
__global__ __launch_bounds__(256) void attn_kernel(
    const float* __restrict__ rg, const float* __restrict__ kg,
    const float* __restrict__ vg, const float* __restrict__ stg,
    const float* __restrict__ cum, const float* __restrict__ excl,
    const float* __restrict__ faaaa, float* __restrict__ y) {
  int bid = blockIdx.x;
  int c = bid & 7, bh = bid >> 3;
  int b = bh >> 4, h = bh & 15;
  __shared__ float st[64][65];
  __shared__ float ktl[64][65];
  __shared__ float vtl[64][65];
  __shared__ float rt[64][65];
  __shared__ float cumS[256], exS[256], fa[64];

#pragma unroll
  for (int i = 0; i < 16; i++) {
    int idx = threadIdx.x + i * 256;
    st[idx >> 6][idx & 63] = stg[(size_t)bid * 4096 + idx];
  }
  cumS[threadIdx.x] = cum[(size_t)bid * 256 + threadIdx.x];
  exS[threadIdx.x] = excl[(size_t)bid * 256 + threadIdx.x];
  if (threadIdx.x < 64) fa[threadIdx.x] = faaaa[h * 64 + threadIdx.x];

  int qr = threadIdx.x >> 2;
  int m0 = (threadIdx.x & 3) * 16;
  float acc[16];

  for (int qt = 0; qt < 4; qt++) {
    __syncthreads();  // protect rt/ktl/vtl from previous iteration readers
#pragma unroll
    for (int i = 0; i < 16; i++) {
      int idx = threadIdx.x + i * 256;
      int qq = idx >> 6, nn = idx & 63;
      rt[qq][nn] = rg[((size_t)(b * TT + c * QQ + qt * 64 + qq)) * CC + h * 64 + nn];
    }
    __syncthreads();
    int q = qt * 64 + qr;
    float eq = exS[q];
#pragma unroll
    for (int j = 0; j < 16; j++) acc[j] = 0.f;
    // inter: (r * w_intra) @ states
    for (int n = 0; n < 64; n++) {
      float rv = rt[qr][n];
#pragma unroll
      for (int j = 0; j < 16; j++) acc[j] += rv * st[n][m0 + j];
    }
    float wi = __expf(eq);
#pragma unroll
    for (int j = 0; j < 16; j++) acc[j] *= wi;

    for (int ktile = 0; ktile <= qt; ktile++) {
      __syncthreads();
#pragma unroll
      for (int i = 0; i < 16; i++) {
        int idx = threadIdx.x + i * 256;
        int qq = idx >> 6, nn = idx & 63;
        size_t g = ((size_t)(b * TT + c * QQ + ktile * 64 + qq)) * CC + h * 64 + nn;
        ktl[qq][nn] = kg[g];
        vtl[qq][nn] = vg[g];
      }
      __syncthreads();
      int klim = (ktile < qt) ? 64 : (qr + 1);  // include diag k==q
      for (int kk = 0; kk < klim; kk++) {
        int kabs = ktile * 64 + kk;
        float pd = 0.f;
        if (kabs == q) {
#pragma unroll
          for (int i = 0; i < 16; i++)
            pd += rt[qr][m0 + i] * fa[m0 + i] * ktl[kk][m0 + i];
        } else {
#pragma unroll
          for (int i = 0; i < 16; i++) pd += rt[qr][m0 + i] * ktl[kk][m0 + i];
        }
        pd += __shfl_xor(pd, 1);
        pd += __shfl_xor(pd, 2);
        float s = (kabs == q) ? pd : pd * __expf(eq - cumS[kabs]);
#pragma unroll
        for (int j = 0; j < 16; j++) acc[j] += s * vtl[kk][m0 + j];
      }
    }
    size_t o = ((size_t)(b * TT + c * QQ + q)) * CC + h * 64 + m0;
#pragma unroll
    for (int j = 0; j < 16; j += 4) {
      float4 ov;
      ov.x = acc[j + 0];
      ov.y = acc[j + 1];
      ov.z = acc[j + 2];
      ov.w = acc[j + 3];
      *(float4*)(y + o + j) = ov;
    }
  }
}

// ---------------------------------------------------------------------------
// 10. LayerNorm over C
// ---------------------------------------------------------------------------
__global__ __launch_bounds__(256) void ln_kernel(const float* __restrict__ y,
                                                 const float* __restrict__ g,
                                                 const float* __restrict__ bta,
                                                 float* __restrict__ out) {
  __shared__ float red[8];
  int bt = blockIdx.x;
  int tid = threadIdx.x;
  float v[4];
  float s = 0.f;
#pragma unroll
  for (int i = 0; i < 4; i++) {
    v[i] = y[(size_t)bt * 1024 + i * 256 + tid];
    s += v[i];
  }
#pragma unroll
  for (int off = 32; off > 0; off >>= 1) s += __shfl_down(s, off);
  if ((tid & 63) == 0) red[tid >> 6] = s;
  __syncthreads();
  if (tid == 0) red[4] = red[0] + red[1] + red[2] + red[3];
  __syncthreads();
  float mu = red[4] * (1.f / 1024.f);
  float s2 = 0.f;
#pragma unroll
  for (int i = 0; i < 4; i++) {
    float d = v[i] - mu;
    s2 += d * d;
  }
#pragma unroll
  for (int off = 32; off > 0; off >>= 1) s2 += __shfl_down(s2, off);
  __syncthreads();
  if ((tid & 63) == 0) red[tid >> 6] = s2;
  __syncthreads();
  if (tid == 0) red[5] = red[0] + red[1] + red[2] + red[3];
  __syncthreads();
  float var = red[5] * (1.f / 1024.f);
  float rstd = rsqrtf(var + 1e-5f);
#pragma unroll
  for (int i = 0; i < 4; i++) {
    int c = i * 256 + tid;
    out[(size_t)bt * 1024 + c] = (v[i] - mu) * rstd * g[c] + bta[c];
  }
}

// ---------------------------------------------------------------------------
extern "C" void kernel_launch(void* const* d_in, const int* in_sizes, int n_in,
                              void* d_out, int out_size, void* d_ws,
                              size_t ws_size, hipStream_t stream) {
  const float* x = (const float*)d_in[0];
  const float* tmx = (const float*)d_in[1];
  const float* tmw = (const float*)d_in[2];
  const float* tmk = (const float*)d_in[3];
  const float* tmv = (const float*)d_in[4];
  const float* tmr = (const float*)d_in[5];
  const float* maa_w1 = (const float*)d_in[6];
  const float* maa_w2 = (const float*)d_in[7];
  const float* decay_w1 = (const float*)d_in[8];
  const float* decay_w2 = (const float*)d_in[9];
  const float* time_decay = (const float*)d_in[10];
  const float* faaaa = (const float*)d_in[11];
  const float* Wr = (const float*)d_in[12];
  const float* Wk = (const float*)d_in[13];
  const float* Wv = (const float*)d_in[14];
  const float* Wo = (const float*)d_in[15];
  const float* lng = (const float*)d_in[16];
  const float* lnb = (const float*)d_in[17];
  float* out = (float*)d_out;
  float* ws = (float*)d_ws;

  const size_t S = (size_t)BT * CC;  // 8388608
  float* xx = ws;                    // B0: xx -> r
  float* xxx = ws + S;               // B1: xxx -> xw -> k
  float* m = ws + 2 * S;             // 8192x128
  float* xk = m + (size_t)BT * 128;  // B3: xk -> y
  float* xv = xk + S;                // B4: xv -> yln
  float* xr = xv + S;                // B5: xr -> v
  float* h1 = xr + S;                // 8192x64
  float* dw2r = h1 + (size_t)BT * 64;
  float* tdr = dw2r + 1024;
  float* wlog = tdr + 16;            // B*H*T = 131072
  float* cum = wlog + 131072;
  float* excl = cum + 131072;
  float* wsl = excl + 131072;        // 512
  float* kvb = wsl + 512;            // 512*4096
  float* stb = kvb + (size_t)512 * 4096;

  float* xw = xxx;   // reuse after maa GEMM consumed xxx
  float* r_ = xx;    // reuse after blend consumed xx
  float* k_ = xxx;   // reuse after gemm64tanh consumed xw
  float* v_ = xr;    // reuse after r-GEMM consumed xr
  float* y_ = xk;    // reuse after k-GEMM consumed xk
  float* yln = xv;   // reuse after v-GEMM consumed xv

  mix_kernel<<<32768, 256, 0, stream>>>(x, tmx, xx, xxx);
  gemm128<true><<<dim3(1, 64), 256, 0, stream>>>(xxx, maa_w1, m, BT, 128, CC);
  blend_kernel<<<BT, 256, 0, stream>>>(x, xx, m, tmw, tmk, tmv, tmr, maa_w2,
                                       xw, xk, xv, xr);
  gemm64tanh<<<dim3(1, 128), 256, 0, stream>>>(xw, decay_w1, h1, BT, 64, CC);
  dw2r_kernel<<<4, 256, 0, stream>>>(decay_w2, time_decay, dw2r, tdr);
  wred_kernel<<<512, 256, 0, stream>>>(h1, dw2r, tdr, wlog);
  gemm128<false><<<dim3(8, 64), 256, 0, stream>>>(xr, Wr, r_, BT, CC, CC);
  gemm128<false><<<dim3(8, 64), 256, 0, stream>>>(xk, Wk, k_, BT, CC, CC);
  gemm128<false><<<dim3(8, 64), 256, 0, stream>>>(xv, Wv, v_, BT, CC, CC);
  wprep_kernel<<<512, 256, 0, stream>>>(wlog, cum, excl, wsl);
  kv_kernel<<<512, 256, 0, stream>>>(k_, v_, cum, wsl, kvb);
  scan_kernel<<<64, 256, 0, stream>>>(kvb, wsl, stb);
  attn_kernel<<<512, 256, 0, stream>>>(r_, k_, v_, stb, cum, excl, faaaa, y_);
  ln_kernel<<<BT, 256, 0, stream>>>(y_, lng, lnb, yln);
  gemm128<false><<<dim3(8, 64), 256, 0, stream>>>(yln, Wo, out, BT, CC, CC);
}

// Round 2
// 1222.216 us; speedup vs baseline: 1.5449x; 1.5449x over previous
//
#include <hip/hip_runtime.h>
#include <math.h>

// B=4, T=2048, C=1024, H=16, N=64, Q=256, nc=8, BT=8192
#define BB 4
#define TT 2048
#define CC 1024
#define HH 16
#define NN 64
#define QQ 256
#define NCH 8
#define BT 8192

typedef unsigned short u16;
typedef __attribute__((ext_vector_type(8))) short bf16x8;
typedef __attribute__((ext_vector_type(4))) float f32x4;

// f32 -> bf16 bits, round-to-nearest-even
__device__ inline u16 f2b(float x) {
  union { float f; unsigned u; } v;
  v.f = x;
  unsigned r = v.u + 0x7FFFu + ((v.u >> 16) & 1u);
  return (u16)(r >> 16);
}

// ---------------------------------------------------------------------------
// 1. time-shift mix: xx[t] = x[t-1]-x[t] (0-pad), xxx = x + xx*time_maa_x
// ---------------------------------------------------------------------------
__global__ __launch_bounds__(256) void mix_kernel(const float* __restrict__ x,
                                                  const float* __restrict__ tmx,
                                                  float* __restrict__ xx,
                                                  float* __restrict__ xxx) {
  size_t i = (size_t)blockIdx.x * 256 + threadIdx.x;  // < 8388608
  int c = (int)(i & 1023);
  size_t row = i >> 10;
  int t = (int)(row & 2047);
  float xv = x[i];
  float prev = (t > 0) ? x[i - 1024] : 0.f;
  float d = prev - xv;
  xx[i] = d;
  xxx[i] = xv + d * tmx[c];
}

// ---------------------------------------------------------------------------
// f32 tiled GEMM (kept for the small maa GEMM): C = tanh(A @ B)
// ---------------------------------------------------------------------------
template <bool TANH>
__global__ __launch_bounds__(256) void gemm128(const float* __restrict__ A,
                                               const float* __restrict__ Bm,
                                               float* __restrict__ Cm,
                                               int M, int N, int K) {
  __shared__ float As[16][132];
  __shared__ float Bs[16][128];
  const int tid = threadIdx.x;
  const int row0 = blockIdx.y * 128;
  const int col0 = blockIdx.x * 128;
  const int tx = tid & 15;
  const int ty = tid >> 4;
  float acc[8][8];
#pragma unroll
  for (int i = 0; i < 8; i++)
#pragma unroll
    for (int j = 0; j < 8; j++) acc[i][j] = 0.f;

  for (int k0 = 0; k0 < K; k0 += 16) {
#pragma unroll
    for (int i = 0; i < 2; i++) {
      int idx4 = tid + i * 256;
      int k4 = idx4 & 3;
      int mm = idx4 >> 2;
      float4 av = *(const float4*)(A + (size_t)(row0 + mm) * K + k0 + k4 * 4);
      As[k4 * 4 + 0][mm] = av.x;
      As[k4 * 4 + 1][mm] = av.y;
      As[k4 * 4 + 2][mm] = av.z;
      As[k4 * 4 + 3][mm] = av.w;
      int nn4 = idx4 & 31;
      int kk2 = idx4 >> 5;
      *(float4*)&Bs[kk2][nn4 * 4] =
          *(const float4*)(Bm + (size_t)(k0 + kk2) * N + col0 + nn4 * 4);
    }
    __syncthreads();
#pragma unroll
    for (int kk = 0; kk < 16; kk++) {
      float4 a0 = *(const float4*)&As[kk][ty * 8];
      float4 a1 = *(const float4*)&As[kk][ty * 8 + 4];
      float4 b0 = *(const float4*)&Bs[kk][tx * 8];
      float4 b1 = *(const float4*)&Bs[kk][tx * 8 + 4];
      float a[8] = {a0.x, a0.y, a0.z, a0.w, a1.x, a1.y, a1.z, a1.w};
      float b[8] = {b0.x, b0.y, b0.z, b0.w, b1.x, b1.y, b1.z, b1.w};
#pragma unroll
      for (int i = 0; i < 8; i++)
#pragma unroll
        for (int j = 0; j < 8; j++) acc[i][j] += a[i] * b[j];
    }
    __syncthreads();
  }
#pragma unroll
  for (int i = 0; i < 8; i++) {
    size_t r = (size_t)(row0 + ty * 8 + i) * N + col0 + tx * 8;
#pragma unroll
    for (int j = 0; j < 8; j += 4) {
      float4 o;
      o.x = TANH ? tanhf(acc[i][j + 0]) : acc[i][j + 0];
      o.y = TANH ? tanhf(acc[i][j + 1]) : acc[i][j + 1];
      o.z = TANH ? tanhf(acc[i][j + 2]) : acc[i][j + 2];
      o.w = TANH ? tanhf(acc[i][j + 3]) : acc[i][j + 3];
      *(float4*)(Cm + r + j) = o;
    }
  }
}

// ---------------------------------------------------------------------------
// small GEMM for decay_w1 (N=64): tanh
// ---------------------------------------------------------------------------
__global__ __launch_bounds__(256) void gemm64tanh(const float* __restrict__ A,
                                                  const float* __restrict__ Bm,
                                                  float* __restrict__ Cm,
                                                  int M, int N, int K) {
  __shared__ float As[16][68];
  __shared__ float Bs[16][64];
  const int tid = threadIdx.x;
  const int row0 = blockIdx.y * 64;
  const int col0 = blockIdx.x * 64;
  const int tx = tid & 15;
  const int ty = tid >> 4;
  float acc[4][4];
#pragma unroll
  for (int i = 0; i < 4; i++)
#pragma unroll
    for (int j = 0; j < 4; j++) acc[i][j] = 0.f;

  for (int k0 = 0; k0 < K; k0 += 16) {
    {
      int k4 = tid & 3;
      int mm = tid >> 2;
      float4 av = *(const float4*)(A + (size_t)(row0 + mm) * K + k0 + k4 * 4);
      As[k4 * 4 + 0][mm] = av.x;
      As[k4 * 4 + 1][mm] = av.y;
      As[k4 * 4 + 2][mm] = av.z;
      As[k4 * 4 + 3][mm] = av.w;
      int nn4 = tid & 15;
      int kk2 = tid >> 4;
      *(float4*)&Bs[kk2][nn4 * 4] =
          *(const float4*)(Bm + (size_t)(k0 + kk2) * N + col0 + nn4 * 4);
    }
    __syncthreads();
#pragma unroll
    for (int kk = 0; kk < 16; kk++) {
      float4 a0 = *(const float4*)&As[kk][ty * 4];
      float4 b0 = *(const float4*)&Bs[kk][tx * 4];
      float a[4] = {a0.x, a0.y, a0.z, a0.w};
      float b[4] = {b0.x, b0.y, b0.z, b0.w};
#pragma unroll
      for (int i = 0; i < 4; i++)
#pragma unroll
        for (int j = 0; j < 4; j++) acc[i][j] += a[i] * b[j];
    }
    __syncthreads();
  }
#pragma unroll
  for (int i = 0; i < 4; i++) {
    float4 o;
    o.x = tanhf(acc[i][0]);
    o.y = tanhf(acc[i][1]);
    o.z = tanhf(acc[i][2]);
    o.w = tanhf(acc[i][3]);
    *(float4*)(Cm + (size_t)(row0 + ty * 4 + i) * N + col0 + tx * 4) = o;
  }
}

// ---------------------------------------------------------------------------
// weight f32[k][n] -> bf16 transposed Wt[n][k], 64x64 LDS tiles, z = which W
// ---------------------------------------------------------------------------
__global__ __launch_bounds__(256) void cvt_wT(const float* __restrict__ W0,
                                              const float* __restrict__ W1,
                                              const float* __restrict__ W2,
                                              const float* __restrict__ W3,
                                              u16* __restrict__ O0,
                                              u16* __restrict__ O1,
                                              u16* __restrict__ O2,
                                              u16* __restrict__ O3) {
  const float* W;
  u16* O;
  switch (blockIdx.z) {
    case 0: W = W0; O = O0; break;
    case 1: W = W1; O = O1; break;
    case 2: W = W2; O = O2; break;
    default: W = W3; O = O3; break;
  }
  __shared__ float t[64][65];
  int bx = blockIdx.x * 64;  // n tile
  int by = blockIdx.y * 64;  // k tile
#pragma unroll
  for (int it = 0; it < 16; it++) {
    int idx = it * 256 + threadIdx.x;
    int r = idx >> 6, c = idx & 63;
    t[r][c] = W[(size_t)(by + r) * 1024 + bx + c];
  }
  __syncthreads();
#pragma unroll
  for (int it = 0; it < 16; it++) {
    int idx = it * 256 + threadIdx.x;
    int n = idx >> 6, k = idx & 63;
    O[(size_t)(bx + n) * 1024 + by + k] = f2b(t[k][n]);
  }
}

// ---------------------------------------------------------------------------
// bf16 MFMA GEMM (m97 pattern): A[M][K] bf16 row-major, Bt[N][K] bf16
// row-major (i.e. B transposed), C[M][N] f32.  128x128 tile, BK=32,
// global_load_lds width=16 staging, 16x16x32 MFMA, 4x4 tiles per wave.
// ---------------------------------------------------------------------------
__global__ __launch_bounds__(256) void gemm_bt_mfma(const u16* __restrict__ A,
                                                    const u16* __restrict__ Bt,
                                                    float* __restrict__ C,
                                                    int M, int N, int K) {
  __shared__ u16 As[128 * 32];  // row-major [m][k], no pad (even bank spread)
  __shared__ u16 Bs[128 * 32];  // row-major [n][k]
  const int tid = threadIdx.x;
  const int lane = tid & 63;
  const int row0 = blockIdx.y * 128;
  const int col0 = blockIdx.x * 128;
  const int wave = tid >> 6;
  const int wr = (wave >> 1) * 64;  // wave row offset in tile
  const int wc = (wave & 1) * 64;   // wave col offset in tile
  const int fr = lane & 15;         // fragment row/col index
  const int fq = lane >> 4;         // quad -> k-slab *8

  f32x4 acc[4][4];
#pragma unroll
  for (int i = 0; i < 4; i++)
#pragma unroll
    for (int j = 0; j < 4; j++) acc[i][j] = (f32x4){0.f, 0.f, 0.f, 0.f};

  // staging chunk indices: chunk i covers X[i>>2][ (i&3)*8 .. +8 )
  const int i0 = tid, i1 = tid + 256;
  const int ra0 = i0 >> 2, ca0 = (i0 & 3) * 8;
  const int ra1 = i1 >> 2, ca1 = (i1 & 3) * 8;

  for (int k0 = 0; k0 < K; k0 += 32) {
    __builtin_amdgcn_global_load_lds(
        (const __attribute__((address_space(1))) void*)(A + (size_t)(row0 + ra0) * K + k0 + ca0),
        (__attribute__((address_space(3))) void*)(As + i0 * 8), 16, 0, 0);
    __builtin_amdgcn_global_load_lds(
        (const __attribute__((address_space(1))) void*)(A + (size_t)(row0 + ra1) * K + k0 + ca1),
        (__attribute__((address_space(3))) void*)(As + i1 * 8), 16, 0, 0);
    __builtin_amdgcn_global_load_lds(
        (const __attribute__((address_space(1))) void*)(Bt + (size_t)(col0 + ra0) * K + k0 + ca0),
        (__attribute__((address_space(3))) void*)(Bs + i0 * 8), 16, 0, 0);
    __builtin_amdgcn_global_load_lds(
        (const __attribute__((address_space(1))) void*)(Bt + (size_t)(col0 + ra1) * K + k0 + ca1),
        (__attribute__((address_space(3))) void*)(Bs + i1 * 8), 16, 0, 0);
    __syncthreads();

    bf16x8 af[4], bf[4];
#pragma unroll
    for (int i = 0; i < 4; i++)
      af[i] = *(const bf16x8*)(As + ((wr + i * 16 + fr) * 32 + fq * 8));
#pragma unroll
    for (int j = 0; j < 4; j++)
      bf[j] = *(const bf16x8*)(Bs + ((wc + j * 16 + fr) * 32 + fq * 8));
#pragma unroll
    for (int i = 0; i < 4; i++)
#pragma unroll
      for (int j = 0; j < 4; j++)
        acc[i][j] = __builtin_amdgcn_mfma_f32_16x16x32_bf16(af[i], bf[j], acc[i][j], 0, 0, 0);
    __syncthreads();
  }
  // D layout: row = fq*4 + r, col = fr
#pragma unroll
  for (int i = 0; i < 4; i++) {
    int grow = row0 + wr + i * 16 + fq * 4;
#pragma unroll
    for (int j = 0; j < 4; j++) {
      int gcol = col0 + wc + j * 16 + fr;
#pragma unroll
      for (int r = 0; r < 4; r++)
        C[(size_t)(grow + r) * N + gcol] = acc[i][j][r];
    }
  }
}

// ---------------------------------------------------------------------------
// 3. blend: m@maa_w2 per f, then xw (f32) / xk,xv,xr (bf16 for MFMA GEMMs)
// ---------------------------------------------------------------------------
__global__ __launch_bounds__(256) void blend_kernel(
    const float* __restrict__ x, const float* __restrict__ xx,
    const float* __restrict__ m, const float* __restrict__ tmw,
    const float* __restrict__ tmk, const float* __restrict__ tmv,
    const float* __restrict__ tmr, const float* __restrict__ w2,
    float* __restrict__ xw, u16* __restrict__ xkb, u16* __restrict__ xvb,
    u16* __restrict__ xrb) {
  int bt = blockIdx.x;
  __shared__ float ms[128];
  if (threadIdx.x < 128) ms[threadIdx.x] = m[(size_t)bt * 128 + threadIdx.x];
  __syncthreads();
  for (int c = threadIdx.x; c < 1024; c += 256) {
    float a0 = 0.f, a1 = 0.f, a2 = 0.f, a3 = 0.f;
#pragma unroll 8
    for (int d = 0; d < 32; d++) {
      a0 += ms[d] * w2[(size_t)d * 1024 + c];
      a1 += ms[32 + d] * w2[(size_t)(32 + d) * 1024 + c];
      a2 += ms[64 + d] * w2[(size_t)(64 + d) * 1024 + c];
      a3 += ms[96 + d] * w2[(size_t)(96 + d) * 1024 + c];
    }
    size_t g = (size_t)bt * 1024 + c;
    float xv_ = x[g], dx = xx[g];
    xw[g] = xv_ + dx * (tmw[c] + a0);
    xkb[g] = f2b(xv_ + dx * (tmk[c] + a1));
    xvb[g] = f2b(xv_ + dx * (tmv[c] + a2));
    xrb[g] = f2b(xv_ + dx * (tmr[c] + a3));
  }
}

// ---------------------------------------------------------------------------
// 5a. reduce decay_w2 over head dim (mean over N) -> dw2r[64][16], tdr[16]
// ---------------------------------------------------------------------------
__global__ __launch_bounds__(256) void dw2r_kernel(const float* __restrict__ dw2,
                                                   const float* __restrict__ td,
                                                   float* __restrict__ dw2r,
                                                   float* __restrict__ tdr) {
  int idx = blockIdx.x * 256 + threadIdx.x;
  if (idx < 1024) {
    int j = idx >> 4, h = idx & 15;
    float s = 0.f;
    for (int n = 0; n < 64; n++) s += dw2[(size_t)j * 1024 + h * 64 + n];
    dw2r[j * 16 + h] = s * (1.f / 64.f);
  }
  if (idx < 16) {
    float s = 0.f;
    for (int n = 0; n < 64; n++) s += td[idx * 64 + n];
    tdr[idx] = s * (1.f / 64.f);
  }
}

// ---------------------------------------------------------------------------
// 5b. wlog[b,h,t] = -exp(tdr[h] + h1[bt,:] . dw2r[:,h])
// ---------------------------------------------------------------------------
__global__ __launch_bounds__(256) void wred_kernel(const float* __restrict__ h1,
                                                   const float* __restrict__ dw2r,
                                                   const float* __restrict__ tdr,
                                                   float* __restrict__ wlog) {
  int idx = blockIdx.x * 256 + threadIdx.x;  // < 131072
  int bt = idx >> 4, h = idx & 15;
  float s = tdr[h];
  const float* hrow = h1 + (size_t)bt * 64;
#pragma unroll 8
  for (int j = 0; j < 64; j++) s += hrow[j] * dw2r[j * 16 + h];
  int b = bt >> 11, t = bt & 2047;
  wlog[((size_t)(b * 16 + h)) * 2048 + t] = -expf(s);
}

// ---------------------------------------------------------------------------
// 7. per-chunk scan
// ---------------------------------------------------------------------------
__global__ __launch_bounds__(256) void wprep_kernel(const float* __restrict__ wlog,
                                                    float* __restrict__ cum,
                                                    float* __restrict__ excl,
                                                    float* __restrict__ wsl) {
  int bid = blockIdx.x;
  int c = bid & 7, bh = bid >> 3;
  int q = threadIdx.x;
  float v = wlog[(size_t)bh * 2048 + c * 256 + q];
  __shared__ float s[256];
  s[q] = v;
  float val = v;
  for (int off = 1; off < 256; off <<= 1) {
    __syncthreads();
    float t = (q >= off) ? s[q - off] : 0.f;
    __syncthreads();
    val += t;
    s[q] = val;
  }
  __syncthreads();
  float total = s[255];
  cum[(size_t)bid * 256 + q] = val;
  excl[(size_t)bid * 256 + q] = val - v;
  if (q == 0) wsl[bid] = total;
}

// ---------------------------------------------------------------------------
// 8a. kv[n][m] = sum_q k[q][n]*w_inter[q]*v[q][m] per (b,h,chunk)
// ---------------------------------------------------------------------------
__global__ __launch_bounds__(256) void kv_kernel(const float* __restrict__ kg,
                                                 const float* __restrict__ vg,
                                                 const float* __restrict__ cum,
                                                 const float* __restrict__ wsl,
                                                 float* __restrict__ kvb) {
  int bid = blockIdx.x;
  int c = bid & 7, bh = bid >> 3;
  int b = bh >> 4, h = bh & 15;
  __shared__ float kw[64][65];
  __shared__ float vs[64][65];
  float wslog = wsl[bid];
  int n_ = threadIdx.x >> 2;
  int m0 = (threadIdx.x & 3) * 16;
  float acc[16];
#pragma unroll
  for (int j = 0; j < 16; j++) acc[j] = 0.f;

  for (int qt = 0; qt < 4; qt++) {
    __syncthreads();
#pragma unroll
    for (int i = 0; i < 16; i++) {
      int idx = threadIdx.x + i * 256;
      int qq = idx >> 6, nn = idx & 63;
      int q = qt * 64 + qq;
      size_t g = ((size_t)(b * TT + c * QQ + q)) * CC + h * 64 + nn;
      float wi = __expf(wslog - cum[(size_t)bid * 256 + q]);
      kw[qq][nn] = kg[g] * wi;
      vs[qq][nn] = vg[g];
    }
    __syncthreads();
    for (int qq = 0; qq < 64; qq++) {
      float a = kw[qq][n_];
#pragma unroll
      for (int j = 0; j < 16; j++) acc[j] += a * vs[qq][m0 + j];
    }
  }
#pragma unroll
  for (int j = 0; j < 16; j++)
    kvb[(size_t)bid * 4096 + n_ * 64 + m0 + j] = acc[j];
}

// ---------------------------------------------------------------------------
// 8b. sequential state scan over chunks (emit state BEFORE update)
// ---------------------------------------------------------------------------
__global__ __launch_bounds__(256) void scan_kernel(const float* __restrict__ kvb,
                                                   const float* __restrict__ wsl,
                                                   float* __restrict__ st) {
  int bh = blockIdx.x;
  int tid = threadIdx.x;
  float s[16];
#pragma unroll
  for (int i = 0; i < 16; i++) s[i] = 0.f;
  for (int c = 0; c < 8; c++) {
    int bid = bh * 8 + c;
    float w = __expf(wsl[bid]);
#pragma unroll
    for (int i = 0; i < 16; i++) {
      size_t e = (size_t)bid * 4096 + i * 256 + tid;
      st[e] = s[i];
      s[i] = w * s[i] + kvb[e];
    }
  }
}

// ---------------------------------------------------------------------------
// 9. fused attention (unchanged this round)
// ---------------------------------------------------------------------------
__global__ __launch_bounds__(256) void attn_kernel(
    const float* __restrict__ rg, const float* __restrict__ kg,
    const float* __restrict__ vg, const float* __restrict__ stg,
    const float* __restrict__ cum, const float* __restrict__ excl,
    const float* __restrict__ faaaa, float* __restrict__ y) {
  int bid = blockIdx.x;
  int c = bid & 7, bh = bid >> 3;
  int b = bh >> 4, h = bh & 15;
  __shared__ float st[64][65];
  __shared__ float ktl[64][65];
  __shared__ float vtl[64][65];
  __shared__ float rt[64][65];
  __shared__ float cumS[256], exS[256], fa[64];

#pragma unroll
  for (int i = 0; i < 16; i++) {
    int idx = threadIdx.x + i * 256;
    st[idx >> 6][idx & 63] = stg[(size_t)bid * 4096 + idx];
  }
  cumS[threadIdx.x] = cum[(size_t)bid * 256 + threadIdx.x];
  exS[threadIdx.x] = excl[(size_t)bid * 256 + threadIdx.x];
  if (threadIdx.x < 64) fa[threadIdx.x] = faaaa[h * 64 + threadIdx.x];

  int qr = threadIdx.x >> 2;
  int m0 = (threadIdx.x & 3) * 16;
  float acc[16];

  for (int qt = 0; qt < 4; qt++) {
    __syncthreads();
#pragma unroll
    for (int i = 0; i < 16; i++) {
      int idx = threadIdx.x + i * 256;
      int qq = idx >> 6, nn = idx & 63;
      rt[qq][nn] = rg[((size_t)(b * TT + c * QQ + qt * 64 + qq)) * CC + h * 64 + nn];
    }
    __syncthreads();
    int q = qt * 64 + qr;
    float eq = exS[q];
#pragma unroll
    for (int j = 0; j < 16; j++) acc[j] = 0.f;
    for (int n = 0; n < 64; n++) {
      float rv = rt[qr][n];
#pragma unroll
      for (int j = 0; j < 16; j++) acc[j] += rv * st[n][m0 + j];
    }
    float wi = __expf(eq);
#pragma unroll
    for (int j = 0; j < 16; j++) acc[j] *= wi;

    for (int ktile = 0; ktile <= qt; ktile++) {
      __syncthreads();
#pragma unroll
      for (int i = 0; i < 16; i++) {
        int idx = threadIdx.x + i * 256;
        int qq = idx >> 6, nn = idx & 63;
        size_t g = ((size_t)(b * TT + c * QQ + ktile * 64 + qq)) * CC + h * 64 + nn;
        ktl[qq][nn] = kg[g];
        vtl[qq][nn] = vg[g];
      }
      __syncthreads();
      int klim = (ktile < qt) ? 64 : (qr + 1);
      for (int kk = 0; kk < klim; kk++) {
        int kabs = ktile * 64 + kk;
        float pd = 0.f;
        if (kabs == q) {
#pragma unroll
          for (int i = 0; i < 16; i++)
            pd += rt[qr][m0 + i] * fa[m0 + i] * ktl[kk][m0 + i];
        } else {
#pragma unroll
          for (int i = 0; i < 16; i++) pd += rt[qr][m0 + i] * ktl[kk][m0 + i];
        }
        pd += __shfl_xor(pd, 1);
        pd += __shfl_xor(pd, 2);
        float s = (kabs == q) ? pd : pd * __expf(eq - cumS[kabs]);
#pragma unroll
        for (int j = 0; j < 16; j++) acc[j] += s * vtl[kk][m0 + j];
      }
    }
    size_t o = ((size_t)(b * TT + c * QQ + q)) * CC + h * 64 + m0;
#pragma unroll
    for (int j = 0; j < 16; j += 4) {
      float4 ov;
      ov.x = acc[j + 0];
      ov.y = acc[j + 1];
      ov.z = acc[j + 2];
      ov.w = acc[j + 3];
      *(float4*)(y + o + j) = ov;
    }
  }
}

// ---------------------------------------------------------------------------
// 10. LayerNorm over C -> bf16 (feeds final MFMA GEMM)
// ---------------------------------------------------------------------------
__global__ __launch_bounds__(256) void ln_kernel(const float* __restrict__ y,
                                                 const float* __restrict__ g,
                                                 const float* __restrict__ bta,
                                                 u16* __restrict__ out) {
  __shared__ float red[8];
  int bt = blockIdx.x;
  int tid = threadIdx.x;
  float v[4];
  float s = 0.f;
#pragma unroll
  for (int i = 0; i < 4; i++) {
    v[i] = y[(size_t)bt * 1024 + i * 256 + tid];
    s += v[i];
  }
#pragma unroll
  for (int off = 32; off > 0; off >>= 1) s += __shfl_down(s, off);
  if ((tid & 63) == 0) red[tid >> 6] = s;
  __syncthreads();
  if (tid == 0) red[4] = red[0] + red[1] + red[2] + red[3];
  __syncthreads();
  float mu = red[4] * (1.f / 1024.f);
  float s2 = 0.f;
#pragma unroll
  for (int i = 0; i < 4; i++) {
    float d = v[i] - mu;
    s2 += d * d;
  }
#pragma unroll
  for (int off = 32; off > 0; off >>= 1) s2 += __shfl_down(s2, off);
  __syncthreads();
  if ((tid & 63) == 0) red[tid >> 6] = s2;
  __syncthreads();
  if (tid == 0) red[5] = red[0] + red[1] + red[2] + red[3];
  __syncthreads();
  float var = red[5] * (1.f / 1024.f);
  float rstd = rsqrtf(var + 1e-5f);
#pragma unroll
  for (int i = 0; i < 4; i++) {
    int c = i * 256 + tid;
    out[(size_t)bt * 1024 + c] = f2b((v[i] - mu) * rstd * g[c] + bta[c]);
  }
}

// ---------------------------------------------------------------------------
extern "C" void kernel_launch(void* const* d_in, const int* in_sizes, int n_in,
                              void* d_out, int out_size, void* d_ws,
                              size_t ws_size, hipStream_t stream) {
  const float* x = (const float*)d_in[0];
  const float* tmx = (const float*)d_in[1];
  const float* tmw = (const float*)d_in[2];
  const float* tmk = (const float*)d_in[3];
  const float* tmv = (const float*)d_in[4];
  const float* tmr = (const float*)d_in[5];
  const float* maa_w1 = (const float*)d_in[6];
  const float* maa_w2 = (const float*)d_in[7];
  const float* decay_w1 = (const float*)d_in[8];
  const float* decay_w2 = (const float*)d_in[9];
  const float* time_decay = (const float*)d_in[10];
  const float* faaaa = (const float*)d_in[11];
  const float* Wr = (const float*)d_in[12];
  const float* Wk = (const float*)d_in[13];
  const float* Wv = (const float*)d_in[14];
  const float* Wo = (const float*)d_in[15];
  const float* lng = (const float*)d_in[16];
  const float* lnb = (const float*)d_in[17];
  float* out = (float*)d_out;
  float* ws = (float*)d_ws;

  const size_t S = (size_t)BT * CC;  // 8388608

  // f32 region
  float* xx = ws;                       // -> r_
  float* xxx = ws + S;                  // -> xw -> k_
  float* v_ = ws + 2 * S;
  float* m = ws + 3 * S;                // BT*128
  float* h1 = m + (size_t)BT * 128;     // BT*64
  float* dw2r = h1 + (size_t)BT * 64;   // 1024
  float* tdr = dw2r + 1024;             // pad to 1024
  float* wlog = tdr + 1024;             // 131072
  float* cum = wlog + 131072;
  float* excl = cum + 131072;
  float* wsl = excl + 131072;           // pad to 1024
  float* kvb = wsl + 1024;              // 512*4096
  float* stb = kvb + (size_t)512 * 4096;
  float* fend = stb + (size_t)512 * 4096;
  // bf16 region
  u16* xrb = (u16*)fend;    // S ushorts; later reused as ylnb
  u16* xkb = xrb + S;       // S ushorts; xkb+xvb reused as y_ (f32, S floats)
  u16* xvb = xkb + S;
  u16* Wrt = xvb + S;       // 1M ushorts each
  u16* Wkt = Wrt + (size_t)1024 * 1024;
  u16* Wvt = Wkt + (size_t)1024 * 1024;
  u16* Wot = Wvt + (size_t)1024 * 1024;
  // aliases
  float* xw = xxx;
  float* r_ = xx;
  float* k_ = xxx;
  float* y_ = (float*)xkb;  // spans xkb+xvb (both dead before attn writes)
  u16* ylnb = xrb;          // xrb dead after r-projection GEMM

  cvt_wT<<<dim3(16, 16, 4), 256, 0, stream>>>(Wr, Wk, Wv, Wo, Wrt, Wkt, Wvt, Wot);
  mix_kernel<<<32768, 256, 0, stream>>>(x, tmx, xx, xxx);
  gemm128<true><<<dim3(1, 64), 256, 0, stream>>>(xxx, maa_w1, m, BT, 128, CC);
  blend_kernel<<<BT, 256, 0, stream>>>(x, xx, m, tmw, tmk, tmv, tmr, maa_w2,
                                       xw, xkb, xvb, xrb);
  gemm64tanh<<<dim3(1, 128), 256, 0, stream>>>(xw, decay_w1, h1, BT, 64, CC);
  dw2r_kernel<<<4, 256, 0, stream>>>(decay_w2, time_decay, dw2r, tdr);
  wred_kernel<<<512, 256, 0, stream>>>(h1, dw2r, tdr, wlog);
  gemm_bt_mfma<<<dim3(8, 64), 256, 0, stream>>>(xrb, Wrt, r_, BT, CC, CC);
  gemm_bt_mfma<<<dim3(8, 64), 256, 0, stream>>>(xkb, Wkt, k_, BT, CC, CC);
  gemm_bt_mfma<<<dim3(8, 64), 256, 0, stream>>>(xvb, Wvt, v_, BT, CC, CC);
  wprep_kernel<<<512, 256, 0, stream>>>(wlog, cum, excl, wsl);
  kv_kernel<<<512, 256, 0, stream>>>(k_, v_, cum, wsl, kvb);
  scan_kernel<<<64, 256, 0, stream>>>(kvb, wsl, stb);
  attn_kernel<<<512, 256, 0, stream>>>(r_, k_, v_, stb, cum, excl, faaaa, y_);
  ln_kernel<<<BT, 256, 0, stream>>>(y_, lng, lnb, ylnb);
  gemm_bt_mfma<<<dim3(8, 64), 256, 0, stream>>>(ylnb, Wot, out, BT, CC, CC);
}

// Round 3
// 763.215 us; speedup vs baseline: 2.4740x; 1.6014x over previous
//
#include <hip/hip_runtime.h>
#include <math.h>

// B=4, T=2048, C=1024, H=16, N=64, Q=256, nc=8, BT=8192
#define BB 4
#define TT 2048
#define CC 1024
#define HH 16
#define NN 64
#define QQ 256
#define NCH 8
#define BT 8192

typedef unsigned short u16;
typedef __attribute__((ext_vector_type(8))) short bf16x8;
typedef __attribute__((ext_vector_type(4))) short bf16x4;
typedef __attribute__((ext_vector_type(4))) float f32x4;

// f32 -> bf16 bits, round-to-nearest-even
__device__ inline u16 f2b(float x) {
  union { float f; unsigned u; } v;
  v.f = x;
  unsigned r = v.u + 0x7FFFu + ((v.u >> 16) & 1u);
  return (u16)(r >> 16);
}
__device__ inline float b2f(u16 u) {
  union { unsigned u; float f; } v;
  v.u = ((unsigned)u) << 16;
  return v.f;
}
// 16B fragment from stride-72 LDS row via two 8B loads (conflict-friendly)
__device__ inline bf16x8 ldfrag(const u16* p) {
  bf16x4 lo = *(const bf16x4*)p;
  bf16x4 hi = *(const bf16x4*)(p + 4);
  return __builtin_shufflevector(lo, hi, 0, 1, 2, 3, 4, 5, 6, 7);
}
// stage 64x64 bf16 tile (global pitch `pitch`) into LDS stride-72
__device__ inline void stage_tile(const u16* __restrict__ g, size_t base,
                                  int pitch, int tid, u16* __restrict__ lds) {
#pragma unroll
  for (int it = 0; it < 2; it++) {
    int cidx = tid + it * 256;  // 0..511
    int r = cidx >> 3, c8 = (cidx & 7) * 8;
    bf16x8 v = *(const bf16x8*)(g + base + (size_t)r * pitch + c8);
    *(bf16x4*)(lds + r * 72 + c8) = __builtin_shufflevector(v, v, 0, 1, 2, 3);
    *(bf16x4*)(lds + r * 72 + c8 + 4) = __builtin_shufflevector(v, v, 4, 5, 6, 7);
  }
}

// ---------------------------------------------------------------------------
// 1. time-shift mix
// ---------------------------------------------------------------------------
__global__ __launch_bounds__(256) void mix_kernel(const float* __restrict__ x,
                                                  const float* __restrict__ tmx,
                                                  float* __restrict__ xx,
                                                  float* __restrict__ xxx) {
  size_t i = (size_t)blockIdx.x * 256 + threadIdx.x;
  int c = (int)(i & 1023);
  size_t row = i >> 10;
  int t = (int)(row & 2047);
  float xv = x[i];
  float prev = (t > 0) ? x[i - 1024] : 0.f;
  float d = prev - xv;
  xx[i] = d;
  xxx[i] = xv + d * tmx[c];
}

// ---------------------------------------------------------------------------
// f32 tiled GEMM (maa): C = tanh(A @ B)
// ---------------------------------------------------------------------------
template <bool TANH>
__global__ __launch_bounds__(256) void gemm128(const float* __restrict__ A,
                                               const float* __restrict__ Bm,
                                               float* __restrict__ Cm,
                                               int M, int N, int K) {
  __shared__ float As[16][132];
  __shared__ float Bs[16][128];
  const int tid = threadIdx.x;
  const int row0 = blockIdx.y * 128;
  const int col0 = blockIdx.x * 128;
  const int tx = tid & 15;
  const int ty = tid >> 4;
  float acc[8][8];
#pragma unroll
  for (int i = 0; i < 8; i++)
#pragma unroll
    for (int j = 0; j < 8; j++) acc[i][j] = 0.f;

  for (int k0 = 0; k0 < K; k0 += 16) {
#pragma unroll
    for (int i = 0; i < 2; i++) {
      int idx4 = tid + i * 256;
      int k4 = idx4 & 3;
      int mm = idx4 >> 2;
      float4 av = *(const float4*)(A + (size_t)(row0 + mm) * K + k0 + k4 * 4);
      As[k4 * 4 + 0][mm] = av.x;
      As[k4 * 4 + 1][mm] = av.y;
      As[k4 * 4 + 2][mm] = av.z;
      As[k4 * 4 + 3][mm] = av.w;
      int nn4 = idx4 & 31;
      int kk2 = idx4 >> 5;
      *(float4*)&Bs[kk2][nn4 * 4] =
          *(const float4*)(Bm + (size_t)(k0 + kk2) * N + col0 + nn4 * 4);
    }
    __syncthreads();
#pragma unroll
    for (int kk = 0; kk < 16; kk++) {
      float4 a0 = *(const float4*)&As[kk][ty * 8];
      float4 a1 = *(const float4*)&As[kk][ty * 8 + 4];
      float4 b0 = *(const float4*)&Bs[kk][tx * 8];
      float4 b1 = *(const float4*)&Bs[kk][tx * 8 + 4];
      float a[8] = {a0.x, a0.y, a0.z, a0.w, a1.x, a1.y, a1.z, a1.w};
      float b[8] = {b0.x, b0.y, b0.z, b0.w, b1.x, b1.y, b1.z, b1.w};
#pragma unroll
      for (int i = 0; i < 8; i++)
#pragma unroll
        for (int j = 0; j < 8; j++) acc[i][j] += a[i] * b[j];
    }
    __syncthreads();
  }
#pragma unroll
  for (int i = 0; i < 8; i++) {
    size_t r = (size_t)(row0 + ty * 8 + i) * N + col0 + tx * 8;
#pragma unroll
    for (int j = 0; j < 8; j += 4) {
      float4 o;
      o.x = TANH ? tanhf(acc[i][j + 0]) : acc[i][j + 0];
      o.y = TANH ? tanhf(acc[i][j + 1]) : acc[i][j + 1];
      o.z = TANH ? tanhf(acc[i][j + 2]) : acc[i][j + 2];
      o.w = TANH ? tanhf(acc[i][j + 3]) : acc[i][j + 3];
      *(float4*)(Cm + r + j) = o;
    }
  }
}

// ---------------------------------------------------------------------------
// small GEMM for decay_w1 (N=64): tanh
// ---------------------------------------------------------------------------
__global__ __launch_bounds__(256) void gemm64tanh(const float* __restrict__ A,
                                                  const float* __restrict__ Bm,
                                                  float* __restrict__ Cm,
                                                  int M, int N, int K) {
  __shared__ float As[16][68];
  __shared__ float Bs[16][64];
  const int tid = threadIdx.x;
  const int row0 = blockIdx.y * 64;
  const int col0 = blockIdx.x * 64;
  const int tx = tid & 15;
  const int ty = tid >> 4;
  float acc[4][4];
#pragma unroll
  for (int i = 0; i < 4; i++)
#pragma unroll
    for (int j = 0; j < 4; j++) acc[i][j] = 0.f;

  for (int k0 = 0; k0 < K; k0 += 16) {
    {
      int k4 = tid & 3;
      int mm = tid >> 2;
      float4 av = *(const float4*)(A + (size_t)(row0 + mm) * K + k0 + k4 * 4);
      As[k4 * 4 + 0][mm] = av.x;
      As[k4 * 4 + 1][mm] = av.y;
      As[k4 * 4 + 2][mm] = av.z;
      As[k4 * 4 + 3][mm] = av.w;
      int nn4 = tid & 15;
      int kk2 = tid >> 4;
      *(float4*)&Bs[kk2][nn4 * 4] =
          *(const float4*)(Bm + (size_t)(k0 + kk2) * N + col0 + nn4 * 4);
    }
    __syncthreads();
#pragma unroll
    for (int kk = 0; kk < 16; kk++) {
      float4 a0 = *(const float4*)&As[kk][ty * 4];
      float4 b0 = *(const float4*)&Bs[kk][tx * 4];
      float a[4] = {a0.x, a0.y, a0.z, a0.w};
      float b[4] = {b0.x, b0.y, b0.z, b0.w};
#pragma unroll
      for (int i = 0; i < 4; i++)
#pragma unroll
        for (int j = 0; j < 4; j++) acc[i][j] += a[i] * b[j];
    }
    __syncthreads();
  }
#pragma unroll
  for (int i = 0; i < 4; i++) {
    float4 o;
    o.x = tanhf(acc[i][0]);
    o.y = tanhf(acc[i][1]);
    o.z = tanhf(acc[i][2]);
    o.w = tanhf(acc[i][3]);
    *(float4*)(Cm + (size_t)(row0 + ty * 4 + i) * N + col0 + tx * 4) = o;
  }
}

// ---------------------------------------------------------------------------
// weight f32[k][n] -> bf16 transposed Wt[n][k]
// ---------------------------------------------------------------------------
__global__ __launch_bounds__(256) void cvt_wT(const float* __restrict__ W0,
                                              const float* __restrict__ W1,
                                              const float* __restrict__ W2,
                                              const float* __restrict__ W3,
                                              u16* __restrict__ O0,
                                              u16* __restrict__ O1,
                                              u16* __restrict__ O2,
                                              u16* __restrict__ O3) {
  const float* W;
  u16* O;
  switch (blockIdx.z) {
    case 0: W = W0; O = O0; break;
    case 1: W = W1; O = O1; break;
    case 2: W = W2; O = O2; break;
    default: W = W3; O = O3; break;
  }
  __shared__ float t[64][65];
  int bx = blockIdx.x * 64;
  int by = blockIdx.y * 64;
#pragma unroll
  for (int it = 0; it < 16; it++) {
    int idx = it * 256 + threadIdx.x;
    int r = idx >> 6, c = idx & 63;
    t[r][c] = W[(size_t)(by + r) * 1024 + bx + c];
  }
  __syncthreads();
#pragma unroll
  for (int it = 0; it < 16; it++) {
    int idx = it * 256 + threadIdx.x;
    int n = idx >> 6, k = idx & 63;
    O[(size_t)(bx + n) * 1024 + by + k] = f2b(t[k][n]);
  }
}

// ---------------------------------------------------------------------------
// v f32 [bt][c] -> vT bf16 [(b*16+h)*64+m][2048] (per-head transposed)
// ---------------------------------------------------------------------------
__global__ __launch_bounds__(256) void vtrans_kernel(const float* __restrict__ v,
                                                     u16* __restrict__ vT) {
  int tt = blockIdx.x;  // t-tile 0..31
  int bh = blockIdx.y;  // 0..63
  int b = bh >> 4, h = bh & 15;
  __shared__ float t[64][65];
#pragma unroll
  for (int it = 0; it < 16; it++) {
    int idx = it * 256 + threadIdx.x;
    int r = idx >> 6, m = idx & 63;
    t[r][m] = v[((size_t)(b * TT + tt * 64 + r)) * CC + h * 64 + m];
  }
  __syncthreads();
#pragma unroll
  for (int it = 0; it < 16; it++) {
    int idx = it * 256 + threadIdx.x;
    int m = idx >> 6, tl = idx & 63;
    vT[((size_t)(bh * 64 + m)) * TT + tt * 64 + tl] = f2b(t[tl][m]);
  }
}

// ---------------------------------------------------------------------------
// bf16 MFMA GEMM: A[M][K] bf16, Bt[N][K] bf16, outputs f32 Cf and/or bf16 Cb
// ---------------------------------------------------------------------------
__global__ __launch_bounds__(256) void gemm_bt_mfma(const u16* __restrict__ A,
                                                    const u16* __restrict__ Bt,
                                                    float* __restrict__ Cf,
                                                    u16* __restrict__ Cb,
                                                    int M, int N, int K) {
  __shared__ u16 As[128 * 32];
  __shared__ u16 Bs[128 * 32];
  const int tid = threadIdx.x;
  const int lane = tid & 63;
  const int row0 = blockIdx.y * 128;
  const int col0 = blockIdx.x * 128;
  const int wave = tid >> 6;
  const int wr = (wave >> 1) * 64;
  const int wc = (wave & 1) * 64;
  const int fr = lane & 15;
  const int fq = lane >> 4;

  f32x4 acc[4][4];
#pragma unroll
  for (int i = 0; i < 4; i++)
#pragma unroll
    for (int j = 0; j < 4; j++) acc[i][j] = (f32x4){0.f, 0.f, 0.f, 0.f};

  const int i0 = tid, i1 = tid + 256;
  const int ra0 = i0 >> 2, ca0 = (i0 & 3) * 8;
  const int ra1 = i1 >> 2, ca1 = (i1 & 3) * 8;

  for (int k0 = 0; k0 < K; k0 += 32) {
    __builtin_amdgcn_global_load_lds(
        (const __attribute__((address_space(1))) void*)(A + (size_t)(row0 + ra0) * K + k0 + ca0),
        (__attribute__((address_space(3))) void*)(As + i0 * 8), 16, 0, 0);
    __builtin_amdgcn_global_load_lds(
        (const __attribute__((address_space(1))) void*)(A + (size_t)(row0 + ra1) * K + k0 + ca1),
        (__attribute__((address_space(3))) void*)(As + i1 * 8), 16, 0, 0);
    __builtin_amdgcn_global_load_lds(
        (const __attribute__((address_space(1))) void*)(Bt + (size_t)(col0 + ra0) * K + k0 + ca0),
        (__attribute__((address_space(3))) void*)(Bs + i0 * 8), 16, 0, 0);
    __builtin_amdgcn_global_load_lds(
        (const __attribute__((address_space(1))) void*)(Bt + (size_t)(col0 + ra1) * K + k0 + ca1),
        (__attribute__((address_space(3))) void*)(Bs + i1 * 8), 16, 0, 0);
    __syncthreads();

    bf16x8 af[4], bf[4];
#pragma unroll
    for (int i = 0; i < 4; i++)
      af[i] = *(const bf16x8*)(As + ((wr + i * 16 + fr) * 32 + fq * 8));
#pragma unroll
    for (int j = 0; j < 4; j++)
      bf[j] = *(const bf16x8*)(Bs + ((wc + j * 16 + fr) * 32 + fq * 8));
#pragma unroll
    for (int i = 0; i < 4; i++)
#pragma unroll
      for (int j = 0; j < 4; j++)
        acc[i][j] = __builtin_amdgcn_mfma_f32_16x16x32_bf16(af[i], bf[j], acc[i][j], 0, 0, 0);
    __syncthreads();
  }
#pragma unroll
  for (int i = 0; i < 4; i++) {
    int grow = row0 + wr + i * 16 + fq * 4;
#pragma unroll
    for (int j = 0; j < 4; j++) {
      int gcol = col0 + wc + j * 16 + fr;
#pragma unroll
      for (int r = 0; r < 4; r++) {
        if (Cf) Cf[(size_t)(grow + r) * N + gcol] = acc[i][j][r];
        if (Cb) Cb[(size_t)(grow + r) * N + gcol] = f2b(acc[i][j][r]);
      }
    }
  }
}

// ---------------------------------------------------------------------------
// 3. blend
// ---------------------------------------------------------------------------
__global__ __launch_bounds__(256) void blend_kernel(
    const float* __restrict__ x, const float* __restrict__ xx,
    const float* __restrict__ m, const float* __restrict__ tmw,
    const float* __restrict__ tmk, const float* __restrict__ tmv,
    const float* __restrict__ tmr, const float* __restrict__ w2,
    float* __restrict__ xw, u16* __restrict__ xkb, u16* __restrict__ xvb,
    u16* __restrict__ xrb) {
  int bt = blockIdx.x;
  __shared__ float ms[128];
  if (threadIdx.x < 128) ms[threadIdx.x] = m[(size_t)bt * 128 + threadIdx.x];
  __syncthreads();
  for (int c = threadIdx.x; c < 1024; c += 256) {
    float a0 = 0.f, a1 = 0.f, a2 = 0.f, a3 = 0.f;
#pragma unroll 8
    for (int d = 0; d < 32; d++) {
      a0 += ms[d] * w2[(size_t)d * 1024 + c];
      a1 += ms[32 + d] * w2[(size_t)(32 + d) * 1024 + c];
      a2 += ms[64 + d] * w2[(size_t)(64 + d) * 1024 + c];
      a3 += ms[96 + d] * w2[(size_t)(96 + d) * 1024 + c];
    }
    size_t g = (size_t)bt * 1024 + c;
    float xv_ = x[g], dx = xx[g];
    xw[g] = xv_ + dx * (tmw[c] + a0);
    xkb[g] = f2b(xv_ + dx * (tmk[c] + a1));
    xvb[g] = f2b(xv_ + dx * (tmv[c] + a2));
    xrb[g] = f2b(xv_ + dx * (tmr[c] + a3));
  }
}

// ---------------------------------------------------------------------------
// 5a/5b: decay reduce + wlog
// ---------------------------------------------------------------------------
__global__ __launch_bounds__(256) void dw2r_kernel(const float* __restrict__ dw2,
                                                   const float* __restrict__ td,
                                                   float* __restrict__ dw2r,
                                                   float* __restrict__ tdr) {
  int idx = blockIdx.x * 256 + threadIdx.x;
  if (idx < 1024) {
    int j = idx >> 4, h = idx & 15;
    float s = 0.f;
    for (int n = 0; n < 64; n++) s += dw2[(size_t)j * 1024 + h * 64 + n];
    dw2r[j * 16 + h] = s * (1.f / 64.f);
  }
  if (idx < 16) {
    float s = 0.f;
    for (int n = 0; n < 64; n++) s += td[idx * 64 + n];
    tdr[idx] = s * (1.f / 64.f);
  }
}

__global__ __launch_bounds__(256) void wred_kernel(const float* __restrict__ h1,
                                                   const float* __restrict__ dw2r,
                                                   const float* __restrict__ tdr,
                                                   float* __restrict__ wlog) {
  int idx = blockIdx.x * 256 + threadIdx.x;
  int bt = idx >> 4, h = idx & 15;
  float s = tdr[h];
  const float* hrow = h1 + (size_t)bt * 64;
#pragma unroll 8
  for (int j = 0; j < 64; j++) s += hrow[j] * dw2r[j * 16 + h];
  int b = bt >> 11, t = bt & 2047;
  wlog[((size_t)(b * 16 + h)) * 2048 + t] = -expf(s);
}

// ---------------------------------------------------------------------------
// 7. per-chunk scan
// ---------------------------------------------------------------------------
__global__ __launch_bounds__(256) void wprep_kernel(const float* __restrict__ wlog,
                                                    float* __restrict__ cum,
                                                    float* __restrict__ excl,
                                                    float* __restrict__ wsl) {
  int bid = blockIdx.x;
  int c = bid & 7, bh = bid >> 3;
  int q = threadIdx.x;
  float v = wlog[(size_t)bh * 2048 + c * 256 + q];
  __shared__ float s[256];
  s[q] = v;
  float val = v;
  for (int off = 1; off < 256; off <<= 1) {
    __syncthreads();
    float t = (q >= off) ? s[q - off] : 0.f;
    __syncthreads();
    val += t;
    s[q] = val;
  }
  __syncthreads();
  float total = s[255];
  cum[(size_t)bid * 256 + q] = val;
  excl[(size_t)bid * 256 + q] = val - v;
  if (q == 0) wsl[bid] = total;
}

// ---------------------------------------------------------------------------
// 8a. kv per chunk (f32, unchanged)
// ---------------------------------------------------------------------------
__global__ __launch_bounds__(256) void kv_kernel(const float* __restrict__ kg,
                                                 const float* __restrict__ vg,
                                                 const float* __restrict__ cum,
                                                 const float* __restrict__ wsl,
                                                 float* __restrict__ kvb) {
  int bid = blockIdx.x;
  int c = bid & 7, bh = bid >> 3;
  int b = bh >> 4, h = bh & 15;
  __shared__ float kw[64][65];
  __shared__ float vs[64][65];
  float wslog = wsl[bid];
  int n_ = threadIdx.x >> 2;
  int m0 = (threadIdx.x & 3) * 16;
  float acc[16];
#pragma unroll
  for (int j = 0; j < 16; j++) acc[j] = 0.f;

  for (int qt = 0; qt < 4; qt++) {
    __syncthreads();
#pragma unroll
    for (int i = 0; i < 16; i++) {
      int idx = threadIdx.x + i * 256;
      int qq = idx >> 6, nn = idx & 63;
      int q = qt * 64 + qq;
      size_t g = ((size_t)(b * TT + c * QQ + q)) * CC + h * 64 + nn;
      float wi = __expf(wslog - cum[(size_t)bid * 256 + q]);
      kw[qq][nn] = kg[g] * wi;
      vs[qq][nn] = vg[g];
    }
    __syncthreads();
    for (int qq = 0; qq < 64; qq++) {
      float a = kw[qq][n_];
#pragma unroll
      for (int j = 0; j < 16; j++) acc[j] += a * vs[qq][m0 + j];
    }
  }
#pragma unroll
  for (int j = 0; j < 16; j++)
    kvb[(size_t)bid * 4096 + n_ * 64 + m0 + j] = acc[j];
}

// ---------------------------------------------------------------------------
// 8b. sequential state scan over chunks
// ---------------------------------------------------------------------------
__global__ __launch_bounds__(256) void scan_kernel(const float* __restrict__ kvb,
                                                   const float* __restrict__ wsl,
                                                   float* __restrict__ st) {
  int bh = blockIdx.x;
  int tid = threadIdx.x;
  float s[16];
#pragma unroll
  for (int i = 0; i < 16; i++) s[i] = 0.f;
  for (int c = 0; c < 8; c++) {
    int bid = bh * 8 + c;
    float w = __expf(wsl[bid]);
#pragma unroll
    for (int i = 0; i < 16; i++) {
      size_t e = (size_t)bid * 4096 + i * 256 + tid;
      st[e] = s[i];
      s[i] = w * s[i] + kvb[e];
    }
  }
}

// ---------------------------------------------------------------------------
// 9. MFMA fused attention.
// block=(b,h,chunk), 256 thr = 4 waves; q-tiles of 64 (wave w -> 16 q rows).
// S = r@k^T (MFMA) -> f32 mask epilogue (diag spliced as P[q][q]=r.(fa*k))
// -> P bf16 -> P@V (MFMA, V^T tiles) ; inter = r@state^T (MFMA) * exp(excl).
// LDS tiles stride-72 u16 rows: dual ds_read_b64 fragments, ~2-way banks.
// ---------------------------------------------------------------------------
__global__ __launch_bounds__(256) void attn_mfma(
    const u16* __restrict__ rb, const u16* __restrict__ kb,
    const u16* __restrict__ vT, const float* __restrict__ stg,
    const float* __restrict__ cum, const float* __restrict__ excl,
    const float* __restrict__ faaaa, float* __restrict__ y) {
  int bid = blockIdx.x;
  int c = bid & 7, bh = bid >> 3;
  int b = bh >> 4, h = bh & 15;
  __shared__ u16 rt[64 * 72];
  __shared__ u16 kt[64 * 72];
  __shared__ u16 vt[64 * 72];
  __shared__ u16 pt[64 * 72];
  __shared__ u16 stT[64 * 72];
  __shared__ float cumS[256], exS[256], faS[64], diagS[64];

  const int tid = threadIdx.x;
  const int lane = tid & 63;
  const int w = tid >> 6;
  const int fr = lane & 15;
  const int fq = lane >> 4;

  cumS[tid] = cum[(size_t)bid * 256 + tid];
  exS[tid] = excl[(size_t)bid * 256 + tid];
  if (tid < 64) faS[tid] = faaaa[h * 64 + tid];
#pragma unroll
  for (int it = 0; it < 16; it++) {
    int idx = tid + it * 256;  // 4096
    int n = idx >> 6, mm = idx & 63;
    stT[mm * 72 + n] = f2b(stg[(size_t)bid * 4096 + idx]);  // [m][n]
  }

  const size_t rowbase = ((size_t)b * TT + c * QQ) * CC + h * 64;  // +t*1024+n
  const size_t vbase0 = (size_t)bh * 64 * TT + c * QQ;             // +m*2048+t

  for (int qt = 0; qt < 4; qt++) {
    __syncthreads();  // previous q-tile fully consumed (incl. stT init at qt=0)
    stage_tile(rb, rowbase + (size_t)(qt * 64) * CC, CC, tid, rt);
    __syncthreads();

    // inter = (r @ state^T-frags) scaled by exp(excl[q])
    f32x4 acc[4];
#pragma unroll
    for (int jm = 0; jm < 4; jm++) acc[jm] = (f32x4){0.f, 0.f, 0.f, 0.f};
    bf16x8 rA[2];
    rA[0] = ldfrag(rt + (w * 16 + fr) * 72 + fq * 8);
    rA[1] = ldfrag(rt + (w * 16 + fr) * 72 + 32 + fq * 8);
#pragma unroll
    for (int ks = 0; ks < 2; ks++)
#pragma unroll
      for (int jm = 0; jm < 4; jm++) {
        bf16x8 bB = ldfrag(stT + (jm * 16 + fr) * 72 + ks * 32 + fq * 8);
        acc[jm] = __builtin_amdgcn_mfma_f32_16x16x32_bf16(rA[ks], bB, acc[jm], 0, 0, 0);
      }
    float er[4];
#pragma unroll
    for (int rr = 0; rr < 4; rr++)
      er[rr] = __expf(exS[qt * 64 + w * 16 + fq * 4 + rr]);
#pragma unroll
    for (int jm = 0; jm < 4; jm++)
#pragma unroll
      for (int rr = 0; rr < 4; rr++) acc[jm][rr] *= er[rr];

    for (int kti = 0; kti <= qt; kti++) {
      __syncthreads();  // kt/vt/pt consumers of previous iteration done
      stage_tile(kb, rowbase + (size_t)(kti * 64) * CC, CC, tid, kt);
      stage_tile(vT, vbase0 + (size_t)(kti * 64), TT, tid, vt);
      __syncthreads();

      if (kti == qt) {  // diag[q] = sum_n r[q][n]*fa[n]*k[q][n]
        int dq = tid >> 2, seg = tid & 3;
        float s = 0.f;
#pragma unroll
        for (int i = 0; i < 16; i++) {
          int n = seg * 16 + i;
          s += b2f(rt[dq * 72 + n]) * faS[n] * b2f(kt[dq * 72 + n]);
        }
        s += __shfl_xor(s, 1);
        s += __shfl_xor(s, 2);
        if (seg == 0) diagS[dq] = s;
        __syncthreads();
      }

      // S = r @ k^T
      f32x4 sacc[4];
#pragma unroll
      for (int jj = 0; jj < 4; jj++) sacc[jj] = (f32x4){0.f, 0.f, 0.f, 0.f};
#pragma unroll
      for (int ks = 0; ks < 2; ks++)
#pragma unroll
        for (int jj = 0; jj < 4; jj++) {
          bf16x8 bB = ldfrag(kt + (jj * 16 + fr) * 72 + ks * 32 + fq * 8);
          sacc[jj] = __builtin_amdgcn_mfma_f32_16x16x32_bf16(rA[ks], bB, sacc[jj], 0, 0, 0);
        }
      // mask epilogue -> P (bf16)
      int ql0 = w * 16 + fq * 4;  // q-local in q-tile
#pragma unroll
      for (int jj = 0; jj < 4; jj++) {
        int kcol = kti * 64 + jj * 16 + fr;  // chunk-local k
        float ck = cumS[kcol];
#pragma unroll
        for (int rr = 0; rr < 4; rr++) {
          int qrow = qt * 64 + ql0 + rr;  // chunk-local q
          float vsc;
          if (kcol < qrow)
            vsc = sacc[jj][rr] * __expf(exS[qrow] - ck);
          else if (kcol == qrow)
            vsc = diagS[ql0 + rr];
          else
            vsc = 0.f;
          pt[(ql0 + rr) * 72 + jj * 16 + fr] = f2b(vsc);
        }
      }
      __syncthreads();  // pt ready
      // O += P @ V  (B-frags from V^T tile)
#pragma unroll
      for (int ks = 0; ks < 2; ks++) {
        bf16x8 pA = ldfrag(pt + (w * 16 + fr) * 72 + ks * 32 + fq * 8);
#pragma unroll
        for (int jm = 0; jm < 4; jm++) {
          bf16x8 vB = ldfrag(vt + (jm * 16 + fr) * 72 + ks * 32 + fq * 8);
          acc[jm] = __builtin_amdgcn_mfma_f32_16x16x32_bf16(pA, vB, acc[jm], 0, 0, 0);
        }
      }
    }
    // write O tiles: D row = fq*4+rr, col = fr
    int qg0 = qt * 64 + w * 16 + fq * 4;
#pragma unroll
    for (int jm = 0; jm < 4; jm++)
#pragma unroll
      for (int rr = 0; rr < 4; rr++)
        y[rowbase + (size_t)(qg0 + rr) * CC + jm * 16 + fr] = acc[jm][rr];
  }
}

// ---------------------------------------------------------------------------
// 10. LayerNorm over C -> bf16
// ---------------------------------------------------------------------------
__global__ __launch_bounds__(256) void ln_kernel(const float* __restrict__ y,
                                                 const float* __restrict__ g,
                                                 const float* __restrict__ bta,
                                                 u16* __restrict__ out) {
  __shared__ float red[8];
  int bt = blockIdx.x;
  int tid = threadIdx.x;
  float v[4];
  float s = 0.f;
#pragma unroll
  for (int i = 0; i < 4; i++) {
    v[i] = y[(size_t)bt * 1024 + i * 256 + tid];
    s += v[i];
  }
#pragma unroll
  for (int off = 32; off > 0; off >>= 1) s += __shfl_down(s, off);
  if ((tid & 63) == 0) red[tid >> 6] = s;
  __syncthreads();
  if (tid == 0) red[4] = red[0] + red[1] + red[2] + red[3];
  __syncthreads();
  float mu = red[4] * (1.f / 1024.f);
  float s2 = 0.f;
#pragma unroll
  for (int i = 0; i < 4; i++) {
    float d = v[i] - mu;
    s2 += d * d;
  }
#pragma unroll
  for (int off = 32; off > 0; off >>= 1) s2 += __shfl_down(s2, off);
  __syncthreads();
  if ((tid & 63) == 0) red[tid >> 6] = s2;
  __syncthreads();
  if (tid == 0) red[5] = red[0] + red[1] + red[2] + red[3];
  __syncthreads();
  float var = red[5] * (1.f / 1024.f);
  float rstd = rsqrtf(var + 1e-5f);
#pragma unroll
  for (int i = 0; i < 4; i++) {
    int c = i * 256 + tid;
    out[(size_t)bt * 1024 + c] = f2b((v[i] - mu) * rstd * g[c] + bta[c]);
  }
}

// ---------------------------------------------------------------------------
extern "C" void kernel_launch(void* const* d_in, const int* in_sizes, int n_in,
                              void* d_out, int out_size, void* d_ws,
                              size_t ws_size, hipStream_t stream) {
  const float* x = (const float*)d_in[0];
  const float* tmx = (const float*)d_in[1];
  const float* tmw = (const float*)d_in[2];
  const float* tmk = (const float*)d_in[3];
  const float* tmv = (const float*)d_in[4];
  const float* tmr = (const float*)d_in[5];
  const float* maa_w1 = (const float*)d_in[6];
  const float* maa_w2 = (const float*)d_in[7];
  const float* decay_w1 = (const float*)d_in[8];
  const float* decay_w2 = (const float*)d_in[9];
  const float* time_decay = (const float*)d_in[10];
  const float* faaaa = (const float*)d_in[11];
  const float* Wr = (const float*)d_in[12];
  const float* Wk = (const float*)d_in[13];
  const float* Wv = (const float*)d_in[14];
  const float* Wo = (const float*)d_in[15];
  const float* lng = (const float*)d_in[16];
  const float* lnb = (const float*)d_in[17];
  float* out = (float*)d_out;
  float* ws = (float*)d_ws;

  const size_t S = (size_t)BT * CC;  // 8388608

  // f32 region
  float* xx = ws;                       // mix out; blend in; then y_ (attn out)
  float* xxx = ws + S;                  // xxx -> xw -> k_ (f32)
  float* v_ = ws + 2 * S;               // v f32 (kv + transpose source)
  float* m = ws + 3 * S;                // BT*128
  float* h1 = m + (size_t)BT * 128;     // BT*64
  float* dw2r = h1 + (size_t)BT * 64;   // 1024
  float* tdr = dw2r + 1024;
  float* wlog = tdr + 1024;             // 131072
  float* cum = wlog + 131072;
  float* excl = cum + 131072;
  float* wsl = excl + 131072;
  float* kvb = wsl + 1024;              // 512*4096
  float* stb = kvb + (size_t)512 * 4096;
  float* fend = stb + (size_t)512 * 4096;
  // bf16 region (aggressively reused)
  u16* xrb = (u16*)fend;  // blend out -> r-GEMM in -> vTg (transpose out)
  u16* xkb = xrb + S;     // blend out -> k-GEMM in -> rb16 -> ylnb
  u16* xvb = xkb + S;     // blend out -> v-GEMM in -> kb16
  u16* Wrt = xvb + S;
  u16* Wkt = Wrt + (size_t)1024 * 1024;
  u16* Wvt = Wkt + (size_t)1024 * 1024;
  u16* Wot = Wvt + (size_t)1024 * 1024;
  // aliases
  float* xw = xxx;
  float* k_ = xxx;
  u16* kb16 = xvb;   // after v-GEMM consumed xvb
  u16* rb16 = xkb;   // after k-GEMM consumed xkb
  u16* vTg = xrb;    // after r-GEMM consumed xrb
  float* y_ = xx;    // after blend consumed xx (r f32 no longer produced)
  u16* ylnb = xkb;   // after attn consumed rb16

  cvt_wT<<<dim3(16, 16, 4), 256, 0, stream>>>(Wr, Wk, Wv, Wo, Wrt, Wkt, Wvt, Wot);
  mix_kernel<<<32768, 256, 0, stream>>>(x, tmx, xx, xxx);
  gemm128<true><<<dim3(1, 64), 256, 0, stream>>>(xxx, maa_w1, m, BT, 128, CC);
  blend_kernel<<<BT, 256, 0, stream>>>(x, xx, m, tmw, tmk, tmv, tmr, maa_w2,
                                       xw, xkb, xvb, xrb);
  gemm64tanh<<<dim3(1, 128), 256, 0, stream>>>(xw, decay_w1, h1, BT, 64, CC);
  dw2r_kernel<<<4, 256, 0, stream>>>(decay_w2, time_decay, dw2r, tdr);
  wred_kernel<<<512, 256, 0, stream>>>(h1, dw2r, tdr, wlog);
  wprep_kernel<<<512, 256, 0, stream>>>(wlog, cum, excl, wsl);
  // order matters for buffer reuse: v -> k -> r -> transpose
  gemm_bt_mfma<<<dim3(8, 64), 256, 0, stream>>>(xvb, Wvt, v_, nullptr, BT, CC, CC);
  gemm_bt_mfma<<<dim3(8, 64), 256, 0, stream>>>(xkb, Wkt, k_, kb16, BT, CC, CC);
  gemm_bt_mfma<<<dim3(8, 64), 256, 0, stream>>>(xrb, Wrt, nullptr, rb16, BT, CC, CC);
  vtrans_kernel<<<dim3(32, 64), 256, 0, stream>>>(v_, vTg);
  kv_kernel<<<512, 256, 0, stream>>>(k_, v_, cum, wsl, kvb);
  scan_kernel<<<64, 256, 0, stream>>>(kvb, wsl, stb);
  attn_mfma<<<512, 256, 0, stream>>>(rb16, kb16, vTg, stb, cum, excl, faaaa, y_);
  ln_kernel<<<BT, 256, 0, stream>>>(y_, lng, lnb, ylnb);
  gemm_bt_mfma<<<dim3(8, 64), 256, 0, stream>>>(ylnb, Wot, out, nullptr, BT, CC, CC);
}

// Round 4
// 487.804 us; speedup vs baseline: 3.8708x; 1.5646x over previous
//
#include <hip/hip_runtime.h>
#include <math.h>

// B=4, T=2048, C=1024, H=16, N=64, Q=256, nc=8, BT=8192
#define BB 4
#define TT 2048
#define CC 1024
#define HH 16
#define NN 64
#define QQ 256
#define NCH 8
#define BT 8192

typedef unsigned short u16;
typedef __attribute__((ext_vector_type(8))) short bf16x8;
typedef __attribute__((ext_vector_type(4))) short bf16x4;
typedef __attribute__((ext_vector_type(4))) float f32x4;
typedef __attribute__((ext_vector_type(4))) u16 u16x4;

// f32 -> bf16 bits, round-to-nearest-even
__device__ inline u16 f2b(float x) {
  union { float f; unsigned u; } v;
  v.f = x;
  unsigned r = v.u + 0x7FFFu + ((v.u >> 16) & 1u);
  return (u16)(r >> 16);
}
__device__ inline float b2f(u16 u) {
  union { unsigned u; float f; } v;
  v.u = ((unsigned)u) << 16;
  return v.f;
}
// 16B fragment from padded LDS row via two 8B loads (conflict-friendly)
__device__ inline bf16x8 ldfrag(const u16* p) {
  bf16x4 lo = *(const bf16x4*)p;
  bf16x4 hi = *(const bf16x4*)(p + 4);
  return __builtin_shufflevector(lo, hi, 0, 1, 2, 3, 4, 5, 6, 7);
}
// stage 64x64 bf16 tile (global pitch `pitch` u16) into LDS stride-72
__device__ inline void stage_tile(const u16* __restrict__ g, size_t base,
                                  int pitch, int tid, u16* __restrict__ lds) {
#pragma unroll
  for (int it = 0; it < 2; it++) {
    int cidx = tid + it * 256;  // 0..511
    int r = cidx >> 3, c8 = (cidx & 7) * 8;
    bf16x8 v = *(const bf16x8*)(g + base + (size_t)r * pitch + c8);
    *(bf16x4*)(lds + r * 72 + c8) = __builtin_shufflevector(v, v, 0, 1, 2, 3);
    *(bf16x4*)(lds + r * 72 + c8 + 4) = __builtin_shufflevector(v, v, 4, 5, 6, 7);
  }
}

// ---------------------------------------------------------------------------
// 1. time-shift mix: xx f32, xxx -> bf16 (feeds maa MFMA GEMM). float4 path.
// ---------------------------------------------------------------------------
__global__ __launch_bounds__(256) void mix_kernel(const float* __restrict__ x,
                                                  const float* __restrict__ tmx,
                                                  float* __restrict__ xx,
                                                  u16* __restrict__ xxxb) {
  size_t e = ((size_t)blockIdx.x * 256 + threadIdx.x) * 4;
  int c = (int)(e & 1023);
  size_t row = e >> 10;
  int t = (int)(row & 2047);
  float4 xv = *(const float4*)(x + e);
  float4 pv = make_float4(0.f, 0.f, 0.f, 0.f);
  if (t > 0) pv = *(const float4*)(x + e - 1024);
  float4 d = make_float4(pv.x - xv.x, pv.y - xv.y, pv.z - xv.z, pv.w - xv.w);
  *(float4*)(xx + e) = d;
  u16x4 o;
  o.x = f2b(xv.x + d.x * tmx[c + 0]);
  o.y = f2b(xv.y + d.y * tmx[c + 1]);
  o.z = f2b(xv.z + d.z * tmx[c + 2]);
  o.w = f2b(xv.w + d.w * tmx[c + 3]);
  *(u16x4*)(xxxb + e) = o;
}

// ---------------------------------------------------------------------------
// small f32 GEMM for decay_w1 (N=64): tanh
// ---------------------------------------------------------------------------
__global__ __launch_bounds__(256) void gemm64tanh(const float* __restrict__ A,
                                                  const float* __restrict__ Bm,
                                                  float* __restrict__ Cm,
                                                  int M, int N, int K) {
  __shared__ float As[16][68];
  __shared__ float Bs[16][64];
  const int tid = threadIdx.x;
  const int row0 = blockIdx.y * 64;
  const int col0 = blockIdx.x * 64;
  const int tx = tid & 15;
  const int ty = tid >> 4;
  float acc[4][4];
#pragma unroll
  for (int i = 0; i < 4; i++)
#pragma unroll
    for (int j = 0; j < 4; j++) acc[i][j] = 0.f;

  for (int k0 = 0; k0 < K; k0 += 16) {
    {
      int k4 = tid & 3;
      int mm = tid >> 2;
      float4 av = *(const float4*)(A + (size_t)(row0 + mm) * K + k0 + k4 * 4);
      As[k4 * 4 + 0][mm] = av.x;
      As[k4 * 4 + 1][mm] = av.y;
      As[k4 * 4 + 2][mm] = av.z;
      As[k4 * 4 + 3][mm] = av.w;
      int nn4 = tid & 15;
      int kk2 = tid >> 4;
      *(float4*)&Bs[kk2][nn4 * 4] =
          *(const float4*)(Bm + (size_t)(k0 + kk2) * N + col0 + nn4 * 4);
    }
    __syncthreads();
#pragma unroll
    for (int kk = 0; kk < 16; kk++) {
      float4 a0 = *(const float4*)&As[kk][ty * 4];
      float4 b0 = *(const float4*)&Bs[kk][tx * 4];
      float a[4] = {a0.x, a0.y, a0.z, a0.w};
      float b[4] = {b0.x, b0.y, b0.z, b0.w};
#pragma unroll
      for (int i = 0; i < 4; i++)
#pragma unroll
        for (int j = 0; j < 4; j++) acc[i][j] += a[i] * b[j];
    }
    __syncthreads();
  }
#pragma unroll
  for (int i = 0; i < 4; i++) {
    float4 o;
    o.x = tanhf(acc[i][0]);
    o.y = tanhf(acc[i][1]);
    o.z = tanhf(acc[i][2]);
    o.w = tanhf(acc[i][3]);
    *(float4*)(Cm + (size_t)(row0 + ty * 4 + i) * N + col0 + tx * 4) = o;
  }
}

// ---------------------------------------------------------------------------
// weight f32[k][n] (1024x1024) -> bf16 transposed Wt[n][k]
// ---------------------------------------------------------------------------
__global__ __launch_bounds__(256) void cvt_wT(const float* __restrict__ W0,
                                              const float* __restrict__ W1,
                                              const float* __restrict__ W2,
                                              const float* __restrict__ W3,
                                              u16* __restrict__ O0,
                                              u16* __restrict__ O1,
                                              u16* __restrict__ O2,
                                              u16* __restrict__ O3) {
  const float* W;
  u16* O;
  switch (blockIdx.z) {
    case 0: W = W0; O = O0; break;
    case 1: W = W1; O = O1; break;
    case 2: W = W2; O = O2; break;
    default: W = W3; O = O3; break;
  }
  __shared__ float t[64][65];
  int bx = blockIdx.x * 64;
  int by = blockIdx.y * 64;
#pragma unroll
  for (int it = 0; it < 16; it++) {
    int idx = it * 256 + threadIdx.x;
    int r = idx >> 6, c = idx & 63;
    t[r][c] = W[(size_t)(by + r) * 1024 + bx + c];
  }
  __syncthreads();
#pragma unroll
  for (int it = 0; it < 16; it++) {
    int idx = it * 256 + threadIdx.x;
    int n = idx >> 6, k = idx & 63;
    O[(size_t)(bx + n) * 1024 + by + k] = f2b(t[k][n]);
  }
}

// ---------------------------------------------------------------------------
// generic transpose+cvt: in f32 [R][C] -> out bf16 [C][R]  (R,C mult of 64)
// ---------------------------------------------------------------------------
__global__ __launch_bounds__(256) void cvt_T(const float* __restrict__ in,
                                             u16* __restrict__ out, int R, int C) {
  __shared__ float t[64][65];
  int c0 = blockIdx.x * 64, r0 = blockIdx.y * 64;
#pragma unroll
  for (int it = 0; it < 16; it++) {
    int idx = it * 256 + threadIdx.x;
    int r = idx >> 6, c = idx & 63;
    t[r][c] = in[(size_t)(r0 + r) * C + c0 + c];
  }
  __syncthreads();
#pragma unroll
  for (int it = 0; it < 16; it++) {
    int idx = it * 256 + threadIdx.x;
    int c = idx >> 6, r = idx & 63;
    out[(size_t)(c0 + c) * R + r0 + r] = f2b(t[r][c]);
  }
}

// ---------------------------------------------------------------------------
// bf16 MFMA GEMM (m97): A[M][K], Bt[N][K]; out f32 Cf and/or bf16 Cb (opt tanh)
// ---------------------------------------------------------------------------
template <bool TANH>
__global__ __launch_bounds__(256) void gemm_bt_mfma(const u16* __restrict__ A,
                                                    const u16* __restrict__ Bt,
                                                    float* __restrict__ Cf,
                                                    u16* __restrict__ Cb,
                                                    int M, int N, int K) {
  __shared__ u16 As[128 * 32];
  __shared__ u16 Bs[128 * 32];
  const int tid = threadIdx.x;
  const int lane = tid & 63;
  const int row0 = blockIdx.y * 128;
  const int col0 = blockIdx.x * 128;
  const int wave = tid >> 6;
  const int wr = (wave >> 1) * 64;
  const int wc = (wave & 1) * 64;
  const int fr = lane & 15;
  const int fq = lane >> 4;

  f32x4 acc[4][4];
#pragma unroll
  for (int i = 0; i < 4; i++)
#pragma unroll
    for (int j = 0; j < 4; j++) acc[i][j] = (f32x4){0.f, 0.f, 0.f, 0.f};

  const int i0 = tid, i1 = tid + 256;
  const int ra0 = i0 >> 2, ca0 = (i0 & 3) * 8;
  const int ra1 = i1 >> 2, ca1 = (i1 & 3) * 8;

  for (int k0 = 0; k0 < K; k0 += 32) {
    __builtin_amdgcn_global_load_lds(
        (const __attribute__((address_space(1))) void*)(A + (size_t)(row0 + ra0) * K + k0 + ca0),
        (__attribute__((address_space(3))) void*)(As + i0 * 8), 16, 0, 0);
    __builtin_amdgcn_global_load_lds(
        (const __attribute__((address_space(1))) void*)(A + (size_t)(row0 + ra1) * K + k0 + ca1),
        (__attribute__((address_space(3))) void*)(As + i1 * 8), 16, 0, 0);
    __builtin_amdgcn_global_load_lds(
        (const __attribute__((address_space(1))) void*)(Bt + (size_t)(col0 + ra0) * K + k0 + ca0),
        (__attribute__((address_space(3))) void*)(Bs + i0 * 8), 16, 0, 0);
    __builtin_amdgcn_global_load_lds(
        (const __attribute__((address_space(1))) void*)(Bt + (size_t)(col0 + ra1) * K + k0 + ca1),
        (__attribute__((address_space(3))) void*)(Bs + i1 * 8), 16, 0, 0);
    __syncthreads();

    bf16x8 af[4], bf[4];
#pragma unroll
    for (int i = 0; i < 4; i++)
      af[i] = *(const bf16x8*)(As + ((wr + i * 16 + fr) * 32 + fq * 8));
#pragma unroll
    for (int j = 0; j < 4; j++)
      bf[j] = *(const bf16x8*)(Bs + ((wc + j * 16 + fr) * 32 + fq * 8));
#pragma unroll
    for (int i = 0; i < 4; i++)
#pragma unroll
      for (int j = 0; j < 4; j++)
        acc[i][j] = __builtin_amdgcn_mfma_f32_16x16x32_bf16(af[i], bf[j], acc[i][j], 0, 0, 0);
    __syncthreads();
  }
#pragma unroll
  for (int i = 0; i < 4; i++) {
    int grow = row0 + wr + i * 16 + fq * 4;
#pragma unroll
    for (int j = 0; j < 4; j++) {
      int gcol = col0 + wc + j * 16 + fr;
#pragma unroll
      for (int r = 0; r < 4; r++) {
        float vv = acc[i][j][r];
        if (TANH) vv = tanhf(vv);
        if (Cf) Cf[(size_t)(grow + r) * N + gcol] = vv;
        if (Cb) Cb[(size_t)(grow + r) * N + gcol] = f2b(vv);
      }
    }
  }
}

// ---------------------------------------------------------------------------
// 3. blend via MFMA: m[8192][128] bf16 (4 f-slices of K=32) @ w2T[1024][128]
// block = 64 bt x 64 c; one MFMA per (col-tile, f). Fused x/xx/tm* epilogue.
// ---------------------------------------------------------------------------
__global__ __launch_bounds__(256) void blend_mfma(
    const u16* __restrict__ mb, const u16* __restrict__ w2T,
    const float* __restrict__ x, const float* __restrict__ xx,
    const float* __restrict__ tmw, const float* __restrict__ tmk,
    const float* __restrict__ tmv, const float* __restrict__ tmr,
    float* __restrict__ xw, u16* __restrict__ xkb, u16* __restrict__ xvb,
    u16* __restrict__ xrb) {
  __shared__ u16 mS[64 * 136];
  __shared__ u16 wS[64 * 136];
  const int tid = threadIdx.x;
  const int lane = tid & 63;
  const int w = tid >> 6;
  const int fr = lane & 15;
  const int fq = lane >> 4;
  const int c0 = blockIdx.x * 64;
  const int bt0 = blockIdx.y * 64;

  // stage m-tile [64][128] and w2T-slab [64][128]
#pragma unroll
  for (int it = 0; it < 4; it++) {
    int idx = tid + it * 256;  // 0..1023
    int r = idx >> 4, c8 = (idx & 15) * 8;
    bf16x8 v = *(const bf16x8*)(mb + (size_t)(bt0 + r) * 128 + c8);
    *(bf16x4*)(mS + r * 136 + c8) = __builtin_shufflevector(v, v, 0, 1, 2, 3);
    *(bf16x4*)(mS + r * 136 + c8 + 4) = __builtin_shufflevector(v, v, 4, 5, 6, 7);
    bf16x8 u = *(const bf16x8*)(w2T + (size_t)(c0 + r) * 128 + c8);
    *(bf16x4*)(wS + r * 136 + c8) = __builtin_shufflevector(u, u, 0, 1, 2, 3);
    *(bf16x4*)(wS + r * 136 + c8 + 4) = __builtin_shufflevector(u, u, 4, 5, 6, 7);
  }
  __syncthreads();

  f32x4 acc[4][4];  // [col-tile j][f]
#pragma unroll
  for (int j = 0; j < 4; j++)
#pragma unroll
    for (int f = 0; f < 4; f++) acc[j][f] = (f32x4){0.f, 0.f, 0.f, 0.f};

#pragma unroll
  for (int f = 0; f < 4; f++) {
    bf16x8 aA = ldfrag(mS + (w * 16 + fr) * 136 + f * 32 + fq * 8);
#pragma unroll
    for (int j = 0; j < 4; j++) {
      bf16x8 bB = ldfrag(wS + (j * 16 + fr) * 136 + f * 32 + fq * 8);
      acc[j][f] = __builtin_amdgcn_mfma_f32_16x16x32_bf16(aA, bB, acc[j][f], 0, 0, 0);
    }
  }

  // epilogue: D row = fq*4+rr (bt-local), col = fr (c-local 16 within j)
#pragma unroll
  for (int j = 0; j < 4; j++) {
    int c = c0 + j * 16 + fr;
    float w_ = tmw[c], k_ = tmk[c], v_ = tmv[c], r_ = tmr[c];
#pragma unroll
    for (int rr = 0; rr < 4; rr++) {
      int bt = bt0 + w * 16 + fq * 4 + rr;
      size_t g = (size_t)bt * 1024 + c;
      float xv_ = x[g], dx = xx[g];
      xw[g] = xv_ + dx * (w_ + acc[j][0][rr]);
      xkb[g] = f2b(xv_ + dx * (k_ + acc[j][1][rr]));
      xvb[g] = f2b(xv_ + dx * (v_ + acc[j][2][rr]));
      xrb[g] = f2b(xv_ + dx * (r_ + acc[j][3][rr]));
    }
  }
}

// ---------------------------------------------------------------------------
// 5a/5b: decay reduce + wlog
// ---------------------------------------------------------------------------
__global__ __launch_bounds__(256) void dw2r_kernel(const float* __restrict__ dw2,
                                                   const float* __restrict__ td,
                                                   float* __restrict__ dw2r,
                                                   float* __restrict__ tdr) {
  int idx = blockIdx.x * 256 + threadIdx.x;
  if (idx < 1024) {
    int j = idx >> 4, h = idx & 15;
    float s = 0.f;
    for (int n = 0; n < 64; n++) s += dw2[(size_t)j * 1024 + h * 64 + n];
    dw2r[j * 16 + h] = s * (1.f / 64.f);
  }
  if (idx < 16) {
    float s = 0.f;
    for (int n = 0; n < 64; n++) s += td[idx * 64 + n];
    tdr[idx] = s * (1.f / 64.f);
  }
}

__global__ __launch_bounds__(256) void wred_kernel(const float* __restrict__ h1,
                                                   const float* __restrict__ dw2r,
                                                   const float* __restrict__ tdr,
                                                   float* __restrict__ wlog) {
  int idx = blockIdx.x * 256 + threadIdx.x;
  int bt = idx >> 4, h = idx & 15;
  float s = tdr[h];
  const float* hrow = h1 + (size_t)bt * 64;
#pragma unroll 8
  for (int j = 0; j < 64; j++) s += hrow[j] * dw2r[j * 16 + h];
  int b = bt >> 11, t = bt & 2047;
  wlog[((size_t)(b * 16 + h)) * 2048 + t] = -expf(s);
}

// ---------------------------------------------------------------------------
// 7. per-chunk scan
// ---------------------------------------------------------------------------
__global__ __launch_bounds__(256) void wprep_kernel(const float* __restrict__ wlog,
                                                    float* __restrict__ cum,
                                                    float* __restrict__ excl,
                                                    float* __restrict__ wsl) {
  int bid = blockIdx.x;
  int c = bid & 7, bh = bid >> 3;
  int q = threadIdx.x;
  float v = wlog[(size_t)bh * 2048 + c * 256 + q];
  __shared__ float s[256];
  s[q] = v;
  float val = v;
  for (int off = 1; off < 256; off <<= 1) {
    __syncthreads();
    float t = (q >= off) ? s[q - off] : 0.f;
    __syncthreads();
    val += t;
    s[q] = val;
  }
  __syncthreads();
  float total = s[255];
  cum[(size_t)bid * 256 + q] = val;
  excl[(size_t)bid * 256 + q] = val - v;
  if (q == 0) wsl[bid] = total;
}

// ---------------------------------------------------------------------------
// kvtrans: per-head transpose of bf16 k,v; k scaled by w_inter.
// vT/kTw layout: [(b*16+h)*64+m][2048]
// ---------------------------------------------------------------------------
__global__ __launch_bounds__(256) void kvtrans_kernel(
    const u16* __restrict__ vb, const u16* __restrict__ kb,
    const float* __restrict__ cum, const float* __restrict__ wsl,
    u16* __restrict__ vT, u16* __restrict__ kTw) {
  int tt = blockIdx.x;  // t-tile 0..31
  int bh = blockIdx.y;  // 0..63
  int b = bh >> 4, h = bh & 15;
  int cc = tt >> 2;
  int bidc = bh * 8 + cc;
  __shared__ float tv[64][65];
  __shared__ float tk[64][65];
  float wslog = wsl[bidc];
#pragma unroll
  for (int it = 0; it < 16; it++) {
    int idx = it * 256 + threadIdx.x;
    int r = idx >> 6, m = idx & 63;
    size_t g = ((size_t)(b * TT + tt * 64 + r)) * CC + h * 64 + m;
    tv[r][m] = b2f(vb[g]);
    tk[r][m] = b2f(kb[g]) * __expf(wslog - cum[(size_t)bidc * 256 + (tt & 3) * 64 + r]);
  }
  __syncthreads();
#pragma unroll
  for (int it = 0; it < 16; it++) {
    int idx = it * 256 + threadIdx.x;
    int m = idx >> 6, tl = idx & 63;
    size_t o = ((size_t)(bh * 64 + m)) * TT + tt * 64 + tl;
    vT[o] = f2b(tv[tl][m]);
    kTw[o] = f2b(tk[tl][m]);
  }
}

// ---------------------------------------------------------------------------
// 8a. kv via MFMA: kv[n][m] = sum_q kTw[n][q] * vT[m][q], per (b,h,chunk)
// ---------------------------------------------------------------------------
__global__ __launch_bounds__(256) void kv_mfma(const u16* __restrict__ kTw,
                                               const u16* __restrict__ vT,
                                               float* __restrict__ kvb) {
  int bid = blockIdx.x;
  int c = bid & 7, bh = bid >> 3;
  __shared__ u16 kS[64 * 72];
  __shared__ u16 vS[64 * 72];
  const int tid = threadIdx.x;
  const int lane = tid & 63;
  const int w = tid >> 6;
  const int fr = lane & 15;
  const int fq = lane >> 4;
  f32x4 acc[4];
#pragma unroll
  for (int j = 0; j < 4; j++) acc[j] = (f32x4){0.f, 0.f, 0.f, 0.f};
  const size_t base = (size_t)bh * 64 * TT + c * QQ;
  for (int qt = 0; qt < 4; qt++) {
    __syncthreads();
    stage_tile(kTw, base + qt * 64, TT, tid, kS);
    stage_tile(vT, base + qt * 64, TT, tid, vS);
    __syncthreads();
#pragma unroll
    for (int ks = 0; ks < 2; ks++) {
      bf16x8 aA = ldfrag(kS + (w * 16 + fr) * 72 + ks * 32 + fq * 8);
#pragma unroll
      for (int j = 0; j < 4; j++) {
        bf16x8 bB = ldfrag(vS + (j * 16 + fr) * 72 + ks * 32 + fq * 8);
        acc[j] = __builtin_amdgcn_mfma_f32_16x16x32_bf16(aA, bB, acc[j], 0, 0, 0);
      }
    }
  }
#pragma unroll
  for (int j = 0; j < 4; j++)
#pragma unroll
    for (int rr = 0; rr < 4; rr++)
      kvb[(size_t)bid * 4096 + (w * 16 + fq * 4 + rr) * 64 + j * 16 + fr] = acc[j][rr];
}

// ---------------------------------------------------------------------------
// 8b. sequential state scan over chunks (emit state BEFORE update)
// ---------------------------------------------------------------------------
__global__ __launch_bounds__(256) void scan_kernel(const float* __restrict__ kvb,
                                                   const float* __restrict__ wsl,
                                                   float* __restrict__ st) {
  int bh = blockIdx.x;
  int tid = threadIdx.x;
  float s[16];
#pragma unroll
  for (int i = 0; i < 16; i++) s[i] = 0.f;
  for (int c = 0; c < 8; c++) {
    int bid = bh * 8 + c;
    float w = __expf(wsl[bid]);
#pragma unroll
    for (int i = 0; i < 16; i++) {
      size_t e = (size_t)bid * 4096 + i * 256 + tid;
      st[e] = s[i];
      s[i] = w * s[i] + kvb[e];
    }
  }
}

// ---------------------------------------------------------------------------
// 9. MFMA fused attention (unchanged from R3)
// ---------------------------------------------------------------------------
__global__ __launch_bounds__(256) void attn_mfma(
    const u16* __restrict__ rb, const u16* __restrict__ kb,
    const u16* __restrict__ vT, const float* __restrict__ stg,
    const float* __restrict__ cum, const float* __restrict__ excl,
    const float* __restrict__ faaaa, float* __restrict__ y) {
  int bid = blockIdx.x;
  int c = bid & 7, bh = bid >> 3;
  int b = bh >> 4, h = bh & 15;
  __shared__ u16 rt[64 * 72];
  __shared__ u16 kt[64 * 72];
  __shared__ u16 vt[64 * 72];
  __shared__ u16 pt[64 * 72];
  __shared__ u16 stT[64 * 72];
  __shared__ float cumS[256], exS[256], faS[64], diagS[64];

  const int tid = threadIdx.x;
  const int lane = tid & 63;
  const int w = tid >> 6;
  const int fr = lane & 15;
  const int fq = lane >> 4;

  cumS[tid] = cum[(size_t)bid * 256 + tid];
  exS[tid] = excl[(size_t)bid * 256 + tid];
  if (tid < 64) faS[tid] = faaaa[h * 64 + tid];
#pragma unroll
  for (int it = 0; it < 16; it++) {
    int idx = tid + it * 256;
    int n = idx >> 6, mm = idx & 63;
    stT[mm * 72 + n] = f2b(stg[(size_t)bid * 4096 + idx]);
  }

  const size_t rowbase = ((size_t)b * TT + c * QQ) * CC + h * 64;
  const size_t vbase0 = (size_t)bh * 64 * TT + c * QQ;

  for (int qt = 0; qt < 4; qt++) {
    __syncthreads();
    stage_tile(rb, rowbase + (size_t)(qt * 64) * CC, CC, tid, rt);
    __syncthreads();

    f32x4 acc[4];
#pragma unroll
    for (int jm = 0; jm < 4; jm++) acc[jm] = (f32x4){0.f, 0.f, 0.f, 0.f};
    bf16x8 rA[2];
    rA[0] = ldfrag(rt + (w * 16 + fr) * 72 + fq * 8);
    rA[1] = ldfrag(rt + (w * 16 + fr) * 72 + 32 + fq * 8);
#pragma unroll
    for (int ks = 0; ks < 2; ks++)
#pragma unroll
      for (int jm = 0; jm < 4; jm++) {
        bf16x8 bB = ldfrag(stT + (jm * 16 + fr) * 72 + ks * 32 + fq * 8);
        acc[jm] = __builtin_amdgcn_mfma_f32_16x16x32_bf16(rA[ks], bB, acc[jm], 0, 0, 0);
      }
    float er[4];
#pragma unroll
    for (int rr = 0; rr < 4; rr++)
      er[rr] = __expf(exS[qt * 64 + w * 16 + fq * 4 + rr]);
#pragma unroll
    for (int jm = 0; jm < 4; jm++)
#pragma unroll
      for (int rr = 0; rr < 4; rr++) acc[jm][rr] *= er[rr];

    for (int kti = 0; kti <= qt; kti++) {
      __syncthreads();
      stage_tile(kb, rowbase + (size_t)(kti * 64) * CC, CC, tid, kt);
      stage_tile(vT, vbase0 + (size_t)(kti * 64), TT, tid, vt);
      __syncthreads();

      if (kti == qt) {
        int dq = tid >> 2, seg = tid & 3;
        float s = 0.f;
#pragma unroll
        for (int i = 0; i < 16; i++) {
          int n = seg * 16 + i;
          s += b2f(rt[dq * 72 + n]) * faS[n] * b2f(kt[dq * 72 + n]);
        }
        s += __shfl_xor(s, 1);
        s += __shfl_xor(s, 2);
        if (seg == 0) diagS[dq] = s;
        __syncthreads();
      }

      f32x4 sacc[4];
#pragma unroll
      for (int jj = 0; jj < 4; jj++) sacc[jj] = (f32x4){0.f, 0.f, 0.f, 0.f};
#pragma unroll
      for (int ks = 0; ks < 2; ks++)
#pragma unroll
        for (int jj = 0; jj < 4; jj++) {
          bf16x8 bB = ldfrag(kt + (jj * 16 + fr) * 72 + ks * 32 + fq * 8);
          sacc[jj] = __builtin_amdgcn_mfma_f32_16x16x32_bf16(rA[ks], bB, sacc[jj], 0, 0, 0);
        }
      int ql0 = w * 16 + fq * 4;
#pragma unroll
      for (int jj = 0; jj < 4; jj++) {
        int kcol = kti * 64 + jj * 16 + fr;
        float ck = cumS[kcol];
#pragma unroll
        for (int rr = 0; rr < 4; rr++) {
          int qrow = qt * 64 + ql0 + rr;
          float vsc;
          if (kcol < qrow)
            vsc = sacc[jj][rr] * __expf(exS[qrow] - ck);
          else if (kcol == qrow)
            vsc = diagS[ql0 + rr];
          else
            vsc = 0.f;
          pt[(ql0 + rr) * 72 + jj * 16 + fr] = f2b(vsc);
        }
      }
      __syncthreads();
#pragma unroll
      for (int ks = 0; ks < 2; ks++) {
        bf16x8 pA = ldfrag(pt + (w * 16 + fr) * 72 + ks * 32 + fq * 8);
#pragma unroll
        for (int jm = 0; jm < 4; jm++) {
          bf16x8 vB = ldfrag(vt + (jm * 16 + fr) * 72 + ks * 32 + fq * 8);
          acc[jm] = __builtin_amdgcn_mfma_f32_16x16x32_bf16(pA, vB, acc[jm], 0, 0, 0);
        }
      }
    }
    int qg0 = qt * 64 + w * 16 + fq * 4;
#pragma unroll
    for (int jm = 0; jm < 4; jm++)
#pragma unroll
      for (int rr = 0; rr < 4; rr++)
        y[rowbase + (size_t)(qg0 + rr) * CC + jm * 16 + fr] = acc[jm][rr];
  }
}

// ---------------------------------------------------------------------------
// 10. LayerNorm over C -> bf16
// ---------------------------------------------------------------------------
__global__ __launch_bounds__(256) void ln_kernel(const float* __restrict__ y,
                                                 const float* __restrict__ g,
                                                 const float* __restrict__ bta,
                                                 u16* __restrict__ out) {
  __shared__ float red[8];
  int bt = blockIdx.x;
  int tid = threadIdx.x;
  float v[4];
  float s = 0.f;
#pragma unroll
  for (int i = 0; i < 4; i++) {
    v[i] = y[(size_t)bt * 1024 + i * 256 + tid];
    s += v[i];
  }
#pragma unroll
  for (int off = 32; off > 0; off >>= 1) s += __shfl_down(s, off);
  if ((tid & 63) == 0) red[tid >> 6] = s;
  __syncthreads();
  if (tid == 0) red[4] = red[0] + red[1] + red[2] + red[3];
  __syncthreads();
  float mu = red[4] * (1.f / 1024.f);
  float s2 = 0.f;
#pragma unroll
  for (int i = 0; i < 4; i++) {
    float d = v[i] - mu;
    s2 += d * d;
  }
#pragma unroll
  for (int off = 32; off > 0; off >>= 1) s2 += __shfl_down(s2, off);
  __syncthreads();
  if ((tid & 63) == 0) red[tid >> 6] = s2;
  __syncthreads();
  if (tid == 0) red[5] = red[0] + red[1] + red[2] + red[3];
  __syncthreads();
  float var = red[5] * (1.f / 1024.f);
  float rstd = rsqrtf(var + 1e-5f);
#pragma unroll
  for (int i = 0; i < 4; i++) {
    int c = i * 256 + tid;
    out[(size_t)bt * 1024 + c] = f2b((v[i] - mu) * rstd * g[c] + bta[c]);
  }
}

// ---------------------------------------------------------------------------
extern "C" void kernel_launch(void* const* d_in, const int* in_sizes, int n_in,
                              void* d_out, int out_size, void* d_ws,
                              size_t ws_size, hipStream_t stream) {
  const float* x = (const float*)d_in[0];
  const float* tmx = (const float*)d_in[1];
  const float* tmw = (const float*)d_in[2];
  const float* tmk = (const float*)d_in[3];
  const float* tmv = (const float*)d_in[4];
  const float* tmr = (const float*)d_in[5];
  const float* maa_w1 = (const float*)d_in[6];
  const float* maa_w2 = (const float*)d_in[7];
  const float* decay_w1 = (const float*)d_in[8];
  const float* decay_w2 = (const float*)d_in[9];
  const float* time_decay = (const float*)d_in[10];
  const float* faaaa = (const float*)d_in[11];
  const float* Wr = (const float*)d_in[12];
  const float* Wk = (const float*)d_in[13];
  const float* Wv = (const float*)d_in[14];
  const float* Wo = (const float*)d_in[15];
  const float* lng = (const float*)d_in[16];
  const float* lnb = (const float*)d_in[17];
  float* out = (float*)d_out;
  float* ws = (float*)d_ws;

  const size_t S = (size_t)BT * CC;  // 8388608

  // f32 region
  float* xx = ws;                     // mix out -> blend in; later y_ (attn out)
  float* xw = ws + S;                 // blend out -> gemm64tanh in
  float* h1 = ws + 2 * S;             // BT*64
  float* dw2r = h1 + (size_t)BT * 64; // 1024
  float* tdr = dw2r + 1024;
  float* wlog = tdr + 1024;           // 131072
  float* cum = wlog + 131072;
  float* excl = cum + 131072;
  float* wsl = excl + 131072;
  float* kvb = wsl + 1024;            // 512*4096
  float* stb = kvb + (size_t)512 * 4096;
  float* fend = stb + (size_t)512 * 4096;
  // bf16 region (u16)
  u16* xxxb = (u16*)fend;             // mix out -> maa GEMM in -> vT
  u16* mb = xxxb + S;                 // BT*128 (maa out -> blend in)
  u16* xkb = mb + (size_t)BT * 128;   // blend out -> k-GEMM in -> rb16
  u16* xvb = xkb + S;                 // blend out -> v-GEMM in -> kb16 -> ylnb
  u16* xrb = xvb + S;                 // blend out -> r-GEMM in -> kTw
  u16* Vb = xrb + S;                  // v-GEMM bf16 out
  u16* Wrt = Vb + S;
  u16* Wkt = Wrt + (size_t)1024 * 1024;
  u16* Wvt = Wkt + (size_t)1024 * 1024;
  u16* Wot = Wvt + (size_t)1024 * 1024;
  u16* w1T = Wot + (size_t)1024 * 1024;  // [128][1024]
  u16* w2T = w1T + (size_t)128 * 1024;   // [1024][128]
  // aliases (stream-ordered reuse)
  u16* kb16 = xvb;  // after v-GEMM consumed xvb
  u16* rb16 = xkb;  // after k-GEMM consumed xkb
  u16* vT = xxxb;   // after maa GEMM consumed xxxb
  u16* kTw = xrb;   // after r-GEMM consumed xrb
  float* y_ = xx;   // after blend consumed xx
  u16* ylnb = xvb;  // after attn consumed kb16

  cvt_wT<<<dim3(16, 16, 4), 256, 0, stream>>>(Wr, Wk, Wv, Wo, Wrt, Wkt, Wvt, Wot);
  cvt_T<<<dim3(2, 16), 256, 0, stream>>>(maa_w1, w1T, 1024, 128);
  cvt_T<<<dim3(16, 2), 256, 0, stream>>>(maa_w2, w2T, 128, 1024);
  mix_kernel<<<8192, 256, 0, stream>>>(x, tmx, xx, xxxb);
  gemm_bt_mfma<true><<<dim3(1, 64), 256, 0, stream>>>(xxxb, w1T, nullptr, mb, BT, 128, CC);
  blend_mfma<<<dim3(16, 128), 256, 0, stream>>>(mb, w2T, x, xx, tmw, tmk, tmv,
                                                tmr, xw, xkb, xvb, xrb);
  gemm64tanh<<<dim3(1, 128), 256, 0, stream>>>(xw, decay_w1, h1, BT, 64, CC);
  dw2r_kernel<<<4, 256, 0, stream>>>(decay_w2, time_decay, dw2r, tdr);
  wred_kernel<<<512, 256, 0, stream>>>(h1, dw2r, tdr, wlog);
  wprep_kernel<<<512, 256, 0, stream>>>(wlog, cum, excl, wsl);
  // order matters for buffer reuse: v -> k -> r -> transposes
  gemm_bt_mfma<false><<<dim3(8, 64), 256, 0, stream>>>(xvb, Wvt, nullptr, Vb, BT, CC, CC);
  gemm_bt_mfma<false><<<dim3(8, 64), 256, 0, stream>>>(xkb, Wkt, nullptr, kb16, BT, CC, CC);
  gemm_bt_mfma<false><<<dim3(8, 64), 256, 0, stream>>>(xrb, Wrt, nullptr, rb16, BT, CC, CC);
  kvtrans_kernel<<<dim3(32, 64), 256, 0, stream>>>(Vb, kb16, cum, wsl, vT, kTw);
  kv_mfma<<<512, 256, 0, stream>>>(kTw, vT, kvb);
  scan_kernel<<<64, 256, 0, stream>>>(kvb, wsl, stb);
  attn_mfma<<<512, 256, 0, stream>>>(rb16, kb16, vT, stb, cum, excl, faaaa, y_);
  ln_kernel<<<BT, 256, 0, stream>>>(y_, lng, lnb, ylnb);
  gemm_bt_mfma<false><<<dim3(8, 64), 256, 0, stream>>>(ylnb, Wot, out, nullptr, BT, CC, CC);
}

// Round 5
// 432.439 us; speedup vs baseline: 4.3663x; 1.1280x over previous
//
#include <hip/hip_runtime.h>
#include <math.h>

// B=4, T=2048, C=1024, H=16, N=64, Q=256, nc=8, BT=8192
#define BB 4
#define TT 2048
#define CC 1024
#define HH 16
#define NN 64
#define QQ 256
#define NCH 8
#define BT 8192

typedef unsigned short u16;
typedef __attribute__((ext_vector_type(8))) short bf16x8;
typedef __attribute__((ext_vector_type(4))) short bf16x4;
typedef __attribute__((ext_vector_type(4))) float f32x4;
typedef __attribute__((ext_vector_type(4))) u16 u16x4;

// f32 -> bf16 bits, round-to-nearest-even
__device__ inline u16 f2b(float x) {
  union { float f; unsigned u; } v;
  v.f = x;
  unsigned r = v.u + 0x7FFFu + ((v.u >> 16) & 1u);
  return (u16)(r >> 16);
}
__device__ inline float b2f(u16 u) {
  union { unsigned u; float f; } v;
  v.u = ((unsigned)u) << 16;
  return v.f;
}
// 16B fragment from padded LDS row via two 8B loads (conflict-friendly)
__device__ inline bf16x8 ldfrag(const u16* p) {
  bf16x4 lo = *(const bf16x4*)p;
  bf16x4 hi = *(const bf16x4*)(p + 4);
  return __builtin_shufflevector(lo, hi, 0, 1, 2, 3, 4, 5, 6, 7);
}
// stage 64x64 bf16 tile (global pitch `pitch` u16) into LDS stride-72
__device__ inline void stage_tile(const u16* __restrict__ g, size_t base,
                                  int pitch, int tid, u16* __restrict__ lds) {
#pragma unroll
  for (int it = 0; it < 2; it++) {
    int cidx = tid + it * 256;  // 0..511
    int r = cidx >> 3, c8 = (cidx & 7) * 8;
    bf16x8 v = *(const bf16x8*)(g + base + (size_t)r * pitch + c8);
    *(bf16x4*)(lds + r * 72 + c8) = __builtin_shufflevector(v, v, 0, 1, 2, 3);
    *(bf16x4*)(lds + r * 72 + c8 + 4) = __builtin_shufflevector(v, v, 4, 5, 6, 7);
  }
}

// ---------------------------------------------------------------------------
// 1. time-shift mix: xx f32, xxx -> bf16
// ---------------------------------------------------------------------------
__global__ __launch_bounds__(256) void mix_kernel(const float* __restrict__ x,
                                                  const float* __restrict__ tmx,
                                                  float* __restrict__ xx,
                                                  u16* __restrict__ xxxb) {
  size_t e = ((size_t)blockIdx.x * 256 + threadIdx.x) * 4;
  int c = (int)(e & 1023);
  size_t row = e >> 10;
  int t = (int)(row & 2047);
  float4 xv = *(const float4*)(x + e);
  float4 pv = make_float4(0.f, 0.f, 0.f, 0.f);
  if (t > 0) pv = *(const float4*)(x + e - 1024);
  float4 d = make_float4(pv.x - xv.x, pv.y - xv.y, pv.z - xv.z, pv.w - xv.w);
  *(float4*)(xx + e) = d;
  u16x4 o;
  o.x = f2b(xv.x + d.x * tmx[c + 0]);
  o.y = f2b(xv.y + d.y * tmx[c + 1]);
  o.z = f2b(xv.z + d.z * tmx[c + 2]);
  o.w = f2b(xv.w + d.w * tmx[c + 3]);
  *(u16x4*)(xxxb + e) = o;
}

// ---------------------------------------------------------------------------
// weight f32[k][n] (1024x1024) -> bf16 transposed Wt[n][k]
// ---------------------------------------------------------------------------
__global__ __launch_bounds__(256) void cvt_wT(const float* __restrict__ W0,
                                              const float* __restrict__ W1,
                                              const float* __restrict__ W2,
                                              const float* __restrict__ W3,
                                              u16* __restrict__ O0,
                                              u16* __restrict__ O1,
                                              u16* __restrict__ O2,
                                              u16* __restrict__ O3) {
  const float* W;
  u16* O;
  switch (blockIdx.z) {
    case 0: W = W0; O = O0; break;
    case 1: W = W1; O = O1; break;
    case 2: W = W2; O = O2; break;
    default: W = W3; O = O3; break;
  }
  __shared__ float t[64][65];
  int bx = blockIdx.x * 64;
  int by = blockIdx.y * 64;
#pragma unroll
  for (int it = 0; it < 16; it++) {
    int idx = it * 256 + threadIdx.x;
    int r = idx >> 6, c = idx & 63;
    t[r][c] = W[(size_t)(by + r) * 1024 + bx + c];
  }
  __syncthreads();
#pragma unroll
  for (int it = 0; it < 16; it++) {
    int idx = it * 256 + threadIdx.x;
    int n = idx >> 6, k = idx & 63;
    O[(size_t)(bx + n) * 1024 + by + k] = f2b(t[k][n]);
  }
}

// ---------------------------------------------------------------------------
// generic transpose+cvt: in f32 [R][C] -> out bf16 [C][R]  (R,C mult of 64)
// ---------------------------------------------------------------------------
__global__ __launch_bounds__(256) void cvt_T(const float* __restrict__ in,
                                             u16* __restrict__ out, int R, int C) {
  __shared__ float t[64][65];
  int c0 = blockIdx.x * 64, r0 = blockIdx.y * 64;
#pragma unroll
  for (int it = 0; it < 16; it++) {
    int idx = it * 256 + threadIdx.x;
    int r = idx >> 6, c = idx & 63;
    t[r][c] = in[(size_t)(r0 + r) * C + c0 + c];
  }
  __syncthreads();
#pragma unroll
  for (int it = 0; it < 16; it++) {
    int idx = it * 256 + threadIdx.x;
    int c = idx >> 6, r = idx & 63;
    out[(size_t)(c0 + c) * R + r0 + r] = f2b(t[r][c]);
  }
}

// ---------------------------------------------------------------------------
// bf16 MFMA GEMM (m97): A[M][K], Bt[N][K]; out f32 Cf and/or bf16 Cb (opt tanh)
// ---------------------------------------------------------------------------
template <bool TANH>
__global__ __launch_bounds__(256) void gemm_bt_mfma(const u16* __restrict__ A,
                                                    const u16* __restrict__ Bt,
                                                    float* __restrict__ Cf,
                                                    u16* __restrict__ Cb,
                                                    int M, int N, int K) {
  __shared__ u16 As[128 * 32];
  __shared__ u16 Bs[128 * 32];
  const int tid = threadIdx.x;
  const int lane = tid & 63;
  const int row0 = blockIdx.y * 128;
  const int col0 = blockIdx.x * 128;
  const int wave = tid >> 6;
  const int wr = (wave >> 1) * 64;
  const int wc = (wave & 1) * 64;
  const int fr = lane & 15;
  const int fq = lane >> 4;

  f32x4 acc[4][4];
#pragma unroll
  for (int i = 0; i < 4; i++)
#pragma unroll
    for (int j = 0; j < 4; j++) acc[i][j] = (f32x4){0.f, 0.f, 0.f, 0.f};

  const int i0 = tid, i1 = tid + 256;
  const int ra0 = i0 >> 2, ca0 = (i0 & 3) * 8;
  const int ra1 = i1 >> 2, ca1 = (i1 & 3) * 8;

  for (int k0 = 0; k0 < K; k0 += 32) {
    __builtin_amdgcn_global_load_lds(
        (const __attribute__((address_space(1))) void*)(A + (size_t)(row0 + ra0) * K + k0 + ca0),
        (__attribute__((address_space(3))) void*)(As + i0 * 8), 16, 0, 0);
    __builtin_amdgcn_global_load_lds(
        (const __attribute__((address_space(1))) void*)(A + (size_t)(row0 + ra1) * K + k0 + ca1),
        (__attribute__((address_space(3))) void*)(As + i1 * 8), 16, 0, 0);
    __builtin_amdgcn_global_load_lds(
        (const __attribute__((address_space(1))) void*)(Bt + (size_t)(col0 + ra0) * K + k0 + ca0),
        (__attribute__((address_space(3))) void*)(Bs + i0 * 8), 16, 0, 0);
    __builtin_amdgcn_global_load_lds(
        (const __attribute__((address_space(1))) void*)(Bt + (size_t)(col0 + ra1) * K + k0 + ca1),
        (__attribute__((address_space(3))) void*)(Bs + i1 * 8), 16, 0, 0);
    __syncthreads();

    bf16x8 af[4], bf[4];
#pragma unroll
    for (int i = 0; i < 4; i++)
      af[i] = *(const bf16x8*)(As + ((wr + i * 16 + fr) * 32 + fq * 8));
#pragma unroll
    for (int j = 0; j < 4; j++)
      bf[j] = *(const bf16x8*)(Bs + ((wc + j * 16 + fr) * 32 + fq * 8));
#pragma unroll
    for (int i = 0; i < 4; i++)
#pragma unroll
      for (int j = 0; j < 4; j++)
        acc[i][j] = __builtin_amdgcn_mfma_f32_16x16x32_bf16(af[i], bf[j], acc[i][j], 0, 0, 0);
    __syncthreads();
  }
#pragma unroll
  for (int i = 0; i < 4; i++) {
    int grow = row0 + wr + i * 16 + fq * 4;
#pragma unroll
    for (int j = 0; j < 4; j++) {
      int gcol = col0 + wc + j * 16 + fr;
#pragma unroll
      for (int r = 0; r < 4; r++) {
        float vv = acc[i][j][r];
        if (TANH) vv = tanhf(vv);
        if (Cf) Cf[(size_t)(grow + r) * N + gcol] = vv;
        if (Cb) Cb[(size_t)(grow + r) * N + gcol] = f2b(vv);
      }
    }
  }
}

// ---------------------------------------------------------------------------
// 3. blend via MFMA (fused x/xx/tm* epilogue); xw now bf16 too.
// ---------------------------------------------------------------------------
__global__ __launch_bounds__(256) void blend_mfma(
    const u16* __restrict__ mb, const u16* __restrict__ w2T,
    const float* __restrict__ x, const float* __restrict__ xx,
    const float* __restrict__ tmw, const float* __restrict__ tmk,
    const float* __restrict__ tmv, const float* __restrict__ tmr,
    u16* __restrict__ xwb, u16* __restrict__ xkb, u16* __restrict__ xvb,
    u16* __restrict__ xrb) {
  __shared__ u16 mS[64 * 136];
  __shared__ u16 wS[64 * 136];
  const int tid = threadIdx.x;
  const int lane = tid & 63;
  const int w = tid >> 6;
  const int fr = lane & 15;
  const int fq = lane >> 4;
  const int c0 = blockIdx.x * 64;
  const int bt0 = blockIdx.y * 64;

#pragma unroll
  for (int it = 0; it < 4; it++) {
    int idx = tid + it * 256;  // 0..1023
    int r = idx >> 4, c8 = (idx & 15) * 8;
    bf16x8 v = *(const bf16x8*)(mb + (size_t)(bt0 + r) * 128 + c8);
    *(bf16x4*)(mS + r * 136 + c8) = __builtin_shufflevector(v, v, 0, 1, 2, 3);
    *(bf16x4*)(mS + r * 136 + c8 + 4) = __builtin_shufflevector(v, v, 4, 5, 6, 7);
    bf16x8 u = *(const bf16x8*)(w2T + (size_t)(c0 + r) * 128 + c8);
    *(bf16x4*)(wS + r * 136 + c8) = __builtin_shufflevector(u, u, 0, 1, 2, 3);
    *(bf16x4*)(wS + r * 136 + c8 + 4) = __builtin_shufflevector(u, u, 4, 5, 6, 7);
  }
  __syncthreads();

  f32x4 acc[4][4];  // [col-tile j][f]
#pragma unroll
  for (int j = 0; j < 4; j++)
#pragma unroll
    for (int f = 0; f < 4; f++) acc[j][f] = (f32x4){0.f, 0.f, 0.f, 0.f};

#pragma unroll
  for (int f = 0; f < 4; f++) {
    bf16x8 aA = ldfrag(mS + (w * 16 + fr) * 136 + f * 32 + fq * 8);
#pragma unroll
    for (int j = 0; j < 4; j++) {
      bf16x8 bB = ldfrag(wS + (j * 16 + fr) * 136 + f * 32 + fq * 8);
      acc[j][f] = __builtin_amdgcn_mfma_f32_16x16x32_bf16(aA, bB, acc[j][f], 0, 0, 0);
    }
  }

#pragma unroll
  for (int j = 0; j < 4; j++) {
    int c = c0 + j * 16 + fr;
    float w_ = tmw[c], k_ = tmk[c], v_ = tmv[c], r_ = tmr[c];
#pragma unroll
    for (int rr = 0; rr < 4; rr++) {
      int bt = bt0 + w * 16 + fq * 4 + rr;
      size_t g = (size_t)bt * 1024 + c;
      float xv_ = x[g], dx = xx[g];
      xwb[g] = f2b(xv_ + dx * (w_ + acc[j][0][rr]));
      xkb[g] = f2b(xv_ + dx * (k_ + acc[j][1][rr]));
      xvb[g] = f2b(xv_ + dx * (v_ + acc[j][2][rr]));
      xrb[g] = f2b(xv_ + dx * (r_ + acc[j][3][rr]));
    }
  }
}

// ---------------------------------------------------------------------------
// 5a. decay reduce: dw2r f32 [64][16], tdr f32 [16], dw2rbT bf16 [16][64]
// ---------------------------------------------------------------------------
__global__ __launch_bounds__(256) void dw2r_kernel(const float* __restrict__ dw2,
                                                   const float* __restrict__ td,
                                                   float* __restrict__ dw2r,
                                                   float* __restrict__ tdr,
                                                   u16* __restrict__ dw2rbT) {
  int idx = blockIdx.x * 256 + threadIdx.x;
  if (idx < 1024) {
    int j = idx >> 4, h = idx & 15;
    float s = 0.f;
    for (int n = 0; n < 64; n++) s += dw2[(size_t)j * 1024 + h * 64 + n];
    float m = s * (1.f / 64.f);
    dw2r[j * 16 + h] = m;
    dw2rbT[h * 64 + j] = f2b(m);
  }
  if (idx < 16) {
    float s = 0.f;
    for (int n = 0; n < 64; n++) s += td[idx * 64 + n];
    tdr[idx] = s * (1.f / 64.f);
  }
}

// ---------------------------------------------------------------------------
// 5b. fused decay GEMM: h1 = tanh(xw @ d1) via MFMA (K=1024), then
//     wlog = -exp(tdr + h1 @ dw2r) via a second 2-step MFMA. 64-row tiles.
// ---------------------------------------------------------------------------
__global__ __launch_bounds__(256) void decay_mfma(const u16* __restrict__ xwb,
                                                  const u16* __restrict__ d1T,
                                                  const u16* __restrict__ dw2rbT,
                                                  const float* __restrict__ tdr,
                                                  float* __restrict__ wlog) {
  __shared__ u16 As[64 * 32];
  __shared__ u16 Bs[64 * 32];
  __shared__ u16 h1S[64 * 72];
  __shared__ u16 dwS[16 * 72];
  const int tid = threadIdx.x;
  const int lane = tid & 63;
  const int w = tid >> 6;
  const int fr = lane & 15;
  const int fq = lane >> 4;
  const int bt0 = blockIdx.x * 64;

  // stage dw2rbT [16][64] -> dwS stride 72
#pragma unroll
  for (int it = 0; it < 4; it++) {
    int idx = tid + it * 256;  // 0..1023
    int r = idx >> 6, c = idx & 63;
    dwS[r * 72 + c] = dw2rbT[r * 64 + c];
  }

  f32x4 acc[4];
#pragma unroll
  for (int j = 0; j < 4; j++) acc[j] = (f32x4){0.f, 0.f, 0.f, 0.f};

  const int ra = tid >> 2, ca = (tid & 3) * 8;
  for (int k0 = 0; k0 < 1024; k0 += 32) {
    __builtin_amdgcn_global_load_lds(
        (const __attribute__((address_space(1))) void*)(xwb + (size_t)(bt0 + ra) * 1024 + k0 + ca),
        (__attribute__((address_space(3))) void*)(As + tid * 8), 16, 0, 0);
    __builtin_amdgcn_global_load_lds(
        (const __attribute__((address_space(1))) void*)(d1T + (size_t)ra * 1024 + k0 + ca),
        (__attribute__((address_space(3))) void*)(Bs + tid * 8), 16, 0, 0);
    __syncthreads();
    bf16x8 aA = *(const bf16x8*)(As + ((w * 16 + fr) * 32 + fq * 8));
#pragma unroll
    for (int j = 0; j < 4; j++) {
      bf16x8 bB = *(const bf16x8*)(Bs + ((j * 16 + fr) * 32 + fq * 8));
      acc[j] = __builtin_amdgcn_mfma_f32_16x16x32_bf16(aA, bB, acc[j], 0, 0, 0);
    }
    __syncthreads();
  }
  // tanh -> h1S (wave-private 16-row slab, but sync for dwS + safety)
#pragma unroll
  for (int j = 0; j < 4; j++)
#pragma unroll
    for (int rr = 0; rr < 4; rr++)
      h1S[(w * 16 + fq * 4 + rr) * 72 + j * 16 + fr] = f2b(tanhf(acc[j][rr]));
  __syncthreads();

  // stage 2: [16 rows] x [16 h] = h1 @ dw2r^T-frags, K=64
  f32x4 a2 = (f32x4){0.f, 0.f, 0.f, 0.f};
#pragma unroll
  for (int ks = 0; ks < 2; ks++) {
    bf16x8 aA = ldfrag(h1S + (w * 16 + fr) * 72 + ks * 32 + fq * 8);
    bf16x8 bB = ldfrag(dwS + fr * 72 + ks * 32 + fq * 8);
    a2 = __builtin_amdgcn_mfma_f32_16x16x32_bf16(aA, bB, a2, 0, 0, 0);
  }
  float tdv = tdr[fr];
#pragma unroll
  for (int rr = 0; rr < 4; rr++) {
    int bt = bt0 + w * 16 + fq * 4 + rr;
    int b = bt >> 11, tl = bt & 2047;
    wlog[((size_t)(b * 16 + fr)) * 2048 + tl] = -__expf(tdv + a2[rr]);
  }
}

// ---------------------------------------------------------------------------
// 7. per-chunk scan
// ---------------------------------------------------------------------------
__global__ __launch_bounds__(256) void wprep_kernel(const float* __restrict__ wlog,
                                                    float* __restrict__ cum,
                                                    float* __restrict__ excl,
                                                    float* __restrict__ wsl) {
  int bid = blockIdx.x;
  int c = bid & 7, bh = bid >> 3;
  int q = threadIdx.x;
  float v = wlog[(size_t)bh * 2048 + c * 256 + q];
  __shared__ float s[256];
  s[q] = v;
  float val = v;
  for (int off = 1; off < 256; off <<= 1) {
    __syncthreads();
    float t = (q >= off) ? s[q - off] : 0.f;
    __syncthreads();
    val += t;
    s[q] = val;
  }
  __syncthreads();
  float total = s[255];
  cum[(size_t)bid * 256 + q] = val;
  excl[(size_t)bid * 256 + q] = val - v;
  if (q == 0) wsl[bid] = total;
}

// ---------------------------------------------------------------------------
// kvtrans: per-head transpose of bf16 k,v; k scaled by w_inter.
// ---------------------------------------------------------------------------
__global__ __launch_bounds__(256) void kvtrans_kernel(
    const u16* __restrict__ vb, const u16* __restrict__ kb,
    const float* __restrict__ cum, const float* __restrict__ wsl,
    u16* __restrict__ vT, u16* __restrict__ kTw) {
  int tt = blockIdx.x;  // t-tile 0..31
  int bh = blockIdx.y;  // 0..63
  int b = bh >> 4, h = bh & 15;
  int cc = tt >> 2;
  int bidc = bh * 8 + cc;
  __shared__ float tv[64][65];
  __shared__ float tk[64][65];
  float wslog = wsl[bidc];
#pragma unroll
  for (int it = 0; it < 16; it++) {
    int idx = it * 256 + threadIdx.x;
    int r = idx >> 6, m = idx & 63;
    size_t g = ((size_t)(b * TT + tt * 64 + r)) * CC + h * 64 + m;
    tv[r][m] = b2f(vb[g]);
    tk[r][m] = b2f(kb[g]) * __expf(wslog - cum[(size_t)bidc * 256 + (tt & 3) * 64 + r]);
  }
  __syncthreads();
#pragma unroll
  for (int it = 0; it < 16; it++) {
    int idx = it * 256 + threadIdx.x;
    int m = idx >> 6, tl = idx & 63;
    size_t o = ((size_t)(bh * 64 + m)) * TT + tt * 64 + tl;
    vT[o] = f2b(tv[tl][m]);
    kTw[o] = f2b(tk[tl][m]);
  }
}

// ---------------------------------------------------------------------------
// 8a. kv via MFMA
// ---------------------------------------------------------------------------
__global__ __launch_bounds__(256) void kv_mfma(const u16* __restrict__ kTw,
                                               const u16* __restrict__ vT,
                                               float* __restrict__ kvb) {
  int bid = blockIdx.x;
  int c = bid & 7, bh = bid >> 3;
  __shared__ u16 kS[64 * 72];
  __shared__ u16 vS[64 * 72];
  const int tid = threadIdx.x;
  const int lane = tid & 63;
  const int w = tid >> 6;
  const int fr = lane & 15;
  const int fq = lane >> 4;
  f32x4 acc[4];
#pragma unroll
  for (int j = 0; j < 4; j++) acc[j] = (f32x4){0.f, 0.f, 0.f, 0.f};
  const size_t base = (size_t)bh * 64 * TT + c * QQ;
  for (int qt = 0; qt < 4; qt++) {
    __syncthreads();
    stage_tile(kTw, base + qt * 64, TT, tid, kS);
    stage_tile(vT, base + qt * 64, TT, tid, vS);
    __syncthreads();
#pragma unroll
    for (int ks = 0; ks < 2; ks++) {
      bf16x8 aA = ldfrag(kS + (w * 16 + fr) * 72 + ks * 32 + fq * 8);
#pragma unroll
      for (int j = 0; j < 4; j++) {
        bf16x8 bB = ldfrag(vS + (j * 16 + fr) * 72 + ks * 32 + fq * 8);
        acc[j] = __builtin_amdgcn_mfma_f32_16x16x32_bf16(aA, bB, acc[j], 0, 0, 0);
      }
    }
  }
#pragma unroll
  for (int j = 0; j < 4; j++)
#pragma unroll
    for (int rr = 0; rr < 4; rr++)
      kvb[(size_t)bid * 4096 + (w * 16 + fq * 4 + rr) * 64 + j * 16 + fr] = acc[j][rr];
}

// ---------------------------------------------------------------------------
// 8b. sequential state scan over chunks
// ---------------------------------------------------------------------------
__global__ __launch_bounds__(256) void scan_kernel(const float* __restrict__ kvb,
                                                   const float* __restrict__ wsl,
                                                   float* __restrict__ st) {
  int bh = blockIdx.x;
  int tid = threadIdx.x;
  float s[16];
#pragma unroll
  for (int i = 0; i < 16; i++) s[i] = 0.f;
  for (int c = 0; c < 8; c++) {
    int bid = bh * 8 + c;
    float w = __expf(wsl[bid]);
#pragma unroll
    for (int i = 0; i < 16; i++) {
      size_t e = (size_t)bid * 4096 + i * 256 + tid;
      st[e] = s[i];
      s[i] = w * s[i] + kvb[e];
    }
  }
}

// ---------------------------------------------------------------------------
// 9. MFMA fused attention
// ---------------------------------------------------------------------------
__global__ __launch_bounds__(256) void attn_mfma(
    const u16* __restrict__ rb, const u16* __restrict__ kb,
    const u16* __restrict__ vT, const float* __restrict__ stg,
    const float* __restrict__ cum, const float* __restrict__ excl,
    const float* __restrict__ faaaa, float* __restrict__ y) {
  int bid = blockIdx.x;
  int c = bid & 7, bh = bid >> 3;
  int b = bh >> 4, h = bh & 15;
  __shared__ u16 rt[64 * 72];
  __shared__ u16 kt[64 * 72];
  __shared__ u16 vt[64 * 72];
  __shared__ u16 pt[64 * 72];
  __shared__ u16 stT[64 * 72];
  __shared__ float cumS[256], exS[256], faS[64], diagS[64];

  const int tid = threadIdx.x;
  const int lane = tid & 63;
  const int w = tid >> 6;
  const int fr = lane & 15;
  const int fq = lane >> 4;

  cumS[tid] = cum[(size_t)bid * 256 + tid];
  exS[tid] = excl[(size_t)bid * 256 + tid];
  if (tid < 64) faS[tid] = faaaa[h * 64 + tid];
#pragma unroll
  for (int it = 0; it < 16; it++) {
    int idx = tid + it * 256;
    int n = idx >> 6, mm = idx & 63;
    stT[mm * 72 + n] = f2b(stg[(size_t)bid * 4096 + idx]);
  }

  const size_t rowbase = ((size_t)b * TT + c * QQ) * CC + h * 64;
  const size_t vbase0 = (size_t)bh * 64 * TT + c * QQ;

  for (int qt = 0; qt < 4; qt++) {
    __syncthreads();
    stage_tile(rb, rowbase + (size_t)(qt * 64) * CC, CC, tid, rt);
    __syncthreads();

    f32x4 acc[4];
#pragma unroll
    for (int jm = 0; jm < 4; jm++) acc[jm] = (f32x4){0.f, 0.f, 0.f, 0.f};
    bf16x8 rA[2];
    rA[0] = ldfrag(rt + (w * 16 + fr) * 72 + fq * 8);
    rA[1] = ldfrag(rt + (w * 16 + fr) * 72 + 32 + fq * 8);
#pragma unroll
    for (int ks = 0; ks < 2; ks++)
#pragma unroll
      for (int jm = 0; jm < 4; jm++) {
        bf16x8 bB = ldfrag(stT + (jm * 16 + fr) * 72 + ks * 32 + fq * 8);
        acc[jm] = __builtin_amdgcn_mfma_f32_16x16x32_bf16(rA[ks], bB, acc[jm], 0, 0, 0);
      }
    float er[4];
#pragma unroll
    for (int rr = 0; rr < 4; rr++)
      er[rr] = __expf(exS[qt * 64 + w * 16 + fq * 4 + rr]);
#pragma unroll
    for (int jm = 0; jm < 4; jm++)
#pragma unroll
      for (int rr = 0; rr < 4; rr++) acc[jm][rr] *= er[rr];

    for (int kti = 0; kti <= qt; kti++) {
      __syncthreads();
      stage_tile(kb, rowbase + (size_t)(kti * 64) * CC, CC, tid, kt);
      stage_tile(vT, vbase0 + (size_t)(kti * 64), TT, tid, vt);
      __syncthreads();

      if (kti == qt) {
        int dq = tid >> 2, seg = tid & 3;
        float s = 0.f;
#pragma unroll
        for (int i = 0; i < 16; i++) {
          int n = seg * 16 + i;
          s += b2f(rt[dq * 72 + n]) * faS[n] * b2f(kt[dq * 72 + n]);
        }
        s += __shfl_xor(s, 1);
        s += __shfl_xor(s, 2);
        if (seg == 0) diagS[dq] = s;
        __syncthreads();
      }

      f32x4 sacc[4];
#pragma unroll
      for (int jj = 0; jj < 4; jj++) sacc[jj] = (f32x4){0.f, 0.f, 0.f, 0.f};
#pragma unroll
      for (int ks = 0; ks < 2; ks++)
#pragma unroll
        for (int jj = 0; jj < 4; jj++) {
          bf16x8 bB = ldfrag(kt + (jj * 16 + fr) * 72 + ks * 32 + fq * 8);
          sacc[jj] = __builtin_amdgcn_mfma_f32_16x16x32_bf16(rA[ks], bB, sacc[jj], 0, 0, 0);
        }
      int ql0 = w * 16 + fq * 4;
#pragma unroll
      for (int jj = 0; jj < 4; jj++) {
        int kcol = kti * 64 + jj * 16 + fr;
        float ck = cumS[kcol];
#pragma unroll
        for (int rr = 0; rr < 4; rr++) {
          int qrow = qt * 64 + ql0 + rr;
          float vsc;
          if (kcol < qrow)
            vsc = sacc[jj][rr] * __expf(exS[qrow] - ck);
          else if (kcol == qrow)
            vsc = diagS[ql0 + rr];
          else
            vsc = 0.f;
          pt[(ql0 + rr) * 72 + jj * 16 + fr] = f2b(vsc);
        }
      }
      __syncthreads();
#pragma unroll
      for (int ks = 0; ks < 2; ks++) {
        bf16x8 pA = ldfrag(pt + (w * 16 + fr) * 72 + ks * 32 + fq * 8);
#pragma unroll
        for (int jm = 0; jm < 4; jm++) {
          bf16x8 vB = ldfrag(vt + (jm * 16 + fr) * 72 + ks * 32 + fq * 8);
          acc[jm] = __builtin_amdgcn_mfma_f32_16x16x32_bf16(pA, vB, acc[jm], 0, 0, 0);
        }
      }
    }
    int qg0 = qt * 64 + w * 16 + fq * 4;
#pragma unroll
    for (int jm = 0; jm < 4; jm++)
#pragma unroll
      for (int rr = 0; rr < 4; rr++)
        y[rowbase + (size_t)(qg0 + rr) * CC + jm * 16 + fr] = acc[jm][rr];
  }
}

// ---------------------------------------------------------------------------
// 10. LayerNorm over C -> bf16
// ---------------------------------------------------------------------------
__global__ __launch_bounds__(256) void ln_kernel(const float* __restrict__ y,
                                                 const float* __restrict__ g,
                                                 const float* __restrict__ bta,
                                                 u16* __restrict__ out) {
  __shared__ float red[8];
  int bt = blockIdx.x;
  int tid = threadIdx.x;
  float v[4];
  float s = 0.f;
#pragma unroll
  for (int i = 0; i < 4; i++) {
    v[i] = y[(size_t)bt * 1024 + i * 256 + tid];
    s += v[i];
  }
#pragma unroll
  for (int off = 32; off > 0; off >>= 1) s += __shfl_down(s, off);
  if ((tid & 63) == 0) red[tid >> 6] = s;
  __syncthreads();
  if (tid == 0) red[4] = red[0] + red[1] + red[2] + red[3];
  __syncthreads();
  float mu = red[4] * (1.f / 1024.f);
  float s2 = 0.f;
#pragma unroll
  for (int i = 0; i < 4; i++) {
    float d = v[i] - mu;
    s2 += d * d;
  }
#pragma unroll
  for (int off = 32; off > 0; off >>= 1) s2 += __shfl_down(s2, off);
  __syncthreads();
  if ((tid & 63) == 0) red[tid >> 6] = s2;
  __syncthreads();
  if (tid == 0) red[5] = red[0] + red[1] + red[2] + red[3];
  __syncthreads();
  float var = red[5] * (1.f / 1024.f);
  float rstd = rsqrtf(var + 1e-5f);
#pragma unroll
  for (int i = 0; i < 4; i++) {
    int c = i * 256 + tid;
    out[(size_t)bt * 1024 + c] = f2b((v[i] - mu) * rstd * g[c] + bta[c]);
  }
}

// ---------------------------------------------------------------------------
extern "C" void kernel_launch(void* const* d_in, const int* in_sizes, int n_in,
                              void* d_out, int out_size, void* d_ws,
                              size_t ws_size, hipStream_t stream) {
  const float* x = (const float*)d_in[0];
  const float* tmx = (const float*)d_in[1];
  const float* tmw = (const float*)d_in[2];
  const float* tmk = (const float*)d_in[3];
  const float* tmv = (const float*)d_in[4];
  const float* tmr = (const float*)d_in[5];
  const float* maa_w1 = (const float*)d_in[6];
  const float* maa_w2 = (const float*)d_in[7];
  const float* decay_w1 = (const float*)d_in[8];
  const float* decay_w2 = (const float*)d_in[9];
  const float* time_decay = (const float*)d_in[10];
  const float* faaaa = (const float*)d_in[11];
  const float* Wr = (const float*)d_in[12];
  const float* Wk = (const float*)d_in[13];
  const float* Wv = (const float*)d_in[14];
  const float* Wo = (const float*)d_in[15];
  const float* lng = (const float*)d_in[16];
  const float* lnb = (const float*)d_in[17];
  float* out = (float*)d_out;
  float* ws = (float*)d_ws;

  const size_t S = (size_t)BT * CC;  // 8388608

  // f32 region
  float* xx = ws;                     // mix out -> blend in; later y_ (attn out)
  float* dw2r = ws + S;               // 1024
  float* tdr = dw2r + 1024;           // pad to 1024
  float* wlog = tdr + 1024;           // 131072
  float* cum = wlog + 131072;
  float* excl = cum + 131072;
  float* wsl = excl + 131072;         // pad to 1024
  float* kvb = wsl + 1024;            // 512*4096
  float* stb = kvb + (size_t)512 * 4096;
  float* fend = stb + (size_t)512 * 4096;
  // bf16 region (u16)
  u16* xxxb = (u16*)fend;             // mix out -> maa GEMM in -> vT
  u16* mb = xxxb + S;                 // BT*128
  u16* xkb = mb + (size_t)BT * 128;   // blend out -> k-GEMM in -> rb16
  u16* xvb = xkb + S;                 // blend out -> v-GEMM in -> kb16 -> ylnb
  u16* xrb = xvb + S;                 // blend out -> r-GEMM in -> kTw
  u16* xwb = xrb + S;                 // blend out -> decay_mfma in
  u16* Vb = xwb + S;                  // v-GEMM bf16 out
  u16* Wrt = Vb + S;
  u16* Wkt = Wrt + (size_t)1024 * 1024;
  u16* Wvt = Wkt + (size_t)1024 * 1024;
  u16* Wot = Wvt + (size_t)1024 * 1024;
  u16* w1T = Wot + (size_t)1024 * 1024;   // [128][1024]
  u16* w2T = w1T + (size_t)128 * 1024;    // [1024][128]
  u16* d1T = w2T + (size_t)1024 * 128;    // [64][1024]
  u16* dw2rbT = d1T + (size_t)64 * 1024;  // [16][64]
  // aliases (stream-ordered reuse)
  u16* kb16 = xvb;  // after v-GEMM consumed xvb
  u16* rb16 = xkb;  // after k-GEMM consumed xkb
  u16* vT = xxxb;   // after maa GEMM consumed xxxb
  u16* kTw = xrb;   // after r-GEMM consumed xrb
  float* y_ = xx;   // after blend consumed xx
  u16* ylnb = xvb;  // after attn consumed kb16

  cvt_wT<<<dim3(16, 16, 4), 256, 0, stream>>>(Wr, Wk, Wv, Wo, Wrt, Wkt, Wvt, Wot);
  cvt_T<<<dim3(2, 16), 256, 0, stream>>>(maa_w1, w1T, 1024, 128);
  cvt_T<<<dim3(16, 2), 256, 0, stream>>>(maa_w2, w2T, 128, 1024);
  cvt_T<<<dim3(1, 16), 256, 0, stream>>>(decay_w1, d1T, 1024, 64);
  dw2r_kernel<<<4, 256, 0, stream>>>(decay_w2, time_decay, dw2r, tdr, dw2rbT);
  mix_kernel<<<8192, 256, 0, stream>>>(x, tmx, xx, xxxb);
  gemm_bt_mfma<true><<<dim3(1, 64), 256, 0, stream>>>(xxxb, w1T, nullptr, mb, BT, 128, CC);
  blend_mfma<<<dim3(16, 128), 256, 0, stream>>>(mb, w2T, x, xx, tmw, tmk, tmv,
                                                tmr, xwb, xkb, xvb, xrb);
  decay_mfma<<<128, 256, 0, stream>>>(xwb, d1T, dw2rbT, tdr, wlog);
  wprep_kernel<<<512, 256, 0, stream>>>(wlog, cum, excl, wsl);
  // order matters for buffer reuse: v -> k -> r -> transposes
  gemm_bt_mfma<false><<<dim3(8, 64), 256, 0, stream>>>(xvb, Wvt, nullptr, Vb, BT, CC, CC);
  gemm_bt_mfma<false><<<dim3(8, 64), 256, 0, stream>>>(xkb, Wkt, nullptr, kb16, BT, CC, CC);
  gemm_bt_mfma<false><<<dim3(8, 64), 256, 0, stream>>>(xrb, Wrt, nullptr, rb16, BT, CC, CC);
  kvtrans_kernel<<<dim3(32, 64), 256, 0, stream>>>(Vb, kb16, cum, wsl, vT, kTw);
  kv_mfma<<<512, 256, 0, stream>>>(kTw, vT, kvb);
  scan_kernel<<<64, 256, 0, stream>>>(kvb, wsl, stb);
  attn_mfma<<<512, 256, 0, stream>>>(rb16, kb16, vT, stb, cum, excl, faaaa, y_);
  ln_kernel<<<BT, 256, 0, stream>>>(y_, lng, lnb, ylnb);
  gemm_bt_mfma<false><<<dim3(8, 64), 256, 0, stream>>>(ylnb, Wot, out, nullptr, BT, CC, CC);
}

// Round 6
// 408.405 us; speedup vs baseline: 4.6233x; 1.0588x over previous
//
#include <hip/hip_runtime.h>
#include <math.h>

// B=4, T=2048, C=1024, H=16, N=64, Q=256, nc=8, BT=8192
#define BB 4
#define TT 2048
#define CC 1024
#define HH 16
#define NN 64
#define QQ 256
#define NCH 8
#define BT 8192

typedef unsigned short u16;
typedef __attribute__((ext_vector_type(8))) short bf16x8;
typedef __attribute__((ext_vector_type(4))) short bf16x4;
typedef __attribute__((ext_vector_type(4))) float f32x4;
typedef __attribute__((ext_vector_type(4))) u16 u16x4;

// f32 -> bf16 bits, round-to-nearest-even
__device__ inline u16 f2b(float x) {
  union { float f; unsigned u; } v;
  v.f = x;
  unsigned r = v.u + 0x7FFFu + ((v.u >> 16) & 1u);
  return (u16)(r >> 16);
}
__device__ inline float b2f(u16 u) {
  union { unsigned u; float f; } v;
  v.u = ((unsigned)u) << 16;
  return v.f;
}
// 16B fragment from padded LDS row via two 8B loads (conflict-friendly)
__device__ inline bf16x8 ldfrag(const u16* p) {
  bf16x4 lo = *(const bf16x4*)p;
  bf16x4 hi = *(const bf16x4*)(p + 4);
  return __builtin_shufflevector(lo, hi, 0, 1, 2, 3, 4, 5, 6, 7);
}
// stage 64x64 bf16 tile (global pitch `pitch` u16) into LDS stride-72
__device__ inline void stage_tile(const u16* __restrict__ g, size_t base,
                                  int pitch, int tid, u16* __restrict__ lds) {
#pragma unroll
  for (int it = 0; it < 2; it++) {
    int cidx = tid + it * 256;  // 0..511
    int r = cidx >> 3, c8 = (cidx & 7) * 8;
    bf16x8 v = *(const bf16x8*)(g + base + (size_t)r * pitch + c8);
    *(bf16x4*)(lds + r * 72 + c8) = __builtin_shufflevector(v, v, 0, 1, 2, 3);
    *(bf16x4*)(lds + r * 72 + c8 + 4) = __builtin_shufflevector(v, v, 4, 5, 6, 7);
  }
}

// ---------------------------------------------------------------------------
// 1. time-shift mix: xx f32, xxx -> bf16
// ---------------------------------------------------------------------------
__global__ __launch_bounds__(256) void mix_kernel(const float* __restrict__ x,
                                                  const float* __restrict__ tmx,
                                                  float* __restrict__ xx,
                                                  u16* __restrict__ xxxb) {
  size_t e = ((size_t)blockIdx.x * 256 + threadIdx.x) * 4;
  int c = (int)(e & 1023);
  size_t row = e >> 10;
  int t = (int)(row & 2047);
  float4 xv = *(const float4*)(x + e);
  float4 pv = make_float4(0.f, 0.f, 0.f, 0.f);
  if (t > 0) pv = *(const float4*)(x + e - 1024);
  float4 d = make_float4(pv.x - xv.x, pv.y - xv.y, pv.z - xv.z, pv.w - xv.w);
  *(float4*)(xx + e) = d;
  u16x4 o;
  o.x = f2b(xv.x + d.x * tmx[c + 0]);
  o.y = f2b(xv.y + d.y * tmx[c + 1]);
  o.z = f2b(xv.z + d.z * tmx[c + 2]);
  o.w = f2b(xv.w + d.w * tmx[c + 3]);
  *(u16x4*)(xxxb + e) = o;
}

// ---------------------------------------------------------------------------
// weight f32[k][n] (1024x1024) -> bf16 transposed Wt[n][k]
// ---------------------------------------------------------------------------
__global__ __launch_bounds__(256) void cvt_wT(const float* __restrict__ W0,
                                              const float* __restrict__ W1,
                                              const float* __restrict__ W2,
                                              const float* __restrict__ W3,
                                              u16* __restrict__ O0,
                                              u16* __restrict__ O1,
                                              u16* __restrict__ O2,
                                              u16* __restrict__ O3) {
  const float* W;
  u16* O;
  switch (blockIdx.z) {
    case 0: W = W0; O = O0; break;
    case 1: W = W1; O = O1; break;
    case 2: W = W2; O = O2; break;
    default: W = W3; O = O3; break;
  }
  __shared__ float t[64][65];
  int bx = blockIdx.x * 64;
  int by = blockIdx.y * 64;
#pragma unroll
  for (int it = 0; it < 16; it++) {
    int idx = it * 256 + threadIdx.x;
    int r = idx >> 6, c = idx & 63;
    t[r][c] = W[(size_t)(by + r) * 1024 + bx + c];
  }
  __syncthreads();
#pragma unroll
  for (int it = 0; it < 16; it++) {
    int idx = it * 256 + threadIdx.x;
    int n = idx >> 6, k = idx & 63;
    O[(size_t)(bx + n) * 1024 + by + k] = f2b(t[k][n]);
  }
}

// ---------------------------------------------------------------------------
// generic transpose+cvt: in f32 [R][C] -> out bf16 [C][R]  (R,C mult of 64)
// ---------------------------------------------------------------------------
__global__ __launch_bounds__(256) void cvt_T(const float* __restrict__ in,
                                             u16* __restrict__ out, int R, int C) {
  __shared__ float t[64][65];
  int c0 = blockIdx.x * 64, r0 = blockIdx.y * 64;
#pragma unroll
  for (int it = 0; it < 16; it++) {
    int idx = it * 256 + threadIdx.x;
    int r = idx >> 6, c = idx & 63;
    t[r][c] = in[(size_t)(r0 + r) * C + c0 + c];
  }
  __syncthreads();
#pragma unroll
  for (int it = 0; it < 16; it++) {
    int idx = it * 256 + threadIdx.x;
    int c = idx >> 6, r = idx & 63;
    out[(size_t)(c0 + c) * R + r0 + r] = f2b(t[r][c]);
  }
}

// ---------------------------------------------------------------------------
// bf16 MFMA GEMM (m97): A[M][K], Bt[N][K]; out f32 Cf and/or bf16 Cb (opt tanh)
// ---------------------------------------------------------------------------
template <bool TANH>
__global__ __launch_bounds__(256) void gemm_bt_mfma(const u16* __restrict__ A,
                                                    const u16* __restrict__ Bt,
                                                    float* __restrict__ Cf,
                                                    u16* __restrict__ Cb,
                                                    int M, int N, int K) {
  __shared__ u16 As[128 * 32];
  __shared__ u16 Bs[128 * 32];
  const int tid = threadIdx.x;
  const int lane = tid & 63;
  const int row0 = blockIdx.y * 128;
  const int col0 = blockIdx.x * 128;
  const int wave = tid >> 6;
  const int wr = (wave >> 1) * 64;
  const int wc = (wave & 1) * 64;
  const int fr = lane & 15;
  const int fq = lane >> 4;

  f32x4 acc[4][4];
#pragma unroll
  for (int i = 0; i < 4; i++)
#pragma unroll
    for (int j = 0; j < 4; j++) acc[i][j] = (f32x4){0.f, 0.f, 0.f, 0.f};

  const int i0 = tid, i1 = tid + 256;
  const int ra0 = i0 >> 2, ca0 = (i0 & 3) * 8;
  const int ra1 = i1 >> 2, ca1 = (i1 & 3) * 8;

  for (int k0 = 0; k0 < K; k0 += 32) {
    __builtin_amdgcn_global_load_lds(
        (const __attribute__((address_space(1))) void*)(A + (size_t)(row0 + ra0) * K + k0 + ca0),
        (__attribute__((address_space(3))) void*)(As + i0 * 8), 16, 0, 0);
    __builtin_amdgcn_global_load_lds(
        (const __attribute__((address_space(1))) void*)(A + (size_t)(row0 + ra1) * K + k0 + ca1),
        (__attribute__((address_space(3))) void*)(As + i1 * 8), 16, 0, 0);
    __builtin_amdgcn_global_load_lds(
        (const __attribute__((address_space(1))) void*)(Bt + (size_t)(col0 + ra0) * K + k0 + ca0),
        (__attribute__((address_space(3))) void*)(Bs + i0 * 8), 16, 0, 0);
    __builtin_amdgcn_global_load_lds(
        (const __attribute__((address_space(1))) void*)(Bt + (size_t)(col0 + ra1) * K + k0 + ca1),
        (__attribute__((address_space(3))) void*)(Bs + i1 * 8), 16, 0, 0);
    __syncthreads();

    bf16x8 af[4], bf[4];
#pragma unroll
    for (int i = 0; i < 4; i++)
      af[i] = *(const bf16x8*)(As + ((wr + i * 16 + fr) * 32 + fq * 8));
#pragma unroll
    for (int j = 0; j < 4; j++)
      bf[j] = *(const bf16x8*)(Bs + ((wc + j * 16 + fr) * 32 + fq * 8));
#pragma unroll
    for (int i = 0; i < 4; i++)
#pragma unroll
      for (int j = 0; j < 4; j++)
        acc[i][j] = __builtin_amdgcn_mfma_f32_16x16x32_bf16(af[i], bf[j], acc[i][j], 0, 0, 0);
    __syncthreads();
  }
#pragma unroll
  for (int i = 0; i < 4; i++) {
    int grow = row0 + wr + i * 16 + fq * 4;
#pragma unroll
    for (int j = 0; j < 4; j++) {
      int gcol = col0 + wc + j * 16 + fr;
#pragma unroll
      for (int r = 0; r < 4; r++) {
        float vv = acc[i][j][r];
        if (TANH) vv = tanhf(vv);
        if (Cf) Cf[(size_t)(grow + r) * N + gcol] = vv;
        if (Cb) Cb[(size_t)(grow + r) * N + gcol] = f2b(vv);
      }
    }
  }
}

// ---------------------------------------------------------------------------
// fused r/k/v projection GEMM: blockIdx.z selects (A, Bt, Cb) triple.
// M=8192, N=K=1024, bf16 out. 3x concurrency -> 1536 blocks (6/CU).
// ---------------------------------------------------------------------------
__global__ __launch_bounds__(256) void gemm3_mfma(
    const u16* __restrict__ A0, const u16* __restrict__ A1,
    const u16* __restrict__ A2, const u16* __restrict__ B0,
    const u16* __restrict__ B1, const u16* __restrict__ B2,
    u16* __restrict__ C0, u16* __restrict__ C1, u16* __restrict__ C2) {
  const u16* A;
  const u16* Bt;
  u16* Cb;
  switch (blockIdx.z) {
    case 0: A = A0; Bt = B0; Cb = C0; break;
    case 1: A = A1; Bt = B1; Cb = C1; break;
    default: A = A2; Bt = B2; Cb = C2; break;
  }
  __shared__ u16 As[128 * 32];
  __shared__ u16 Bs[128 * 32];
  const int tid = threadIdx.x;
  const int lane = tid & 63;
  const int row0 = blockIdx.y * 128;
  const int col0 = blockIdx.x * 128;
  const int wave = tid >> 6;
  const int wr = (wave >> 1) * 64;
  const int wc = (wave & 1) * 64;
  const int fr = lane & 15;
  const int fq = lane >> 4;

  f32x4 acc[4][4];
#pragma unroll
  for (int i = 0; i < 4; i++)
#pragma unroll
    for (int j = 0; j < 4; j++) acc[i][j] = (f32x4){0.f, 0.f, 0.f, 0.f};

  const int i0 = tid, i1 = tid + 256;
  const int ra0 = i0 >> 2, ca0 = (i0 & 3) * 8;
  const int ra1 = i1 >> 2, ca1 = (i1 & 3) * 8;

  for (int k0 = 0; k0 < 1024; k0 += 32) {
    __builtin_amdgcn_global_load_lds(
        (const __attribute__((address_space(1))) void*)(A + (size_t)(row0 + ra0) * 1024 + k0 + ca0),
        (__attribute__((address_space(3))) void*)(As + i0 * 8), 16, 0, 0);
    __builtin_amdgcn_global_load_lds(
        (const __attribute__((address_space(1))) void*)(A + (size_t)(row0 + ra1) * 1024 + k0 + ca1),
        (__attribute__((address_space(3))) void*)(As + i1 * 8), 16, 0, 0);
    __builtin_amdgcn_global_load_lds(
        (const __attribute__((address_space(1))) void*)(Bt + (size_t)(col0 + ra0) * 1024 + k0 + ca0),
        (__attribute__((address_space(3))) void*)(Bs + i0 * 8), 16, 0, 0);
    __builtin_amdgcn_global_load_lds(
        (const __attribute__((address_space(1))) void*)(Bt + (size_t)(col0 + ra1) * 1024 + k0 + ca1),
        (__attribute__((address_space(3))) void*)(Bs + i1 * 8), 16, 0, 0);
    __syncthreads();

    bf16x8 af[4], bf[4];
#pragma unroll
    for (int i = 0; i < 4; i++)
      af[i] = *(const bf16x8*)(As + ((wr + i * 16 + fr) * 32 + fq * 8));
#pragma unroll
    for (int j = 0; j < 4; j++)
      bf[j] = *(const bf16x8*)(Bs + ((wc + j * 16 + fr) * 32 + fq * 8));
#pragma unroll
    for (int i = 0; i < 4; i++)
#pragma unroll
      for (int j = 0; j < 4; j++)
        acc[i][j] = __builtin_amdgcn_mfma_f32_16x16x32_bf16(af[i], bf[j], acc[i][j], 0, 0, 0);
    __syncthreads();
  }
#pragma unroll
  for (int i = 0; i < 4; i++) {
    int grow = row0 + wr + i * 16 + fq * 4;
#pragma unroll
    for (int j = 0; j < 4; j++) {
      int gcol = col0 + wc + j * 16 + fr;
#pragma unroll
      for (int r = 0; r < 4; r++)
        Cb[(size_t)(grow + r) * 1024 + gcol] = f2b(acc[i][j][r]);
    }
  }
}

// ---------------------------------------------------------------------------
// 3. blend via MFMA (fused x/xx/tm* epilogue); all four outputs bf16.
// ---------------------------------------------------------------------------
__global__ __launch_bounds__(256) void blend_mfma(
    const u16* __restrict__ mb, const u16* __restrict__ w2T,
    const float* __restrict__ x, const float* __restrict__ xx,
    const float* __restrict__ tmw, const float* __restrict__ tmk,
    const float* __restrict__ tmv, const float* __restrict__ tmr,
    u16* __restrict__ xwb, u16* __restrict__ xkb, u16* __restrict__ xvb,
    u16* __restrict__ xrb) {
  __shared__ u16 mS[64 * 136];
  __shared__ u16 wS[64 * 136];
  const int tid = threadIdx.x;
  const int lane = tid & 63;
  const int w = tid >> 6;
  const int fr = lane & 15;
  const int fq = lane >> 4;
  const int c0 = blockIdx.x * 64;
  const int bt0 = blockIdx.y * 64;

#pragma unroll
  for (int it = 0; it < 4; it++) {
    int idx = tid + it * 256;  // 0..1023
    int r = idx >> 4, c8 = (idx & 15) * 8;
    bf16x8 v = *(const bf16x8*)(mb + (size_t)(bt0 + r) * 128 + c8);
    *(bf16x4*)(mS + r * 136 + c8) = __builtin_shufflevector(v, v, 0, 1, 2, 3);
    *(bf16x4*)(mS + r * 136 + c8 + 4) = __builtin_shufflevector(v, v, 4, 5, 6, 7);
    bf16x8 u = *(const bf16x8*)(w2T + (size_t)(c0 + r) * 128 + c8);
    *(bf16x4*)(wS + r * 136 + c8) = __builtin_shufflevector(u, u, 0, 1, 2, 3);
    *(bf16x4*)(wS + r * 136 + c8 + 4) = __builtin_shufflevector(u, u, 4, 5, 6, 7);
  }
  __syncthreads();

  f32x4 acc[4][4];  // [col-tile j][f]
#pragma unroll
  for (int j = 0; j < 4; j++)
#pragma unroll
    for (int f = 0; f < 4; f++) acc[j][f] = (f32x4){0.f, 0.f, 0.f, 0.f};

#pragma unroll
  for (int f = 0; f < 4; f++) {
    bf16x8 aA = ldfrag(mS + (w * 16 + fr) * 136 + f * 32 + fq * 8);
#pragma unroll
    for (int j = 0; j < 4; j++) {
      bf16x8 bB = ldfrag(wS + (j * 16 + fr) * 136 + f * 32 + fq * 8);
      acc[j][f] = __builtin_amdgcn_mfma_f32_16x16x32_bf16(aA, bB, acc[j][f], 0, 0, 0);
    }
  }

#pragma unroll
  for (int j = 0; j < 4; j++) {
    int c = c0 + j * 16 + fr;
    float w_ = tmw[c], k_ = tmk[c], v_ = tmv[c], r_ = tmr[c];
#pragma unroll
    for (int rr = 0; rr < 4; rr++) {
      int bt = bt0 + w * 16 + fq * 4 + rr;
      size_t g = (size_t)bt * 1024 + c;
      float xv_ = x[g], dx = xx[g];
      xwb[g] = f2b(xv_ + dx * (w_ + acc[j][0][rr]));
      xkb[g] = f2b(xv_ + dx * (k_ + acc[j][1][rr]));
      xvb[g] = f2b(xv_ + dx * (v_ + acc[j][2][rr]));
      xrb[g] = f2b(xv_ + dx * (r_ + acc[j][3][rr]));
    }
  }
}

// ---------------------------------------------------------------------------
// 5a. decay reduce: dw2r f32 [64][16], tdr f32 [16], dw2rbT bf16 [16][64]
// ---------------------------------------------------------------------------
__global__ __launch_bounds__(256) void dw2r_kernel(const float* __restrict__ dw2,
                                                   const float* __restrict__ td,
                                                   float* __restrict__ dw2r,
                                                   float* __restrict__ tdr,
                                                   u16* __restrict__ dw2rbT) {
  int idx = blockIdx.x * 256 + threadIdx.x;
  if (idx < 1024) {
    int j = idx >> 4, h = idx & 15;
    float s = 0.f;
    for (int n = 0; n < 64; n++) s += dw2[(size_t)j * 1024 + h * 64 + n];
    float m = s * (1.f / 64.f);
    dw2r[j * 16 + h] = m;
    dw2rbT[h * 64 + j] = f2b(m);
  }
  if (idx < 16) {
    float s = 0.f;
    for (int n = 0; n < 64; n++) s += td[idx * 64 + n];
    tdr[idx] = s * (1.f / 64.f);
  }
}

// ---------------------------------------------------------------------------
// 5b. fused decay GEMM: h1 = tanh(xw @ d1) via MFMA (K=1024), then
//     wlog = -exp(tdr + h1 @ dw2r) via a second 2-step MFMA. 64-row tiles.
// ---------------------------------------------------------------------------
__global__ __launch_bounds__(256) void decay_mfma(const u16* __restrict__ xwb,
                                                  const u16* __restrict__ d1T,
                                                  const u16* __restrict__ dw2rbT,
                                                  const float* __restrict__ tdr,
                                                  float* __restrict__ wlog) {
  __shared__ u16 As[64 * 32];
  __shared__ u16 Bs[64 * 32];
  __shared__ u16 h1S[64 * 72];
  __shared__ u16 dwS[16 * 72];
  const int tid = threadIdx.x;
  const int lane = tid & 63;
  const int w = tid >> 6;
  const int fr = lane & 15;
  const int fq = lane >> 4;
  const int bt0 = blockIdx.x * 64;

#pragma unroll
  for (int it = 0; it < 4; it++) {
    int idx = tid + it * 256;
    int r = idx >> 6, c = idx & 63;
    dwS[r * 72 + c] = dw2rbT[r * 64 + c];
  }

  f32x4 acc[4];
#pragma unroll
  for (int j = 0; j < 4; j++) acc[j] = (f32x4){0.f, 0.f, 0.f, 0.f};

  const int ra = tid >> 2, ca = (tid & 3) * 8;
  for (int k0 = 0; k0 < 1024; k0 += 32) {
    __builtin_amdgcn_global_load_lds(
        (const __attribute__((address_space(1))) void*)(xwb + (size_t)(bt0 + ra) * 1024 + k0 + ca),
        (__attribute__((address_space(3))) void*)(As + tid * 8), 16, 0, 0);
    __builtin_amdgcn_global_load_lds(
        (const __attribute__((address_space(1))) void*)(d1T + (size_t)ra * 1024 + k0 + ca),
        (__attribute__((address_space(3))) void*)(Bs + tid * 8), 16, 0, 0);
    __syncthreads();
    bf16x8 aA = *(const bf16x8*)(As + ((w * 16 + fr) * 32 + fq * 8));
#pragma unroll
    for (int j = 0; j < 4; j++) {
      bf16x8 bB = *(const bf16x8*)(Bs + ((j * 16 + fr) * 32 + fq * 8));
      acc[j] = __builtin_amdgcn_mfma_f32_16x16x32_bf16(aA, bB, acc[j], 0, 0, 0);
    }
    __syncthreads();
  }
#pragma unroll
  for (int j = 0; j < 4; j++)
#pragma unroll
    for (int rr = 0; rr < 4; rr++)
      h1S[(w * 16 + fq * 4 + rr) * 72 + j * 16 + fr] = f2b(tanhf(acc[j][rr]));
  __syncthreads();

  f32x4 a2 = (f32x4){0.f, 0.f, 0.f, 0.f};
#pragma unroll
  for (int ks = 0; ks < 2; ks++) {
    bf16x8 aA = ldfrag(h1S + (w * 16 + fr) * 72 + ks * 32 + fq * 8);
    bf16x8 bB = ldfrag(dwS + fr * 72 + ks * 32 + fq * 8);
    a2 = __builtin_amdgcn_mfma_f32_16x16x32_bf16(aA, bB, a2, 0, 0, 0);
  }
  float tdv = tdr[fr];
#pragma unroll
  for (int rr = 0; rr < 4; rr++) {
    int bt = bt0 + w * 16 + fq * 4 + rr;
    int b = bt >> 11, tl = bt & 2047;
    wlog[((size_t)(b * 16 + fr)) * 2048 + tl] = -__expf(tdv + a2[rr]);
  }
}

// ---------------------------------------------------------------------------
// 7. per-chunk scan
// ---------------------------------------------------------------------------
__global__ __launch_bounds__(256) void wprep_kernel(const float* __restrict__ wlog,
                                                    float* __restrict__ cum,
                                                    float* __restrict__ excl,
                                                    float* __restrict__ wsl) {
  int bid = blockIdx.x;
  int c = bid & 7, bh = bid >> 3;
  int q = threadIdx.x;
  float v = wlog[(size_t)bh * 2048 + c * 256 + q];
  __shared__ float s[256];
  s[q] = v;
  float val = v;
  for (int off = 1; off < 256; off <<= 1) {
    __syncthreads();
    float t = (q >= off) ? s[q - off] : 0.f;
    __syncthreads();
    val += t;
    s[q] = val;
  }
  __syncthreads();
  float total = s[255];
  cum[(size_t)bid * 256 + q] = val;
  excl[(size_t)bid * 256 + q] = val - v;
  if (q == 0) wsl[bid] = total;
}

// ---------------------------------------------------------------------------
// kvtrans2: per-head transpose of bf16 k,v (k scaled by w_inter on output),
// plus diag[b,h,t] = sum_n r*fa*k (raw k), via full-wave reduce.
// ---------------------------------------------------------------------------
__global__ __launch_bounds__(256) void kvtrans2_kernel(
    const u16* __restrict__ vb, const u16* __restrict__ kb,
    const u16* __restrict__ rb, const float* __restrict__ faaaa,
    const float* __restrict__ cum, const float* __restrict__ wsl,
    u16* __restrict__ vT, u16* __restrict__ kTw, float* __restrict__ diagG) {
  int tt = blockIdx.x;  // t-tile 0..31
  int bh = blockIdx.y;  // 0..63
  int b = bh >> 4, h = bh & 15;
  int cc = tt >> 2;
  int bidc = bh * 8 + cc;
  __shared__ float tv[64][65];
  __shared__ float tk[64][65];
  __shared__ float wfac[64];
  __shared__ float faS[64];
  const int tid = threadIdx.x;
  float wslog = wsl[bidc];
  if (tid < 64) {
    wfac[tid] = __expf(wslog - cum[(size_t)bidc * 256 + (tt & 3) * 64 + tid]);
    faS[tid] = faaaa[h * 64 + tid];
  }
  __syncthreads();
  const int m = tid & 63;
  float fam = faS[m];
#pragma unroll
  for (int it = 0; it < 16; it++) {
    int r = it * 4 + (tid >> 6);
    size_t g = ((size_t)(b * TT + tt * 64 + r)) * CC + h * 64 + m;
    float vraw = b2f(vb[g]);
    float kraw = b2f(kb[g]);
    float rraw = b2f(rb[g]);
    tv[r][m] = vraw;
    tk[r][m] = kraw;
    float s = rraw * fam * kraw;
    s += __shfl_xor(s, 1);
    s += __shfl_xor(s, 2);
    s += __shfl_xor(s, 4);
    s += __shfl_xor(s, 8);
    s += __shfl_xor(s, 16);
    s += __shfl_xor(s, 32);
    if (m == 0) diagG[(size_t)bh * 2048 + tt * 64 + r] = s;
  }
  __syncthreads();
#pragma unroll
  for (int it = 0; it < 16; it++) {
    int idx = it * 256 + tid;
    int mm = idx >> 6, tl = idx & 63;
    size_t o = ((size_t)(bh * 64 + mm)) * TT + tt * 64 + tl;
    vT[o] = f2b(tv[tl][mm]);
    kTw[o] = f2b(tk[tl][mm] * wfac[tl]);
  }
}

// ---------------------------------------------------------------------------
// 8a. kv via MFMA
// ---------------------------------------------------------------------------
__global__ __launch_bounds__(256) void kv_mfma(const u16* __restrict__ kTw,
                                               const u16* __restrict__ vT,
                                               float* __restrict__ kvb) {
  int bid = blockIdx.x;
  int c = bid & 7, bh = bid >> 3;
  __shared__ u16 kS[64 * 72];
  __shared__ u16 vS[64 * 72];
  const int tid = threadIdx.x;
  const int lane = tid & 63;
  const int w = tid >> 6;
  const int fr = lane & 15;
  const int fq = lane >> 4;
  f32x4 acc[4];
#pragma unroll
  for (int j = 0; j < 4; j++) acc[j] = (f32x4){0.f, 0.f, 0.f, 0.f};
  const size_t base = (size_t)bh * 64 * TT + c * QQ;
  for (int qt = 0; qt < 4; qt++) {
    __syncthreads();
    stage_tile(kTw, base + qt * 64, TT, tid, kS);
    stage_tile(vT, base + qt * 64, TT, tid, vS);
    __syncthreads();
#pragma unroll
    for (int ks = 0; ks < 2; ks++) {
      bf16x8 aA = ldfrag(kS + (w * 16 + fr) * 72 + ks * 32 + fq * 8);
#pragma unroll
      for (int j = 0; j < 4; j++) {
        bf16x8 bB = ldfrag(vS + (j * 16 + fr) * 72 + ks * 32 + fq * 8);
        acc[j] = __builtin_amdgcn_mfma_f32_16x16x32_bf16(aA, bB, acc[j], 0, 0, 0);
      }
    }
  }
#pragma unroll
  for (int j = 0; j < 4; j++)
#pragma unroll
    for (int rr = 0; rr < 4; rr++)
      kvb[(size_t)bid * 4096 + (w * 16 + fq * 4 + rr) * 64 + j * 16 + fr] = acc[j][rr];
}

// ---------------------------------------------------------------------------
// 8b. sequential state scan over chunks
// ---------------------------------------------------------------------------
__global__ __launch_bounds__(256) void scan_kernel(const float* __restrict__ kvb,
                                                   const float* __restrict__ wsl,
                                                   float* __restrict__ st) {
  int bh = blockIdx.x;
  int tid = threadIdx.x;
  float s[16];
#pragma unroll
  for (int i = 0; i < 16; i++) s[i] = 0.f;
  for (int c = 0; c < 8; c++) {
    int bid = bh * 8 + c;
    float w = __expf(wsl[bid]);
#pragma unroll
    for (int i = 0; i < 16; i++) {
      size_t e = (size_t)bid * 4096 + i * 256 + tid;
      st[e] = s[i];
      s[i] = w * s[i] + kvb[e];
    }
  }
}

// ---------------------------------------------------------------------------
// 9. MFMA fused attention. Mask via factored exp tables:
// exp(excl[q]-cum[k]) = exp(excl[q]-cc) * exp(cc-cum[k]), cc = cum[127]
// (both exponents bounded ~|47| -> no overflow; true product <= 1).
// Diagonal read from diagG (precomputed in kvtrans2).
// ---------------------------------------------------------------------------
__global__ __launch_bounds__(256) void attn_mfma(
    const u16* __restrict__ rb, const u16* __restrict__ kb,
    const u16* __restrict__ vT, const float* __restrict__ stg,
    const float* __restrict__ cum, const float* __restrict__ excl,
    const float* __restrict__ diagG, float* __restrict__ y) {
  int bid = blockIdx.x;
  int c = bid & 7, bh = bid >> 3;
  int b = bh >> 4, h = bh & 15;
  __shared__ u16 rt[64 * 72];
  __shared__ u16 kt[64 * 72];
  __shared__ u16 vt[64 * 72];
  __shared__ u16 pt[64 * 72];
  __shared__ u16 stT[64 * 72];
  __shared__ float cumS[256], exS[256], diagS[256], ekS[256];

  const int tid = threadIdx.x;
  const int lane = tid & 63;
  const int w = tid >> 6;
  const int fr = lane & 15;
  const int fq = lane >> 4;

  cumS[tid] = cum[(size_t)bid * 256 + tid];
  exS[tid] = excl[(size_t)bid * 256 + tid];
  diagS[tid] = diagG[(size_t)bh * 2048 + c * 256 + tid];
#pragma unroll
  for (int it = 0; it < 16; it++) {
    int idx = tid + it * 256;
    int n = idx >> 6, mm = idx & 63;
    stT[mm * 72 + n] = f2b(stg[(size_t)bid * 4096 + idx]);
  }
  __syncthreads();
  const float ccm = cumS[127];
  ekS[tid] = __expf(ccm - cumS[tid]);

  const size_t rowbase = ((size_t)b * TT + c * QQ) * CC + h * 64;
  const size_t vbase0 = (size_t)bh * 64 * TT + c * QQ;

  for (int qt = 0; qt < 4; qt++) {
    __syncthreads();
    stage_tile(rb, rowbase + (size_t)(qt * 64) * CC, CC, tid, rt);
    __syncthreads();

    f32x4 acc[4];
#pragma unroll
    for (int jm = 0; jm < 4; jm++) acc[jm] = (f32x4){0.f, 0.f, 0.f, 0.f};
    bf16x8 rA[2];
    rA[0] = ldfrag(rt + (w * 16 + fr) * 72 + fq * 8);
    rA[1] = ldfrag(rt + (w * 16 + fr) * 72 + 32 + fq * 8);
#pragma unroll
    for (int ks = 0; ks < 2; ks++)
#pragma unroll
      for (int jm = 0; jm < 4; jm++) {
        bf16x8 bB = ldfrag(stT + (jm * 16 + fr) * 72 + ks * 32 + fq * 8);
        acc[jm] = __builtin_amdgcn_mfma_f32_16x16x32_bf16(rA[ks], bB, acc[jm], 0, 0, 0);
      }
    int ql0 = w * 16 + fq * 4;
    float er[4], eqc[4];
#pragma unroll
    for (int rr = 0; rr < 4; rr++) {
      float ex = exS[qt * 64 + ql0 + rr];
      er[rr] = __expf(ex);
      eqc[rr] = __expf(ex - ccm);
    }
#pragma unroll
    for (int jm = 0; jm < 4; jm++)
#pragma unroll
      for (int rr = 0; rr < 4; rr++) acc[jm][rr] *= er[rr];

    for (int kti = 0; kti <= qt; kti++) {
      __syncthreads();
      stage_tile(kb, rowbase + (size_t)(kti * 64) * CC, CC, tid, kt);
      stage_tile(vT, vbase0 + (size_t)(kti * 64), TT, tid, vt);
      __syncthreads();

      f32x4 sacc[4];
#pragma unroll
      for (int jj = 0; jj < 4; jj++) sacc[jj] = (f32x4){0.f, 0.f, 0.f, 0.f};
#pragma unroll
      for (int ks = 0; ks < 2; ks++)
#pragma unroll
        for (int jj = 0; jj < 4; jj++) {
          bf16x8 bB = ldfrag(kt + (jj * 16 + fr) * 72 + ks * 32 + fq * 8);
          sacc[jj] = __builtin_amdgcn_mfma_f32_16x16x32_bf16(rA[ks], bB, sacc[jj], 0, 0, 0);
        }
#pragma unroll
      for (int jj = 0; jj < 4; jj++) {
        int kcol = kti * 64 + jj * 16 + fr;
        float ek = ekS[kcol];
#pragma unroll
        for (int rr = 0; rr < 4; rr++) {
          int qrow = qt * 64 + ql0 + rr;
          float vsc;
          if (kcol < qrow)
            vsc = sacc[jj][rr] * eqc[rr] * ek;
          else if (kcol == qrow)
            vsc = diagS[qrow];
          else
            vsc = 0.f;
          pt[(ql0 + rr) * 72 + jj * 16 + fr] = f2b(vsc);
        }
      }
      __syncthreads();
#pragma unroll
      for (int ks = 0; ks < 2; ks++) {
        bf16x8 pA = ldfrag(pt + (w * 16 + fr) * 72 + ks * 32 + fq * 8);
#pragma unroll
        for (int jm = 0; jm < 4; jm++) {
          bf16x8 vB = ldfrag(vt + (jm * 16 + fr) * 72 + ks * 32 + fq * 8);
          acc[jm] = __builtin_amdgcn_mfma_f32_16x16x32_bf16(pA, vB, acc[jm], 0, 0, 0);
        }
      }
    }
    int qg0 = qt * 64 + w * 16 + fq * 4;
#pragma unroll
    for (int jm = 0; jm < 4; jm++)
#pragma unroll
      for (int rr = 0; rr < 4; rr++)
        y[rowbase + (size_t)(qg0 + rr) * CC + jm * 16 + fr] = acc[jm][rr];
  }
}

// ---------------------------------------------------------------------------
// 10. LayerNorm over C -> bf16
// ---------------------------------------------------------------------------
__global__ __launch_bounds__(256) void ln_kernel(const float* __restrict__ y,
                                                 const float* __restrict__ g,
                                                 const float* __restrict__ bta,
                                                 u16* __restrict__ out) {
  __shared__ float red[8];
  int bt = blockIdx.x;
  int tid = threadIdx.x;
  float v[4];
  float s = 0.f;
#pragma unroll
  for (int i = 0; i < 4; i++) {
    v[i] = y[(size_t)bt * 1024 + i * 256 + tid];
    s += v[i];
  }
#pragma unroll
  for (int off = 32; off > 0; off >>= 1) s += __shfl_down(s, off);
  if ((tid & 63) == 0) red[tid >> 6] = s;
  __syncthreads();
  if (tid == 0) red[4] = red[0] + red[1] + red[2] + red[3];
  __syncthreads();
  float mu = red[4] * (1.f / 1024.f);
  float s2 = 0.f;
#pragma unroll
  for (int i = 0; i < 4; i++) {
    float d = v[i] - mu;
    s2 += d * d;
  }
#pragma unroll
  for (int off = 32; off > 0; off >>= 1) s2 += __shfl_down(s2, off);
  __syncthreads();
  if ((tid & 63) == 0) red[tid >> 6] = s2;
  __syncthreads();
  if (tid == 0) red[5] = red[0] + red[1] + red[2] + red[3];
  __syncthreads();
  float var = red[5] * (1.f / 1024.f);
  float rstd = rsqrtf(var + 1e-5f);
#pragma unroll
  for (int i = 0; i < 4; i++) {
    int c = i * 256 + tid;
    out[(size_t)bt * 1024 + c] = f2b((v[i] - mu) * rstd * g[c] + bta[c]);
  }
}

// ---------------------------------------------------------------------------
extern "C" void kernel_launch(void* const* d_in, const int* in_sizes, int n_in,
                              void* d_out, int out_size, void* d_ws,
                              size_t ws_size, hipStream_t stream) {
  const float* x = (const float*)d_in[0];
  const float* tmx = (const float*)d_in[1];
  const float* tmw = (const float*)d_in[2];
  const float* tmk = (const float*)d_in[3];
  const float* tmv = (const float*)d_in[4];
  const float* tmr = (const float*)d_in[5];
  const float* maa_w1 = (const float*)d_in[6];
  const float* maa_w2 = (const float*)d_in[7];
  const float* decay_w1 = (const float*)d_in[8];
  const float* decay_w2 = (const float*)d_in[9];
  const float* time_decay = (const float*)d_in[10];
  const float* faaaa = (const float*)d_in[11];
  const float* Wr = (const float*)d_in[12];
  const float* Wk = (const float*)d_in[13];
  const float* Wv = (const float*)d_in[14];
  const float* Wo = (const float*)d_in[15];
  const float* lng = (const float*)d_in[16];
  const float* lnb = (const float*)d_in[17];
  float* out = (float*)d_out;
  float* ws = (float*)d_ws;

  const size_t S = (size_t)BT * CC;  // 8388608

  // f32 region
  float* xx = ws;                     // mix out -> blend in; later y_ (attn out)
  float* dw2r = ws + S;               // 1024
  float* tdr = dw2r + 1024;           // pad to 1024
  float* wlog = tdr + 1024;           // 131072
  float* cum = wlog + 131072;
  float* excl = cum + 131072;
  float* wsl = excl + 131072;         // pad to 1024
  float* diagG = wsl + 1024;          // 131072
  float* kvb = diagG + 131072;        // 512*4096
  float* stb = kvb + (size_t)512 * 4096;
  float* fend = stb + (size_t)512 * 4096;
  // bf16 region (u16) — rb16/kb16/Vb are now distinct from blend outputs
  // because the fused gemm3 runs all three projections concurrently.
  u16* xxxb = (u16*)fend;             // mix out -> maa GEMM in -> vT
  u16* mb = xxxb + S;                 // BT*128
  u16* xkb = mb + (size_t)BT * 128;   // blend out -> gemm3 in -> ylnb
  u16* xvb = xkb + S;                 // blend out -> gemm3 in
  u16* xrb = xvb + S;                 // blend out -> gemm3 in -> kTw
  u16* xwb = xrb + S;                 // blend out -> decay_mfma in
  u16* rb16 = xwb + S;                // gemm3 out
  u16* kb16 = rb16 + S;               // gemm3 out
  u16* Vb = kb16 + S;                 // gemm3 out
  u16* Wrt = Vb + S;
  u16* Wkt = Wrt + (size_t)1024 * 1024;
  u16* Wvt = Wkt + (size_t)1024 * 1024;
  u16* Wot = Wvt + (size_t)1024 * 1024;
  u16* w1T = Wot + (size_t)1024 * 1024;   // [128][1024]
  u16* w2T = w1T + (size_t)128 * 1024;    // [1024][128]
  u16* d1T = w2T + (size_t)1024 * 128;    // [64][1024]
  u16* dw2rbT = d1T + (size_t)64 * 1024;  // [16][64]
  // aliases (stream-ordered reuse)
  u16* vT = xxxb;   // after maa GEMM consumed xxxb
  u16* kTw = xrb;   // after gemm3 consumed xrb
  float* y_ = xx;   // after blend consumed xx
  u16* ylnb = xkb;  // after gemm3 consumed xkb

  cvt_wT<<<dim3(16, 16, 4), 256, 0, stream>>>(Wr, Wk, Wv, Wo, Wrt, Wkt, Wvt, Wot);
  cvt_T<<<dim3(2, 16), 256, 0, stream>>>(maa_w1, w1T, 1024, 128);
  cvt_T<<<dim3(16, 2), 256, 0, stream>>>(maa_w2, w2T, 128, 1024);
  cvt_T<<<dim3(1, 16), 256, 0, stream>>>(decay_w1, d1T, 1024, 64);
  dw2r_kernel<<<4, 256, 0, stream>>>(decay_w2, time_decay, dw2r, tdr, dw2rbT);
  mix_kernel<<<8192, 256, 0, stream>>>(x, tmx, xx, xxxb);
  gemm_bt_mfma<true><<<dim3(1, 64), 256, 0, stream>>>(xxxb, w1T, nullptr, mb, BT, 128, CC);
  blend_mfma<<<dim3(16, 128), 256, 0, stream>>>(mb, w2T, x, xx, tmw, tmk, tmv,
                                                tmr, xwb, xkb, xvb, xrb);
  decay_mfma<<<128, 256, 0, stream>>>(xwb, d1T, dw2rbT, tdr, wlog);
  wprep_kernel<<<512, 256, 0, stream>>>(wlog, cum, excl, wsl);
  // fused r/k/v projections (concurrent via z)
  gemm3_mfma<<<dim3(8, 64, 3), 256, 0, stream>>>(xrb, xkb, xvb, Wrt, Wkt, Wvt,
                                                 rb16, kb16, Vb);
  kvtrans2_kernel<<<dim3(32, 64), 256, 0, stream>>>(Vb, kb16, rb16, faaaa, cum,
                                                    wsl, vT, kTw, diagG);
  kv_mfma<<<512, 256, 0, stream>>>(kTw, vT, kvb);
  scan_kernel<<<64, 256, 0, stream>>>(kvb, wsl, stb);
  attn_mfma<<<512, 256, 0, stream>>>(rb16, kb16, vT, stb, cum, excl, diagG, y_);
  ln_kernel<<<BT, 256, 0, stream>>>(y_, lng, lnb, ylnb);
  gemm_bt_mfma<false><<<dim3(8, 64), 256, 0, stream>>>(ylnb, Wot, out, nullptr, BT, CC, CC);
}